// Round 8
// baseline (413.750 us; speedup 1.0000x reference)
//
#include <hip/hip_runtime.h>

// ---------------------------------------------------------------------------
// colorableGNN: 3x GCN(128->128) + FC(128->128) + FC(128->2) + mean-pool + softmax
// R7: fused kernels. k_aggemm = agg (into LDS A-tile) + MFMA GEMM + fp8
// epilogue (Z never hits memory). k_final = agg + GEMM(W3) + FC1 GEMM (H3
// stays in LDS) + FC2 + per-graph pool. 16 -> 9 dispatches, -90MB of
// intermediate round-trips. fp8 gathered activations, bf16 hi/lo weights,
// fp32 accumulate (absmax 0.0 for 4 rounds).
// ---------------------------------------------------------------------------

#define CH 128
#define BSH 7              // 128 dst nodes per bucket
#define SEG 4096           // segment capacity (records) per bucket
#define EPW 4096           // edges per phase-1 workgroup
#define SA 40              // LDS stride for W chunks (shorts)
#define SAF 136            // LDS stride for full-K A tile (shorts, 272B = 17*16)
#define SC8 144            // fp8 epilogue stride (bytes)

typedef unsigned short ushortT;
typedef unsigned int uintT;
typedef unsigned char ucharT;
typedef __attribute__((ext_vector_type(8))) short short8;
typedef __attribute__((ext_vector_type(4))) float floatx4;
typedef __attribute__((ext_vector_type(2))) float floatx2;

__device__ __forceinline__ float bf2f(uintT u) {
    return __uint_as_float(u << 16);
}
__device__ __forceinline__ ushortT f2bf(float f) {
    uintT x = __float_as_uint(f);
    return (ushortT)((x + 0x7fffu + ((x >> 16) & 1u)) >> 16);
}

// ---- zero bfill + pooling accumulators ------------------------------------
__global__ void k_zero(int* __restrict__ bfill, int NB, float* __restrict__ acc, int nacc) {
    int t = threadIdx.x;
    for (int i = t; i < NB; i += 256) bfill[i] = 0;
    for (int i = t; i < nacc; i += 256) acc[i] = 0.f;
}

// ---- phase 1: bin edges into dst-buckets, LDS-staged coalesced writes -----
__global__ __launch_bounds__(256) void k_bin(const int* __restrict__ row,
                                             const int* __restrict__ col,
                                             int* __restrict__ bfill,
                                             uint2* __restrict__ seg,
                                             int E, int NB) {
    __shared__ uint2 staged[EPW];   // 32 KB
    __shared__ int target[EPW];     // 16 KB
    __shared__ int sval[512];
    __shared__ int horig[512];
    __shared__ int pcnt[512];
    __shared__ int gbase[512];
    const int t = threadIdx.x;
    const int e0 = blockIdx.x * EPW;
    const int cnt = min(EPW, E - e0);

    sval[t] = 0; sval[t + 256] = 0;
    __syncthreads();

    int er[16], ec[16];
#pragma unroll
    for (int i = 0; i < 16; ++i) {
        int le = i * 256 + t;
        if (le < cnt) {
            er[i] = row[e0 + le];
            ec[i] = col[e0 + le];
            atomicAdd(&sval[ec[i] >> BSH], 1);
        }
    }
    __syncthreads();
    horig[t] = sval[t]; horig[t + 256] = sval[t + 256];
    __syncthreads();
    for (int off = 1; off < 512; off <<= 1) {
        int a = (t >= off) ? sval[t - off] : 0;
        int b2 = sval[t + 256 - off];
        __syncthreads();
        sval[t] += a;
        sval[t + 256] += b2;
        __syncthreads();
    }
    for (int b = t; b < 512; b += 256) {
        int h = horig[b];
        pcnt[b] = sval[b] - h;
        gbase[b] = (h > 0 && b < NB) ? atomicAdd(&bfill[b], h) : 0;
    }
    __syncthreads();
#pragma unroll
    for (int i = 0; i < 16; ++i) {
        int le = i * 256 + t;
        if (le < cnt) {
            int b = ec[i] >> BSH;
            int j = atomicAdd(&pcnt[b], 1);
            staged[j] = uint2{(uintT)er[i], (uintT)ec[i]};
            int lo = sval[b] - horig[b];
            target[j] = b * SEG + gbase[b] + (j - lo);
        }
    }
    __syncthreads();
    for (int s = t; s < cnt; s += 256) seg[target[s]] = staged[s];
}

// ---- fused: per-bucket degree->invs (blocks 0..NB-1) + bucket scan (NB) ---
__global__ __launch_bounds__(512) void k_binvs_bscan(const int* __restrict__ bfill,
                                                     const uint2* __restrict__ seg,
                                                     float* __restrict__ invs,
                                                     int* __restrict__ bbase,
                                                     int* __restrict__ indptr,
                                                     int NB, int N, int E) {
    const int b = blockIdx.x;
    const int t = threadIdx.x;
    if (b < NB) {
        __shared__ int h[128];
        if (t < 128) h[t] = 0;
        __syncthreads();
        int cnt = bfill[b];
        const uint2* sp = seg + (size_t)b * SEG;
        for (int s = t; s < cnt; s += 512) atomicAdd(&h[sp[s].y & 127], 1);
        __syncthreads();
        int d = b * 128 + t;
        if (t < 128 && d < N) invs[d] = rsqrtf((float)h[t] + 1.0f);
    } else {
        __shared__ int s[512];
        int v = (t < NB) ? bfill[t] : 0;
        s[t] = v;
        __syncthreads();
        for (int off = 1; off < 512; off <<= 1) {
            int a = (t >= off) ? s[t - off] : 0;
            __syncthreads();
            s[t] += a;
            __syncthreads();
        }
        if (t < NB) bbase[t] = s[t] - v;  // exclusive
        if (t == 0) indptr[N] = E;
    }
}

// ---- per-bucket CSR scatter: local degrees+scan, contiguous output --------
__global__ __launch_bounds__(256) void k_scatter(const int* __restrict__ bfill,
                                                 const int* __restrict__ bbase,
                                                 const uint2* __restrict__ seg,
                                                 const float* __restrict__ invs,
                                                 int* __restrict__ indptr,
                                                 uint2* __restrict__ epack, int N) {
    __shared__ uint2 staged[SEG];   // 32 KB
    __shared__ int h[128];
    __shared__ int sc[128];
    __shared__ int pc[128];
    const int b = blockIdx.x;
    const int t = threadIdx.x;
    const int cnt = bfill[b];
    const int base = bbase[b];
    const uint2* sp = seg + (size_t)b * SEG;

    if (t < 128) h[t] = 0;
    __syncthreads();
    for (int s = t; s < cnt; s += 256) atomicAdd(&h[sp[s].y & 127], 1);
    __syncthreads();
    if (t < 128) sc[t] = h[t];
    __syncthreads();
    for (int off = 1; off < 128; off <<= 1) {
        int a = (t >= off && t < 128) ? sc[t - off] : 0;
        __syncthreads();
        if (t < 128) sc[t] += a;
        __syncthreads();
    }
    if (t < 128) {
        int excl = sc[t] - h[t];
        pc[t] = excl;
        int d = b * 128 + t;
        if (d < N) indptr[d] = base + excl;
    }
    __syncthreads();
    for (int s = t; s < cnt; s += 256) {
        uint2 rc = sp[s];
        int src = (int)rc.x, dst = (int)rc.y;
        int j = atomicAdd(&pc[dst & 127], 1);
        uint2 pk;
        pk.x = rc.x;
        pk.y = __float_as_uint(invs[src] * invs[dst]);
        staged[j] = pk;
    }
    __syncthreads();
    for (int s = t; s < cnt; s += 256) epack[base + s] = staged[s];
}

// ---- prep: weights fp32 -> transposed bf16 hi/lo; X fp32 -> fp8 -----------
__global__ void k_prep(const float* __restrict__ X, ucharT* __restrict__ Xb,
                       const float* __restrict__ w0, const float* __restrict__ w1,
                       const float* __restrict__ w2, const float* __restrict__ w3,
                       ushortT* __restrict__ Whi, ushortT* __restrict__ Wlo,
                       int total4) {
    if (blockIdx.x < 256) {
        int idx = blockIdx.x * 256 + threadIdx.x;  // 0..65535
        int m = idx >> 14;
        int r = idx & 16383;
        int n = r >> 7;
        int k = r & 127;
        const float* W = (m == 0) ? w0 : (m == 1) ? w1 : (m == 2) ? w2 : w3;
        float w = W[k * CH + n];
        ushortT hi = f2bf(w);
        float lo = w - bf2f(hi);
        Whi[m * 16384 + n * CH + k] = hi;
        Wlo[m * 16384 + n * CH + k] = f2bf(lo);
    } else {
        int i = (blockIdx.x - 256) * 256 + threadIdx.x;
        if (i < total4) {
            float4 v = reinterpret_cast<const float4*>(X)[i];
            int r0 = __builtin_amdgcn_cvt_pk_fp8_f32(v.x, v.y, 0, false);
            int r1 = __builtin_amdgcn_cvt_pk_fp8_f32(v.z, v.w, r0, true);
            reinterpret_cast<int*>(Xb)[i] = r1;
        }
    }
}

// ---- shared device helper: aggregate 32 nodes/wave into LDS A-tile --------
__device__ __forceinline__ void agg_to_lds(const ushortT* __restrict__ H16,
                                           const uint2* __restrict__ epack,
                                           const int* __restrict__ indptr,
                                           const float* __restrict__ invs,
                                           uintT* __restrict__ As32,
                                           int row0, int wave, int lane, int N) {
    for (int i = 0; i < 32; ++i) {
        int lrow = wave * 32 + i;
        int node = row0 + lrow;
        float ax = 0.f, ay = 0.f;
        if (node < N) {
            float sn = invs[node];
            float sn2 = sn * sn;
            floatx2 hf = __builtin_amdgcn_cvt_pk_f32_fp8((int)H16[(size_t)node * 64 + lane], false);
            ax = sn2 * hf.x;
            ay = sn2 * hf.y;
            int p = indptr[node];
            int p1 = indptr[node + 1];
            for (; p + 16 <= p1; p += 16) {
                uint2 e[16];
#pragma unroll
                for (int q = 0; q < 16; ++q) e[q] = epack[p + q];
                uintT g[16];
#pragma unroll
                for (int q = 0; q < 16; ++q) g[q] = H16[(size_t)(int)e[q].x * 64 + lane];
#pragma unroll
                for (int q = 0; q < 16; ++q) {
                    float wv = __uint_as_float(e[q].y);
                    floatx2 gf = __builtin_amdgcn_cvt_pk_f32_fp8((int)g[q], false);
                    ax += wv * gf.x;
                    ay += wv * gf.y;
                }
            }
            for (; p + 4 <= p1; p += 4) {
                uint2 e[4];
#pragma unroll
                for (int q = 0; q < 4; ++q) e[q] = epack[p + q];
                uintT g[4];
#pragma unroll
                for (int q = 0; q < 4; ++q) g[q] = H16[(size_t)(int)e[q].x * 64 + lane];
#pragma unroll
                for (int q = 0; q < 4; ++q) {
                    float wv = __uint_as_float(e[q].y);
                    floatx2 gf = __builtin_amdgcn_cvt_pk_f32_fp8((int)g[q], false);
                    ax += wv * gf.x;
                    ay += wv * gf.y;
                }
            }
            for (; p < p1; ++p) {
                uint2 e = epack[p];
                uintT g = H16[(size_t)(int)e.x * 64 + lane];
                float wv = __uint_as_float(e.y);
                floatx2 gf = __builtin_amdgcn_cvt_pk_f32_fp8((int)g, false);
                ax += wv * gf.x;
                ay += wv * gf.y;
            }
        }
        As32[lrow * (SAF / 2) + lane] = (uintT)f2bf(ax) | ((uintT)f2bf(ay) << 16);
    }
}

// ---- fused agg + MFMA GEMM, fp8 output (GCN layers 1,2) -------------------
__global__ __launch_bounds__(256) void k_aggemm(const ucharT* __restrict__ H8in,
                                                const uint2* __restrict__ epack,
                                                const int* __restrict__ indptr,
                                                const float* __restrict__ invs,
                                                const ushortT* __restrict__ Whi,
                                                const ushortT* __restrict__ Wlo,
                                                const float* __restrict__ Bias,
                                                ucharT* __restrict__ H8out, int N) {
    __shared__ ushortT As[128 * SAF];   // 34816 B; aliased by fp8 epilogue
    __shared__ ushortT Hs[128 * SA];    // 10240 B
    __shared__ ushortT Ls[128 * SA];    // 10240 B

    const int tid = threadIdx.x;
    const int wave = tid >> 6, lane = tid & 63;
    const int quad = lane >> 4, l15 = lane & 15;
    const int mBase = (wave >> 1) * 64, nBase = (wave & 1) * 64;
    const int row0 = blockIdx.x * 128;
    const int r = tid >> 1, half = tid & 1;

    agg_to_lds((const ushortT*)H8in, epack, indptr, invs,
               reinterpret_cast<uintT*>(As), row0, wave, lane, N);
    __syncthreads();

    floatx4 acc[4][4];
    const floatx4 zero4 = {0.f, 0.f, 0.f, 0.f};
#pragma unroll
    for (int i = 0; i < 4; i++)
#pragma unroll
        for (int j = 0; j < 4; j++) acc[i][j] = zero4;

    for (int ks = 0; ks < 4; ++ks) {
        {
            const uint4* sh = reinterpret_cast<const uint4*>(Whi + r * CH + ks * 32 + half * 16);
            uint4* dh = reinterpret_cast<uint4*>(&Hs[r * SA + half * 16]);
            dh[0] = sh[0]; dh[1] = sh[1];
            const uint4* sl = reinterpret_cast<const uint4*>(Wlo + r * CH + ks * 32 + half * 16);
            uint4* dl = reinterpret_cast<uint4*>(&Ls[r * SA + half * 16]);
            dl[0] = sl[0]; dl[1] = sl[1];
        }
        __syncthreads();
        short8 af[4], hf[4], lf[4];
#pragma unroll
        for (int mt = 0; mt < 4; ++mt)
            af[mt] = *reinterpret_cast<const short8*>(&As[(mBase + mt * 16 + l15) * SAF + ks * 32 + quad * 8]);
#pragma unroll
        for (int nt = 0; nt < 4; ++nt) {
            hf[nt] = *reinterpret_cast<const short8*>(&Hs[(nBase + nt * 16 + l15) * SA + quad * 8]);
            lf[nt] = *reinterpret_cast<const short8*>(&Ls[(nBase + nt * 16 + l15) * SA + quad * 8]);
        }
#pragma unroll
        for (int mt = 0; mt < 4; ++mt)
#pragma unroll
            for (int nt = 0; nt < 4; ++nt) {
                acc[mt][nt] = __builtin_amdgcn_mfma_f32_16x16x32_bf16(af[mt], hf[nt], acc[mt][nt], 0, 0, 0);
                acc[mt][nt] = __builtin_amdgcn_mfma_f32_16x16x32_bf16(af[mt], lf[nt], acc[mt][nt], 0, 0, 0);
            }
        __syncthreads();
    }

    float bb[4];
#pragma unroll
    for (int nt = 0; nt < 4; ++nt) bb[nt] = Bias[nBase + nt * 16 + l15];

    // fp8 epilogue into As alias (all As reads done: barrier above)
    ucharT* Cs8 = reinterpret_cast<ucharT*>(As);
#pragma unroll
    for (int mt = 0; mt < 4; ++mt)
#pragma unroll
        for (int nt = 0; nt < 4; ++nt)
#pragma unroll
            for (int r4 = 0; r4 < 4; ++r4) {
                int lrow = mBase + mt * 16 + quad * 4 + r4;
                float v = fmaxf(acc[mt][nt][r4] + bb[nt], 0.f);
                int f8 = __builtin_amdgcn_cvt_pk_fp8_f32(v, 0.f, 0, false);
                Cs8[lrow * SC8 + nBase + nt * 16 + l15] = (ucharT)(f8 & 0xff);
            }
    __syncthreads();
    {
        int grow = row0 + r;
        if (grow < N) {
            const uint4* s4 = reinterpret_cast<const uint4*>(&Cs8[r * SC8 + half * 64]);
            uint4* dst = reinterpret_cast<uint4*>(H8out + (size_t)grow * CH + half * 64);
#pragma unroll
            for (int q = 0; q < 4; ++q) dst[q] = s4[q];
        }
    }
}

// ---- fused: agg + GEMM(W3) + FC1 GEMM + FC2 + per-graph pool --------------
__global__ __launch_bounds__(256) void k_final(const ucharT* __restrict__ H8in,
                                               const uint2* __restrict__ epack,
                                               const int* __restrict__ indptr,
                                               const float* __restrict__ invs,
                                               const ushortT* __restrict__ W3hi,
                                               const ushortT* __restrict__ W3lo,
                                               const float* __restrict__ B3,
                                               const ushortT* __restrict__ F1hi,
                                               const ushortT* __restrict__ F1lo,
                                               const float* __restrict__ FB1,
                                               const float* __restrict__ FW2,
                                               const float* __restrict__ FB2,
                                               const int* __restrict__ batch,
                                               float* __restrict__ sums,
                                               float* __restrict__ cnts, int N) {
    __shared__ ushortT As[128 * SAF];
    __shared__ ushortT Hs[128 * SA];
    __shared__ ushortT Ls[128 * SA];
    __shared__ float rp0[256];   // [row][nhalf]
    __shared__ float rp1[256];
    __shared__ float ls[192];

    const int tid = threadIdx.x;
    const int wave = tid >> 6, lane = tid & 63;
    const int quad = lane >> 4, l15 = lane & 15;
    const int mBase = (wave >> 1) * 64, nBase = (wave & 1) * 64;
    const int row0 = blockIdx.x * 128;
    const int r = tid >> 1, half = tid & 1;

    agg_to_lds((const ushortT*)H8in, epack, indptr, invs,
               reinterpret_cast<uintT*>(As), row0, wave, lane, N);
    __syncthreads();

    floatx4 acc[4][4];
    const floatx4 zero4 = {0.f, 0.f, 0.f, 0.f};
#pragma unroll
    for (int i = 0; i < 4; i++)
#pragma unroll
        for (int j = 0; j < 4; j++) acc[i][j] = zero4;

    // GEMM with W3
    for (int ks = 0; ks < 4; ++ks) {
        {
            const uint4* sh = reinterpret_cast<const uint4*>(W3hi + r * CH + ks * 32 + half * 16);
            uint4* dh = reinterpret_cast<uint4*>(&Hs[r * SA + half * 16]);
            dh[0] = sh[0]; dh[1] = sh[1];
            const uint4* sl = reinterpret_cast<const uint4*>(W3lo + r * CH + ks * 32 + half * 16);
            uint4* dl = reinterpret_cast<uint4*>(&Ls[r * SA + half * 16]);
            dl[0] = sl[0]; dl[1] = sl[1];
        }
        __syncthreads();
        short8 af[4], hf[4], lf[4];
#pragma unroll
        for (int mt = 0; mt < 4; ++mt)
            af[mt] = *reinterpret_cast<const short8*>(&As[(mBase + mt * 16 + l15) * SAF + ks * 32 + quad * 8]);
#pragma unroll
        for (int nt = 0; nt < 4; ++nt) {
            hf[nt] = *reinterpret_cast<const short8*>(&Hs[(nBase + nt * 16 + l15) * SA + quad * 8]);
            lf[nt] = *reinterpret_cast<const short8*>(&Ls[(nBase + nt * 16 + l15) * SA + quad * 8]);
        }
#pragma unroll
        for (int mt = 0; mt < 4; ++mt)
#pragma unroll
            for (int nt = 0; nt < 4; ++nt) {
                acc[mt][nt] = __builtin_amdgcn_mfma_f32_16x16x32_bf16(af[mt], hf[nt], acc[mt][nt], 0, 0, 0);
                acc[mt][nt] = __builtin_amdgcn_mfma_f32_16x16x32_bf16(af[mt], lf[nt], acc[mt][nt], 0, 0, 0);
            }
        __syncthreads();
    }

    // epilogue 1: H3 = relu(acc + b3) -> bf16 back into As (A of FC1)
    {
        float bb[4];
#pragma unroll
        for (int nt = 0; nt < 4; ++nt) bb[nt] = B3[nBase + nt * 16 + l15];
#pragma unroll
        for (int mt = 0; mt < 4; ++mt)
#pragma unroll
            for (int nt = 0; nt < 4; ++nt)
#pragma unroll
                for (int r4 = 0; r4 < 4; ++r4) {
                    int lrow = mBase + mt * 16 + quad * 4 + r4;
                    float v = fmaxf(acc[mt][nt][r4] + bb[nt], 0.f);
                    As[lrow * SAF + nBase + nt * 16 + l15] = f2bf(v);
                }
    }
    __syncthreads();

    // FC1 GEMM
#pragma unroll
    for (int i = 0; i < 4; i++)
#pragma unroll
        for (int j = 0; j < 4; j++) acc[i][j] = zero4;
    for (int ks = 0; ks < 4; ++ks) {
        {
            const uint4* sh = reinterpret_cast<const uint4*>(F1hi + r * CH + ks * 32 + half * 16);
            uint4* dh = reinterpret_cast<uint4*>(&Hs[r * SA + half * 16]);
            dh[0] = sh[0]; dh[1] = sh[1];
            const uint4* sl = reinterpret_cast<const uint4*>(F1lo + r * CH + ks * 32 + half * 16);
            uint4* dl = reinterpret_cast<uint4*>(&Ls[r * SA + half * 16]);
            dl[0] = sl[0]; dl[1] = sl[1];
        }
        __syncthreads();
        short8 af[4], hf[4], lf[4];
#pragma unroll
        for (int mt = 0; mt < 4; ++mt)
            af[mt] = *reinterpret_cast<const short8*>(&As[(mBase + mt * 16 + l15) * SAF + ks * 32 + quad * 8]);
#pragma unroll
        for (int nt = 0; nt < 4; ++nt) {
            hf[nt] = *reinterpret_cast<const short8*>(&Hs[(nBase + nt * 16 + l15) * SA + quad * 8]);
            lf[nt] = *reinterpret_cast<const short8*>(&Ls[(nBase + nt * 16 + l15) * SA + quad * 8]);
        }
#pragma unroll
        for (int mt = 0; mt < 4; ++mt)
#pragma unroll
            for (int nt = 0; nt < 4; ++nt) {
                acc[mt][nt] = __builtin_amdgcn_mfma_f32_16x16x32_bf16(af[mt], hf[nt], acc[mt][nt], 0, 0, 0);
                acc[mt][nt] = __builtin_amdgcn_mfma_f32_16x16x32_bf16(af[mt], lf[nt], acc[mt][nt], 0, 0, 0);
            }
        __syncthreads();
    }

    // FC2: per-row dot with fcW2 over this lane's 4 columns, reduce over l15
    {
        float bb[4];
#pragma unroll
        for (int nt = 0; nt < 4; ++nt) bb[nt] = FB1[nBase + nt * 16 + l15];
        float w20[4], w21[4];
#pragma unroll
        for (int nt = 0; nt < 4; ++nt) {
            float2 wv = *reinterpret_cast<const float2*>(FW2 + 2 * (nBase + nt * 16 + l15));
            w20[nt] = wv.x;
            w21[nt] = wv.y;
        }
#pragma unroll
        for (int mt = 0; mt < 4; ++mt)
#pragma unroll
            for (int r4 = 0; r4 < 4; ++r4) {
                float d0 = 0.f, d1 = 0.f;
#pragma unroll
                for (int nt = 0; nt < 4; ++nt) {
                    float v = fmaxf(acc[mt][nt][r4] + bb[nt], 0.f);
                    d0 += v * w20[nt];
                    d1 += v * w21[nt];
                }
#pragma unroll
                for (int m = 8; m >= 1; m >>= 1) {
                    d0 += __shfl_xor(d0, m, 64);
                    d1 += __shfl_xor(d1, m, 64);
                }
                if (l15 == 0) {
                    int lrow = mBase + mt * 16 + quad * 4 + r4;
                    rp0[lrow * 2 + (wave & 1)] = d0;
                    rp1[lrow * 2 + (wave & 1)] = d1;
                }
            }
    }
    if (tid < 192) ls[tid] = 0.f;
    __syncthreads();

    if (tid < 128) {
        int node = row0 + tid;
        if (node < N) {
            float d0 = rp0[tid * 2] + rp0[tid * 2 + 1] + FB2[0];
            float d1 = rp1[tid * 2] + rp1[tid * 2 + 1] + FB2[1];
            int g = batch[node];
            atomicAdd(&ls[g], d0);
            atomicAdd(&ls[64 + g], d1);
            atomicAdd(&ls[128 + g], 1.0f);
        }
    }
    __syncthreads();
    if (tid < 64) {
        float c = ls[128 + tid];
        if (c != 0.f) {
            atomicAdd(&sums[2 * tid], ls[tid]);
            atomicAdd(&sums[2 * tid + 1], ls[64 + tid]);
            atomicAdd(&cnts[tid], c);
        }
    }
}

__global__ void k_softmax(const float* __restrict__ sums, const float* __restrict__ cnts,
                          float* __restrict__ out, int G) {
    int g = blockIdx.x * blockDim.x + threadIdx.x;
    if (g < G) {
        float c = fmaxf(cnts[g], 1.0f);
        float p0 = sums[2 * g] / c;
        float p1 = sums[2 * g + 1] / c;
        float m = fmaxf(p0, p1);
        float e0 = expf(p0 - m), e1 = expf(p1 - m);
        float inv = 1.f / (e0 + e1);
        out[2 * g] = e0 * inv;
        out[2 * g + 1] = e1 * inv;
    }
}

// ---------------------------------------------------------------------------
extern "C" void kernel_launch(void* const* d_in, const int* in_sizes, int n_in,
                              void* d_out, int out_size, void* d_ws, size_t ws_size,
                              hipStream_t stream) {
    const float* X   = (const float*)d_in[0];
    const int* EI    = (const int*)d_in[1];
    const int* BATCH = (const int*)d_in[2];
    const float* W1  = (const float*)d_in[3];
    const float* B1  = (const float*)d_in[4];
    const float* W2  = (const float*)d_in[5];
    const float* B2  = (const float*)d_in[6];
    const float* W3  = (const float*)d_in[7];
    const float* B3  = (const float*)d_in[8];
    const float* FW1 = (const float*)d_in[9];
    const float* FB1 = (const float*)d_in[10];
    const float* FW2 = (const float*)d_in[11];
    const float* FB2 = (const float*)d_in[12];

    const int N = in_sizes[0] / CH;
    const int E = in_sizes[1] / 2;
    const int G = out_size / 2;
    const int* rowp = EI;
    const int* colp = EI + E;
    const int NB = (N + 127) >> BSH;

    char* w = (char*)d_ws;
    auto alloc = [&](size_t bytes) -> char* {
        char* p = w;
        w += (bytes + 255) & ~(size_t)255;
        return p;
    };
    ucharT*  Xb8   = (ucharT*)alloc((size_t)N * CH);        // fp8 X
    ucharT*  Ha8   = (ucharT*)alloc((size_t)N * CH);        // fp8 H1
    ucharT*  Hb8   = (ucharT*)alloc((size_t)N * CH);        // fp8 H2
    ushortT* WhiA  = (ushortT*)alloc((size_t)4 * 16384 * 2);
    ushortT* WloA  = (ushortT*)alloc((size_t)4 * 16384 * 2);
    float* invs    = (float*)alloc((size_t)N * 4);
    int*   indptr  = (int*)alloc((size_t)(N + 1) * 4);
    uint2* epack   = (uint2*)alloc((size_t)E * 8);
    uint2* seg     = (uint2*)alloc((size_t)NB * SEG * 8);
    int*   bfill   = (int*)alloc((size_t)NB * 4);
    int*   bbase   = (int*)alloc((size_t)NB * 4);
    float* sums    = (float*)alloc((size_t)G * 3 * 4);      // sums | cnts
    float* cnts    = sums + 2 * G;

    const int nbGemm = (N + 127) / 128;
    const int nbBin  = (E + EPW - 1) / EPW;
    const int total4 = N * CH / 4;

    k_zero<<<1, 256, 0, stream>>>(bfill, NB, sums, 3 * G);
    k_bin<<<nbBin, 256, 0, stream>>>(rowp, colp, bfill, seg, E, NB);
    k_binvs_bscan<<<NB + 1, 512, 0, stream>>>(bfill, seg, invs, bbase, indptr, NB, N, E);
    k_scatter<<<NB, 256, 0, stream>>>(bfill, bbase, seg, invs, indptr, epack, N);
    k_prep<<<256 + (total4 + 255) / 256, 256, 0, stream>>>(X, Xb8, W1, W2, W3, FW1,
                                                           WhiA, WloA, total4);

    // layer 1: agg(X) + GEMM W1 -> fp8 H1
    k_aggemm<<<nbGemm, 256, 0, stream>>>(Xb8, epack, indptr, invs,
                                         WhiA, WloA, B1, Ha8, N);
    // layer 2: agg(H1) + GEMM W2 -> fp8 H2
    k_aggemm<<<nbGemm, 256, 0, stream>>>(Ha8, epack, indptr, invs,
                                         WhiA + 16384, WloA + 16384, B2, Hb8, N);
    // layer 3 + FC1 + FC2 + pool
    k_final<<<nbGemm, 256, 0, stream>>>(Hb8, epack, indptr, invs,
                                        WhiA + 2 * 16384, WloA + 2 * 16384, B3,
                                        WhiA + 3 * 16384, WloA + 3 * 16384, FB1,
                                        FW2, FB2, BATCH, sums, cnts, N);
    k_softmax<<<1, 64, 0, stream>>>(sums, cnts, (float*)d_out, G);
}

// Round 9
// 252.771 us; speedup vs baseline: 1.6369x; 1.6369x over previous
//
#include <hip/hip_runtime.h>

// ---------------------------------------------------------------------------
// colorableGNN: 3x GCN(128->128) + FC(128->128) + FC(128->2) + mean-pool + softmax
// R8: R6 structure restored (R7 fusion => 2 blocks/CU, gather latency
// unhidden, 104us/dispatch). Deltas vs R6: (1) 4B edge records
// (src:16|norm bf16:16) halve edge-stream + CSR traffic; (2) single bf16
// weights (hi/lo dropped -- fp8 activations already pass at absmax 0);
// (3) k_gemm LDS union (34KB -> 4 blocks/CU) + merged prep dispatches.
// NOTE: gather kernels need occupancy; never fuse agg into GEMM (R7).
// ---------------------------------------------------------------------------

#define CH 128
#define BSH 7              // 128 dst nodes per bucket
#define SEG 4096           // segment capacity (records) per bucket
#define EPW 4096           // edges per phase-1 workgroup
#define SA 40              // LDS stride for A/W chunks (shorts)
#define SC 132             // bf16 epilogue stride (shorts)
#define SC8 144            // fp8 epilogue stride (bytes)

typedef unsigned short ushortT;
typedef unsigned int uintT;
typedef unsigned char ucharT;
typedef __attribute__((ext_vector_type(8))) short short8;
typedef __attribute__((ext_vector_type(4))) float floatx4;
typedef __attribute__((ext_vector_type(2))) float floatx2;

__device__ __forceinline__ float bf2f(uintT u) {
    return __uint_as_float(u << 16);
}
__device__ __forceinline__ ushortT f2bf(float f) {
    uintT x = __float_as_uint(f);
    return (ushortT)((x + 0x7fffu + ((x >> 16) & 1u)) >> 16);
}

// ---- zero bfill + pooling accumulators ------------------------------------
__global__ void k_zero(int* __restrict__ bfill, int NB, float* __restrict__ acc, int nacc) {
    int t = threadIdx.x;
    for (int i = t; i < NB; i += 256) bfill[i] = 0;
    for (int i = t; i < nacc; i += 256) acc[i] = 0.f;
}

// ---- phase 1: bin edges into dst-buckets; records packed src|(dst<<16) ----
__global__ __launch_bounds__(256) void k_bin(const int* __restrict__ row,
                                             const int* __restrict__ col,
                                             int* __restrict__ bfill,
                                             uintT* __restrict__ seg,
                                             int E, int NB) {
    __shared__ uintT staged[EPW];   // 16 KB
    __shared__ int target[EPW];     // 16 KB
    __shared__ int sval[512];
    __shared__ int horig[512];
    __shared__ int pcnt[512];
    __shared__ int gbase[512];
    const int t = threadIdx.x;
    const int e0 = blockIdx.x * EPW;
    const int cnt = min(EPW, E - e0);

    sval[t] = 0; sval[t + 256] = 0;
    __syncthreads();

    int er[16], ec[16];
#pragma unroll
    for (int i = 0; i < 16; ++i) {
        int le = i * 256 + t;
        if (le < cnt) {
            er[i] = row[e0 + le];
            ec[i] = col[e0 + le];
            atomicAdd(&sval[ec[i] >> BSH], 1);
        }
    }
    __syncthreads();
    horig[t] = sval[t]; horig[t + 256] = sval[t + 256];
    __syncthreads();
    for (int off = 1; off < 512; off <<= 1) {
        int a = (t >= off) ? sval[t - off] : 0;
        int b2 = sval[t + 256 - off];
        __syncthreads();
        sval[t] += a;
        sval[t + 256] += b2;
        __syncthreads();
    }
    for (int b = t; b < 512; b += 256) {
        int h = horig[b];
        pcnt[b] = sval[b] - h;
        gbase[b] = (h > 0 && b < NB) ? atomicAdd(&bfill[b], h) : 0;
    }
    __syncthreads();
#pragma unroll
    for (int i = 0; i < 16; ++i) {
        int le = i * 256 + t;
        if (le < cnt) {
            int b = ec[i] >> BSH;
            int j = atomicAdd(&pcnt[b], 1);
            staged[j] = (uintT)er[i] | ((uintT)ec[i] << 16);
            int lo = sval[b] - horig[b];
            target[j] = b * SEG + gbase[b] + (j - lo);
        }
    }
    __syncthreads();
    for (int s = t; s < cnt; s += 256) seg[target[s]] = staged[s];
}

// ---- fused: per-bucket degree->invs (blocks 0..NB-1) + bucket scan (NB) ---
__global__ __launch_bounds__(512) void k_binvs_bscan(const int* __restrict__ bfill,
                                                     const uintT* __restrict__ seg,
                                                     float* __restrict__ invs,
                                                     int* __restrict__ bbase,
                                                     int* __restrict__ indptr,
                                                     int NB, int N, int E) {
    const int b = blockIdx.x;
    const int t = threadIdx.x;
    if (b < NB) {
        __shared__ int h[128];
        if (t < 128) h[t] = 0;
        __syncthreads();
        int cnt = bfill[b];
        const uintT* sp = seg + (size_t)b * SEG;
        for (int s = t; s < cnt; s += 512) atomicAdd(&h[(sp[s] >> 16) & 127], 1);
        __syncthreads();
        int d = b * 128 + t;
        if (t < 128 && d < N) invs[d] = rsqrtf((float)h[t] + 1.0f);
    } else {
        __shared__ int s[512];
        int v = (t < NB) ? bfill[t] : 0;
        s[t] = v;
        __syncthreads();
        for (int off = 1; off < 512; off <<= 1) {
            int a = (t >= off) ? s[t - off] : 0;
            __syncthreads();
            s[t] += a;
            __syncthreads();
        }
        if (t < NB) bbase[t] = s[t] - v;  // exclusive
        if (t == 0) indptr[N] = E;
    }
}

// ---- heterogeneous: CSR scatter | weight prep | X->fp8 --------------------
__global__ __launch_bounds__(256) void k_scatterprep(const int* __restrict__ bfill,
                                                     const int* __restrict__ bbase,
                                                     const uintT* __restrict__ seg,
                                                     const float* __restrict__ invs,
                                                     int* __restrict__ indptr,
                                                     uintT* __restrict__ epack,
                                                     const float* __restrict__ X,
                                                     ucharT* __restrict__ Xb,
                                                     const float* __restrict__ w0,
                                                     const float* __restrict__ w1,
                                                     const float* __restrict__ w2,
                                                     const float* __restrict__ w3,
                                                     ushortT* __restrict__ Whi,
                                                     int N, int NB, int total4) {
    const int t = threadIdx.x;
    if ((int)blockIdx.x < NB) {
        // ---- CSR scatter: bucket-local degrees+scan, contiguous output ----
        __shared__ uintT staged[SEG];   // 16 KB
        __shared__ int h[128];
        __shared__ int sc[128];
        __shared__ int pc[128];
        const int b = blockIdx.x;
        const int cnt = bfill[b];
        const int base = bbase[b];
        const uintT* sp = seg + (size_t)b * SEG;

        if (t < 128) h[t] = 0;
        __syncthreads();
        for (int s = t; s < cnt; s += 256) atomicAdd(&h[(sp[s] >> 16) & 127], 1);
        __syncthreads();
        if (t < 128) sc[t] = h[t];
        __syncthreads();
        for (int off = 1; off < 128; off <<= 1) {
            int a = (t >= off && t < 128) ? sc[t - off] : 0;
            __syncthreads();
            if (t < 128) sc[t] += a;
            __syncthreads();
        }
        if (t < 128) {
            int excl = sc[t] - h[t];
            pc[t] = excl;
            int d = b * 128 + t;
            if (d < N) indptr[d] = base + excl;
        }
        __syncthreads();
        for (int s = t; s < cnt; s += 256) {
            uintT rc = sp[s];
            int src = (int)(rc & 0xffffu), dst = (int)(rc >> 16);
            int j = atomicAdd(&pc[dst & 127], 1);
            float nrm = invs[src] * invs[dst];
            staged[j] = (uintT)src | ((uintT)f2bf(nrm) << 16);
        }
        __syncthreads();
        for (int s = t; s < cnt; s += 256) epack[base + s] = staged[s];
    } else if ((int)blockIdx.x < NB + 256) {
        // ---- weight prep: W[k][n] fp32 -> Whi[n][k] bf16 (4 matrices) -----
        int idx = (blockIdx.x - NB) * 256 + t;  // 0..65535
        int m = idx >> 14;
        int r = idx & 16383;
        int n = r >> 7;
        int k = r & 127;
        const float* W = (m == 0) ? w0 : (m == 1) ? w1 : (m == 2) ? w2 : w3;
        Whi[m * 16384 + n * CH + k] = f2bf(W[k * CH + n]);
    } else {
        // ---- X fp32 -> fp8 ------------------------------------------------
        int i = (blockIdx.x - NB - 256) * 256 + t;
        if (i < total4) {
            float4 v = reinterpret_cast<const float4*>(X)[i];
            int r0 = __builtin_amdgcn_cvt_pk_fp8_f32(v.x, v.y, 0, false);
            int r1 = __builtin_amdgcn_cvt_pk_fp8_f32(v.z, v.w, r0, true);
            reinterpret_cast<int*>(Xb)[i] = r1;
        }
    }
}

// ---- aggregation: gather fp8 rows, fp32 accumulate, bf16 out --------------
// one wave per node; 4B edge records (src:16 | norm bf16:16)
__global__ __launch_bounds__(256) void k_agg(const ucharT* __restrict__ H8,
                                             const uintT* __restrict__ epack,
                                             const int* __restrict__ indptr,
                                             const float* __restrict__ invs,
                                             ushortT* __restrict__ Zb, int N) {
    int node = blockIdx.x * 4 + (threadIdx.x >> 6);
    if (node >= N) return;
    int lane = threadIdx.x & 63;

    const ushortT* H16 = reinterpret_cast<const ushortT*>(H8);

    float sn = invs[node];
    float sn2 = sn * sn;
    floatx2 hf = __builtin_amdgcn_cvt_pk_f32_fp8((int)H16[(size_t)node * 64 + lane], false);
    float ax = sn2 * hf.x, ay = sn2 * hf.y;

    int p = indptr[node];
    int p1 = indptr[node + 1];
    for (; p + 8 <= p1; p += 8) {
        uintT e[8];
#pragma unroll
        for (int i = 0; i < 8; ++i) e[i] = epack[p + i];
        uintT g[8];
#pragma unroll
        for (int i = 0; i < 8; ++i) g[i] = H16[(size_t)(int)(e[i] & 0xffffu) * 64 + lane];
#pragma unroll
        for (int i = 0; i < 8; ++i) {
            float wv = bf2f(e[i] >> 16);
            floatx2 gf = __builtin_amdgcn_cvt_pk_f32_fp8((int)g[i], false);
            ax += wv * gf.x;
            ay += wv * gf.y;
        }
    }
    if (p + 4 <= p1) {
        uintT e[4];
#pragma unroll
        for (int i = 0; i < 4; ++i) e[i] = epack[p + i];
        uintT g[4];
#pragma unroll
        for (int i = 0; i < 4; ++i) g[i] = H16[(size_t)(int)(e[i] & 0xffffu) * 64 + lane];
#pragma unroll
        for (int i = 0; i < 4; ++i) {
            float wv = bf2f(e[i] >> 16);
            floatx2 gf = __builtin_amdgcn_cvt_pk_f32_fp8((int)g[i], false);
            ax += wv * gf.x;
            ay += wv * gf.y;
        }
        p += 4;
    }
    for (; p < p1; ++p) {
        uintT e = epack[p];
        uintT g = H16[(size_t)(int)(e & 0xffffu) * 64 + lane];
        float wv = bf2f(e >> 16);
        floatx2 gf = __builtin_amdgcn_cvt_pk_f32_fp8((int)g, false);
        ax += wv * gf.x;
        ay += wv * gf.y;
    }
    uintT o = (uintT)f2bf(ax) | ((uintT)f2bf(ay) << 16);
    reinterpret_cast<uintT*>(Zb)[(size_t)node * 64 + lane] = o;
}

// ---- MFMA GEMM: Out = relu(Z @ W + b); single bf16 W; LDS union -----------
// phase1 (As+Ws chunks, 20KB) and epilogue Cs (33.8KB) share one buffer
// -> 34KB LDS -> 4 blocks/CU.
__global__ __launch_bounds__(256) void k_gemm(const ushortT* __restrict__ Zg,
                                              const ushortT* __restrict__ Whi,
                                              const float* __restrict__ Bias,
                                              void* __restrict__ OutV, int N,
                                              int outFp8) {
    __shared__ ushortT smem[128 * SC];  // 33792 B union
    ushortT* As = smem;                  // [128*SA]
    ushortT* Ws = smem + 128 * SA;       // [128*SA]
    ushortT* Cs = smem;                  // epilogue alias

    const int tid = threadIdx.x;
    const int wave = tid >> 6, lane = tid & 63;
    const int quad = lane >> 4, l15 = lane & 15;
    const int mBase = (wave >> 1) * 64, nBase = (wave & 1) * 64;
    const int row0 = blockIdx.x * 128;
    const int r = tid >> 1, half = tid & 1;

    floatx4 acc[4][4];
    const floatx4 zero4 = {0.f, 0.f, 0.f, 0.f};
#pragma unroll
    for (int i = 0; i < 4; i++)
#pragma unroll
        for (int j = 0; j < 4; j++) acc[i][j] = zero4;

    for (int ks = 0; ks < 4; ++ks) {
        {
            int grow = row0 + r;
            uint4 av0 = {0, 0, 0, 0}, av1 = {0, 0, 0, 0};
            if (grow < N) {
                const uint4* s = reinterpret_cast<const uint4*>(
                    Zg + (size_t)grow * CH + ks * 32 + half * 16);
                av0 = s[0]; av1 = s[1];
            }
            uint4* d = reinterpret_cast<uint4*>(&As[r * SA + half * 16]);
            d[0] = av0; d[1] = av1;
            const uint4* sh = reinterpret_cast<const uint4*>(Whi + r * CH + ks * 32 + half * 16);
            uint4* dh = reinterpret_cast<uint4*>(&Ws[r * SA + half * 16]);
            dh[0] = sh[0]; dh[1] = sh[1];
        }
        __syncthreads();

        short8 af[4], wf[4];
#pragma unroll
        for (int mt = 0; mt < 4; ++mt)
            af[mt] = *reinterpret_cast<const short8*>(&As[(mBase + mt * 16 + l15) * SA + quad * 8]);
#pragma unroll
        for (int nt = 0; nt < 4; ++nt)
            wf[nt] = *reinterpret_cast<const short8*>(&Ws[(nBase + nt * 16 + l15) * SA + quad * 8]);
#pragma unroll
        for (int mt = 0; mt < 4; ++mt)
#pragma unroll
            for (int nt = 0; nt < 4; ++nt)
                acc[mt][nt] = __builtin_amdgcn_mfma_f32_16x16x32_bf16(af[mt], wf[nt], acc[mt][nt], 0, 0, 0);
        __syncthreads();
    }

    float bb[4];
#pragma unroll
    for (int nt = 0; nt < 4; ++nt) bb[nt] = Bias[nBase + nt * 16 + l15];

    if (outFp8) {
        ucharT* Cs8 = reinterpret_cast<ucharT*>(Cs);
#pragma unroll
        for (int mt = 0; mt < 4; ++mt)
#pragma unroll
            for (int nt = 0; nt < 4; ++nt)
#pragma unroll
                for (int r4 = 0; r4 < 4; ++r4) {
                    int lrow = mBase + mt * 16 + quad * 4 + r4;
                    float v = fmaxf(acc[mt][nt][r4] + bb[nt], 0.f);
                    int f8 = __builtin_amdgcn_cvt_pk_fp8_f32(v, 0.f, 0, false);
                    Cs8[lrow * SC8 + nBase + nt * 16 + l15] = (ucharT)(f8 & 0xff);
                }
        __syncthreads();
        int grow = row0 + r;
        if (grow < N) {
            const uint4* s4 = reinterpret_cast<const uint4*>(&Cs8[r * SC8 + half * 64]);
            uint4* dst = reinterpret_cast<uint4*>((ucharT*)OutV + (size_t)grow * CH + half * 64);
#pragma unroll
            for (int q = 0; q < 4; ++q) dst[q] = s4[q];
        }
    } else {
        ushortT* Out = (ushortT*)OutV;
#pragma unroll
        for (int mt = 0; mt < 4; ++mt)
#pragma unroll
            for (int nt = 0; nt < 4; ++nt)
#pragma unroll
                for (int r4 = 0; r4 < 4; ++r4) {
                    int lrow = mBase + mt * 16 + quad * 4 + r4;
                    float v = fmaxf(acc[mt][nt][r4] + bb[nt], 0.f);
                    Cs[lrow * SC + nBase + nt * 16 + l15] = f2bf(v);
                }
        __syncthreads();
        int grow = row0 + r;
        if (grow < N) {
            const uint2* s = reinterpret_cast<const uint2*>(&Cs[r * SC + half * 64]);
            uint4* dst = reinterpret_cast<uint4*>(Out + (size_t)grow * CH + half * 64);
#pragma unroll
            for (int q = 0; q < 8; ++q) {
                uint2 a = s[2 * q], b = s[2 * q + 1];
                uint4 o = {a.x, a.y, b.x, b.y};
                dst[q] = o;
            }
        }
    }
}

// ---- fused FC2 + mean-pool: 8 lanes/node, 3-step shfl_xor reduce ----------
__global__ __launch_bounds__(256) void k_fc2pool(const ushortT* __restrict__ H,
                                                 const float* __restrict__ W2,
                                                 const float* __restrict__ B2,
                                                 const int* __restrict__ batch,
                                                 float* __restrict__ sums,
                                                 float* __restrict__ cnts, int N) {
    __shared__ float ls[192];  // [0..63]=sum0 [64..127]=sum1 [128..191]=cnt
    const int t = threadIdx.x;
    if (t < 192) ls[t] = 0.f;
    __syncthreads();
    const int wave = t >> 6, lane = t & 63;
    const int sub = lane & 7;
    const int ng = lane >> 3;

    float w0[16], w1[16];
#pragma unroll
    for (int i = 0; i < 16; ++i) {
        float2 wv = *reinterpret_cast<const float2*>(W2 + (sub * 16 + i) * 2);
        w0[i] = wv.x;
        w1[i] = wv.y;
    }
    const float b0 = B2[0], b1 = B2[1];

    const int nodeBase = blockIdx.x * 256 + wave * 64;
#pragma unroll
    for (int it = 0; it < 8; ++it) {
        int node = nodeBase + it * 8 + ng;
        float d0 = 0.f, d1 = 0.f;
        if (node < N) {
            const uint4* hp = reinterpret_cast<const uint4*>(H + (size_t)node * CH + sub * 16);
            uint4 a = hp[0], b = hp[1];
            uintT uu[8] = {a.x, a.y, a.z, a.w, b.x, b.y, b.z, b.w};
#pragma unroll
            for (int q = 0; q < 8; ++q) {
                float h0 = bf2f(uu[q] & 0xffffu);
                float h1 = bf2f(uu[q] >> 16);
                d0 += h0 * w0[2 * q] + h1 * w0[2 * q + 1];
                d1 += h0 * w1[2 * q] + h1 * w1[2 * q + 1];
            }
        }
#pragma unroll
        for (int m = 4; m >= 1; m >>= 1) {
            d0 += __shfl_xor(d0, m, 64);
            d1 += __shfl_xor(d1, m, 64);
        }
        if (sub == 0 && node < N) {
            int g = batch[node];
            atomicAdd(&ls[g], d0 + b0);
            atomicAdd(&ls[64 + g], d1 + b1);
            atomicAdd(&ls[128 + g], 1.0f);
        }
    }
    __syncthreads();
    if (t < 64) {
        float c = ls[128 + t];
        if (c != 0.f) {
            atomicAdd(&sums[2 * t], ls[t]);
            atomicAdd(&sums[2 * t + 1], ls[64 + t]);
            atomicAdd(&cnts[t], c);
        }
    }
}

__global__ void k_softmax(const float* __restrict__ sums, const float* __restrict__ cnts,
                          float* __restrict__ out, int G) {
    int g = blockIdx.x * blockDim.x + threadIdx.x;
    if (g < G) {
        float c = fmaxf(cnts[g], 1.0f);
        float p0 = sums[2 * g] / c;
        float p1 = sums[2 * g + 1] / c;
        float m = fmaxf(p0, p1);
        float e0 = expf(p0 - m), e1 = expf(p1 - m);
        float inv = 1.f / (e0 + e1);
        out[2 * g] = e0 * inv;
        out[2 * g + 1] = e1 * inv;
    }
}

// ---------------------------------------------------------------------------
extern "C" void kernel_launch(void* const* d_in, const int* in_sizes, int n_in,
                              void* d_out, int out_size, void* d_ws, size_t ws_size,
                              hipStream_t stream) {
    const float* X   = (const float*)d_in[0];
    const int* EI    = (const int*)d_in[1];
    const int* BATCH = (const int*)d_in[2];
    const float* W1  = (const float*)d_in[3];
    const float* B1  = (const float*)d_in[4];
    const float* W2  = (const float*)d_in[5];
    const float* B2  = (const float*)d_in[6];
    const float* W3  = (const float*)d_in[7];
    const float* B3  = (const float*)d_in[8];
    const float* FW1 = (const float*)d_in[9];
    const float* FB1 = (const float*)d_in[10];
    const float* FW2 = (const float*)d_in[11];
    const float* FB2 = (const float*)d_in[12];

    const int N = in_sizes[0] / CH;
    const int E = in_sizes[1] / 2;
    const int G = out_size / 2;
    const int* rowp = EI;
    const int* colp = EI + E;
    const int NB = (N + 127) >> BSH;

    char* w = (char*)d_ws;
    auto alloc = [&](size_t bytes) -> char* {
        char* p = w;
        w += (bytes + 255) & ~(size_t)255;
        return p;
    };
    ushortT* Zb    = (ushortT*)alloc((size_t)N * CH * 2);   // bf16 Z / Z4
    ushortT* Hb16  = (ushortT*)alloc((size_t)N * CH * 2);   // bf16 H3
    ucharT*  Hb8   = (ucharT*)alloc((size_t)N * CH);        // fp8 H1/H2
    ucharT*  Xb8   = (ucharT*)alloc((size_t)N * CH);        // fp8 X
    ushortT* WhiA  = (ushortT*)alloc((size_t)4 * 16384 * 2);
    float* invs    = (float*)alloc((size_t)N * 4);
    int*   indptr  = (int*)alloc((size_t)(N + 1) * 4);
    uintT* epack   = (uintT*)alloc((size_t)E * 4);
    uintT* seg     = (uintT*)alloc((size_t)NB * SEG * 4);
    int*   bfill   = (int*)alloc((size_t)NB * 4);
    int*   bbase   = (int*)alloc((size_t)NB * 4);
    float* sums    = (float*)alloc((size_t)G * 3 * 4);      // sums | cnts
    float* cnts    = sums + 2 * G;

    const int nbAgg  = (N + 3) / 4;
    const int nbGemm = (N + 127) / 128;
    const int nbBin  = (E + EPW - 1) / EPW;
    const int nbPool = (N + 255) / 256;
    const int total4 = N * CH / 4;
    const int nbSP   = NB + 256 + (total4 + 255) / 256;

    k_zero<<<1, 256, 0, stream>>>(bfill, NB, sums, 3 * G);
    k_bin<<<nbBin, 256, 0, stream>>>(rowp, colp, bfill, seg, E, NB);
    k_binvs_bscan<<<NB + 1, 512, 0, stream>>>(bfill, seg, invs, bbase, indptr, NB, N, E);
    k_scatterprep<<<nbSP, 256, 0, stream>>>(bfill, bbase, seg, invs, indptr, epack,
                                            X, Xb8, W1, W2, W3, FW1, WhiA, N, NB, total4);

    // layer 1
    k_agg<<<nbAgg, 256, 0, stream>>>(Xb8, epack, indptr, invs, Zb, N);
    k_gemm<<<nbGemm, 256, 0, stream>>>(Zb, WhiA, B1, Hb8, N, 1);
    // layer 2
    k_agg<<<nbAgg, 256, 0, stream>>>(Hb8, epack, indptr, invs, Zb, N);
    k_gemm<<<nbGemm, 256, 0, stream>>>(Zb, WhiA + 16384, B2, Hb8, N, 1);
    // layer 3 (bf16 out -> FC1 A-operand)
    k_agg<<<nbAgg, 256, 0, stream>>>(Hb8, epack, indptr, invs, Zb, N);
    k_gemm<<<nbGemm, 256, 0, stream>>>(Zb, WhiA + 2 * 16384, B3, Hb16, N, 0);
    // FC1 (bf16 out -> fc2pool)
    k_gemm<<<nbGemm, 256, 0, stream>>>(Hb16, WhiA + 3 * 16384, FB1, Zb, N, 0);
    // FC2 + pool, then softmax
    k_fc2pool<<<nbPool, 256, 0, stream>>>(Zb, FW2, FB2, BATCH, sums, cnts, N);
    k_softmax<<<1, 64, 0, stream>>>(sums, cnts, (float*)d_out, G);
}

// Round 10
// 228.038 us; speedup vs baseline: 1.8144x; 1.1085x over previous
//
#include <hip/hip_runtime.h>

// ---------------------------------------------------------------------------
// colorableGNN: 3x GCN(128->128) + FC(128->128) + FC(128->2) + mean-pool + softmax
// R9 (deltas vs R8): (1) Z link between agg and GEMM stored fp8 (GEMM stages
// fp8->bf16, exact in bf16, saves ~38MB round-trip); (2) k_agg processes 4
// nodes/wave (16 lanes x 8ch) -> 4 independent edge streams, ~4x gather MLP.
// Weights single bf16; fp32 accumulate. CSR via bucketed counting sort.
// NOTE: gather kernels need occupancy; never fuse agg into GEMM (R7: 104us).
// ---------------------------------------------------------------------------

#define CH 128
#define BSH 7              // 128 dst nodes per bucket
#define SEG 4096           // segment capacity (records) per bucket
#define EPW 4096           // edges per phase-1 workgroup
#define SA 40              // LDS stride for A/W chunks (shorts)
#define SC 132             // bf16 epilogue stride (shorts)
#define SC8 144            // fp8 epilogue stride (bytes)

typedef unsigned short ushortT;
typedef unsigned int uintT;
typedef unsigned char ucharT;
typedef __attribute__((ext_vector_type(8))) short short8;
typedef __attribute__((ext_vector_type(4))) float floatx4;
typedef __attribute__((ext_vector_type(2))) float floatx2;

__device__ __forceinline__ float bf2f(uintT u) {
    return __uint_as_float(u << 16);
}
__device__ __forceinline__ ushortT f2bf(float f) {
    uintT x = __float_as_uint(f);
    return (ushortT)((x + 0x7fffu + ((x >> 16) & 1u)) >> 16);
}
__device__ __forceinline__ void dec4(uintT u, float* o) {
    floatx2 lo = __builtin_amdgcn_cvt_pk_f32_fp8((int)u, false);
    floatx2 hi = __builtin_amdgcn_cvt_pk_f32_fp8((int)u, true);
    o[0] = lo.x; o[1] = lo.y; o[2] = hi.x; o[3] = hi.y;
}

// ---- zero bfill + pooling accumulators ------------------------------------
__global__ void k_zero(int* __restrict__ bfill, int NB, float* __restrict__ acc, int nacc) {
    int t = threadIdx.x;
    for (int i = t; i < NB; i += 256) bfill[i] = 0;
    for (int i = t; i < nacc; i += 256) acc[i] = 0.f;
}

// ---- phase 1: bin edges into dst-buckets; records packed src|(dst<<16) ----
__global__ __launch_bounds__(256) void k_bin(const int* __restrict__ row,
                                             const int* __restrict__ col,
                                             int* __restrict__ bfill,
                                             uintT* __restrict__ seg,
                                             int E, int NB) {
    __shared__ uintT staged[EPW];   // 16 KB
    __shared__ int target[EPW];     // 16 KB
    __shared__ int sval[512];
    __shared__ int horig[512];
    __shared__ int pcnt[512];
    __shared__ int gbase[512];
    const int t = threadIdx.x;
    const int e0 = blockIdx.x * EPW;
    const int cnt = min(EPW, E - e0);

    sval[t] = 0; sval[t + 256] = 0;
    __syncthreads();

    int er[16], ec[16];
#pragma unroll
    for (int i = 0; i < 16; ++i) {
        int le = i * 256 + t;
        if (le < cnt) {
            er[i] = row[e0 + le];
            ec[i] = col[e0 + le];
            atomicAdd(&sval[ec[i] >> BSH], 1);
        }
    }
    __syncthreads();
    horig[t] = sval[t]; horig[t + 256] = sval[t + 256];
    __syncthreads();
    for (int off = 1; off < 512; off <<= 1) {
        int a = (t >= off) ? sval[t - off] : 0;
        int b2 = sval[t + 256 - off];
        __syncthreads();
        sval[t] += a;
        sval[t + 256] += b2;
        __syncthreads();
    }
    for (int b = t; b < 512; b += 256) {
        int h = horig[b];
        pcnt[b] = sval[b] - h;
        gbase[b] = (h > 0 && b < NB) ? atomicAdd(&bfill[b], h) : 0;
    }
    __syncthreads();
#pragma unroll
    for (int i = 0; i < 16; ++i) {
        int le = i * 256 + t;
        if (le < cnt) {
            int b = ec[i] >> BSH;
            int j = atomicAdd(&pcnt[b], 1);
            staged[j] = (uintT)er[i] | ((uintT)ec[i] << 16);
            int lo = sval[b] - horig[b];
            target[j] = b * SEG + gbase[b] + (j - lo);
        }
    }
    __syncthreads();
    for (int s = t; s < cnt; s += 256) seg[target[s]] = staged[s];
}

// ---- fused: per-bucket degree->invs (blocks 0..NB-1) + bucket scan (NB) ---
__global__ __launch_bounds__(512) void k_binvs_bscan(const int* __restrict__ bfill,
                                                     const uintT* __restrict__ seg,
                                                     float* __restrict__ invs,
                                                     int* __restrict__ bbase,
                                                     int* __restrict__ indptr,
                                                     int NB, int N, int E) {
    const int b = blockIdx.x;
    const int t = threadIdx.x;
    if (b < NB) {
        __shared__ int h[128];
        if (t < 128) h[t] = 0;
        __syncthreads();
        int cnt = bfill[b];
        const uintT* sp = seg + (size_t)b * SEG;
        for (int s = t; s < cnt; s += 512) atomicAdd(&h[(sp[s] >> 16) & 127], 1);
        __syncthreads();
        int d = b * 128 + t;
        if (t < 128 && d < N) invs[d] = rsqrtf((float)h[t] + 1.0f);
    } else {
        __shared__ int s[512];
        int v = (t < NB) ? bfill[t] : 0;
        s[t] = v;
        __syncthreads();
        for (int off = 1; off < 512; off <<= 1) {
            int a = (t >= off) ? s[t - off] : 0;
            __syncthreads();
            s[t] += a;
            __syncthreads();
        }
        if (t < NB) bbase[t] = s[t] - v;  // exclusive
        if (t == 0) indptr[N] = E;
    }
}

// ---- heterogeneous: CSR scatter | weight prep | X->fp8 --------------------
__global__ __launch_bounds__(256) void k_scatterprep(const int* __restrict__ bfill,
                                                     const int* __restrict__ bbase,
                                                     const uintT* __restrict__ seg,
                                                     const float* __restrict__ invs,
                                                     int* __restrict__ indptr,
                                                     uintT* __restrict__ epack,
                                                     const float* __restrict__ X,
                                                     ucharT* __restrict__ Xb,
                                                     const float* __restrict__ w0,
                                                     const float* __restrict__ w1,
                                                     const float* __restrict__ w2,
                                                     const float* __restrict__ w3,
                                                     ushortT* __restrict__ Whi,
                                                     int N, int NB, int total4) {
    const int t = threadIdx.x;
    if ((int)blockIdx.x < NB) {
        __shared__ uintT staged[SEG];   // 16 KB
        __shared__ int h[128];
        __shared__ int sc[128];
        __shared__ int pc[128];
        const int b = blockIdx.x;
        const int cnt = bfill[b];
        const int base = bbase[b];
        const uintT* sp = seg + (size_t)b * SEG;

        if (t < 128) h[t] = 0;
        __syncthreads();
        for (int s = t; s < cnt; s += 256) atomicAdd(&h[(sp[s] >> 16) & 127], 1);
        __syncthreads();
        if (t < 128) sc[t] = h[t];
        __syncthreads();
        for (int off = 1; off < 128; off <<= 1) {
            int a = (t >= off && t < 128) ? sc[t - off] : 0;
            __syncthreads();
            if (t < 128) sc[t] += a;
            __syncthreads();
        }
        if (t < 128) {
            int excl = sc[t] - h[t];
            pc[t] = excl;
            int d = b * 128 + t;
            if (d < N) indptr[d] = base + excl;
        }
        __syncthreads();
        for (int s = t; s < cnt; s += 256) {
            uintT rc = sp[s];
            int src = (int)(rc & 0xffffu), dst = (int)(rc >> 16);
            int j = atomicAdd(&pc[dst & 127], 1);
            float nrm = invs[src] * invs[dst];
            staged[j] = (uintT)src | ((uintT)f2bf(nrm) << 16);
        }
        __syncthreads();
        for (int s = t; s < cnt; s += 256) epack[base + s] = staged[s];
    } else if ((int)blockIdx.x < NB + 256) {
        int idx = (blockIdx.x - NB) * 256 + t;  // 0..65535
        int m = idx >> 14;
        int r = idx & 16383;
        int n = r >> 7;
        int k = r & 127;
        const float* W = (m == 0) ? w0 : (m == 1) ? w1 : (m == 2) ? w2 : w3;
        Whi[m * 16384 + n * CH + k] = f2bf(W[k * CH + n]);
    } else {
        int i = (blockIdx.x - NB - 256) * 256 + t;
        if (i < total4) {
            float4 v = reinterpret_cast<const float4*>(X)[i];
            int r0 = __builtin_amdgcn_cvt_pk_fp8_f32(v.x, v.y, 0, false);
            int r1 = __builtin_amdgcn_cvt_pk_fp8_f32(v.z, v.w, r0, true);
            reinterpret_cast<int*>(Xb)[i] = r1;
        }
    }
}

// ---- aggregation: 4 nodes/wave (16 lanes x 8ch), fp8 in, fp8 out ----------
// 4 independent edge streams per wave -> ~32 outstanding gathers.
__global__ __launch_bounds__(256) void k_agg(const ucharT* __restrict__ H8,
                                             const uintT* __restrict__ epack,
                                             const int* __restrict__ indptr,
                                             const float* __restrict__ invs,
                                             ucharT* __restrict__ Z8, int N) {
    const int wave = threadIdx.x >> 6, lane = threadIdx.x & 63;
    const int sub = lane >> 4;          // node slot within wave: 0..3
    const int l = lane & 15;            // channel group: 8 channels
    const int node = blockIdx.x * 16 + wave * 4 + sub;
    if (node >= N) return;

    const uint2* H2 = reinterpret_cast<const uint2*>(H8);

    float acc[8];
    {
        float sn = invs[node];
        float sn2 = sn * sn;
        uint2 h = H2[(size_t)node * 16 + l];
        float d[8];
        dec4(h.x, d); dec4(h.y, d + 4);
#pragma unroll
        for (int j = 0; j < 8; ++j) acc[j] = sn2 * d[j];
    }

    int p = indptr[node];
    int p1 = indptr[node + 1];
    for (; p + 8 <= p1; p += 8) {
        uintT e[8];
#pragma unroll
        for (int i = 0; i < 8; ++i) e[i] = epack[p + i];
        uint2 g[8];
#pragma unroll
        for (int i = 0; i < 8; ++i) g[i] = H2[(size_t)(int)(e[i] & 0xffffu) * 16 + l];
#pragma unroll
        for (int i = 0; i < 8; ++i) {
            float wv = bf2f(e[i] >> 16);
            float d[8];
            dec4(g[i].x, d); dec4(g[i].y, d + 4);
#pragma unroll
            for (int j = 0; j < 8; ++j) acc[j] += wv * d[j];
        }
    }
    if (p + 4 <= p1) {
        uintT e[4];
#pragma unroll
        for (int i = 0; i < 4; ++i) e[i] = epack[p + i];
        uint2 g[4];
#pragma unroll
        for (int i = 0; i < 4; ++i) g[i] = H2[(size_t)(int)(e[i] & 0xffffu) * 16 + l];
#pragma unroll
        for (int i = 0; i < 4; ++i) {
            float wv = bf2f(e[i] >> 16);
            float d[8];
            dec4(g[i].x, d); dec4(g[i].y, d + 4);
#pragma unroll
            for (int j = 0; j < 8; ++j) acc[j] += wv * d[j];
        }
        p += 4;
    }
    for (; p < p1; ++p) {
        uintT e = epack[p];
        uint2 g = H2[(size_t)(int)(e & 0xffffu) * 16 + l];
        float wv = bf2f(e >> 16);
        float d[8];
        dec4(g.x, d); dec4(g.y, d + 4);
#pragma unroll
        for (int j = 0; j < 8; ++j) acc[j] += wv * d[j];
    }

    uint2 o;
    {
        int r0 = __builtin_amdgcn_cvt_pk_fp8_f32(acc[0], acc[1], 0, false);
        r0 = __builtin_amdgcn_cvt_pk_fp8_f32(acc[2], acc[3], r0, true);
        int r1 = __builtin_amdgcn_cvt_pk_fp8_f32(acc[4], acc[5], 0, false);
        r1 = __builtin_amdgcn_cvt_pk_fp8_f32(acc[6], acc[7], r1, true);
        o.x = (uintT)r0; o.y = (uintT)r1;
    }
    reinterpret_cast<uint2*>(Z8)[(size_t)node * 16 + l] = o;
}

// ---- MFMA GEMM: Out = relu(In @ W + b); In bf16 or fp8; single bf16 W -----
// LDS union (As+Ws phase / Cs epilogue) = 33792B -> 4 blocks/CU.
__global__ __launch_bounds__(256) void k_gemm(const void* __restrict__ InV,
                                              const ushortT* __restrict__ Whi,
                                              const float* __restrict__ Bias,
                                              void* __restrict__ OutV, int N,
                                              int inFp8, int outFp8) {
    __shared__ ushortT smem[128 * SC];  // 33792 B union
    ushortT* As = smem;                  // [128*SA]
    ushortT* Ws = smem + 128 * SA;       // [128*SA]
    ushortT* Cs = smem;                  // epilogue alias

    const int tid = threadIdx.x;
    const int wave = tid >> 6, lane = tid & 63;
    const int quad = lane >> 4, l15 = lane & 15;
    const int mBase = (wave >> 1) * 64, nBase = (wave & 1) * 64;
    const int row0 = blockIdx.x * 128;
    const int r = tid >> 1, half = tid & 1;

    floatx4 acc[4][4];
    const floatx4 zero4 = {0.f, 0.f, 0.f, 0.f};
#pragma unroll
    for (int i = 0; i < 4; i++)
#pragma unroll
        for (int j = 0; j < 4; j++) acc[i][j] = zero4;

    for (int ks = 0; ks < 4; ++ks) {
        {
            int grow = row0 + r;
            if (inFp8) {
                uint4 a8 = {0, 0, 0, 0};
                if (grow < N)
                    a8 = *reinterpret_cast<const uint4*>(
                        (const ucharT*)InV + (size_t)grow * CH + ks * 32 + half * 16);
                uintT wds[4] = {a8.x, a8.y, a8.z, a8.w};
                uintT ob[8];
#pragma unroll
                for (int q = 0; q < 4; ++q) {
                    float d[4];
                    dec4(wds[q], d);
                    ob[2 * q] = (uintT)f2bf(d[0]) | ((uintT)f2bf(d[1]) << 16);
                    ob[2 * q + 1] = (uintT)f2bf(d[2]) | ((uintT)f2bf(d[3]) << 16);
                }
                uint4* dd = reinterpret_cast<uint4*>(&As[r * SA + half * 16]);
                dd[0] = uint4{ob[0], ob[1], ob[2], ob[3]};
                dd[1] = uint4{ob[4], ob[5], ob[6], ob[7]};
            } else {
                uint4 av0 = {0, 0, 0, 0}, av1 = {0, 0, 0, 0};
                if (grow < N) {
                    const uint4* s = reinterpret_cast<const uint4*>(
                        (const ushortT*)InV + (size_t)grow * CH + ks * 32 + half * 16);
                    av0 = s[0]; av1 = s[1];
                }
                uint4* d = reinterpret_cast<uint4*>(&As[r * SA + half * 16]);
                d[0] = av0; d[1] = av1;
            }
            const uint4* sh = reinterpret_cast<const uint4*>(Whi + r * CH + ks * 32 + half * 16);
            uint4* dh = reinterpret_cast<uint4*>(&Ws[r * SA + half * 16]);
            dh[0] = sh[0]; dh[1] = sh[1];
        }
        __syncthreads();

        short8 af[4], wf[4];
#pragma unroll
        for (int mt = 0; mt < 4; ++mt)
            af[mt] = *reinterpret_cast<const short8*>(&As[(mBase + mt * 16 + l15) * SA + quad * 8]);
#pragma unroll
        for (int nt = 0; nt < 4; ++nt)
            wf[nt] = *reinterpret_cast<const short8*>(&Ws[(nBase + nt * 16 + l15) * SA + quad * 8]);
#pragma unroll
        for (int mt = 0; mt < 4; ++mt)
#pragma unroll
            for (int nt = 0; nt < 4; ++nt)
                acc[mt][nt] = __builtin_amdgcn_mfma_f32_16x16x32_bf16(af[mt], wf[nt], acc[mt][nt], 0, 0, 0);
        __syncthreads();
    }

    float bb[4];
#pragma unroll
    for (int nt = 0; nt < 4; ++nt) bb[nt] = Bias[nBase + nt * 16 + l15];

    if (outFp8) {
        ucharT* Cs8 = reinterpret_cast<ucharT*>(Cs);
#pragma unroll
        for (int mt = 0; mt < 4; ++mt)
#pragma unroll
            for (int nt = 0; nt < 4; ++nt)
#pragma unroll
                for (int r4 = 0; r4 < 4; ++r4) {
                    int lrow = mBase + mt * 16 + quad * 4 + r4;
                    float v = fmaxf(acc[mt][nt][r4] + bb[nt], 0.f);
                    int f8 = __builtin_amdgcn_cvt_pk_fp8_f32(v, 0.f, 0, false);
                    Cs8[lrow * SC8 + nBase + nt * 16 + l15] = (ucharT)(f8 & 0xff);
                }
        __syncthreads();
        int grow = row0 + r;
        if (grow < N) {
            const uint4* s4 = reinterpret_cast<const uint4*>(&Cs8[r * SC8 + half * 64]);
            uint4* dst = reinterpret_cast<uint4*>((ucharT*)OutV + (size_t)grow * CH + half * 64);
#pragma unroll
            for (int q = 0; q < 4; ++q) dst[q] = s4[q];
        }
    } else {
        ushortT* Out = (ushortT*)OutV;
#pragma unroll
        for (int mt = 0; mt < 4; ++mt)
#pragma unroll
            for (int nt = 0; nt < 4; ++nt)
#pragma unroll
                for (int r4 = 0; r4 < 4; ++r4) {
                    int lrow = mBase + mt * 16 + quad * 4 + r4;
                    float v = fmaxf(acc[mt][nt][r4] + bb[nt], 0.f);
                    Cs[lrow * SC + nBase + nt * 16 + l15] = f2bf(v);
                }
        __syncthreads();
        int grow = row0 + r;
        if (grow < N) {
            const uint2* s = reinterpret_cast<const uint2*>(&Cs[r * SC + half * 64]);
            uint4* dst = reinterpret_cast<uint4*>(Out + (size_t)grow * CH + half * 64);
#pragma unroll
            for (int q = 0; q < 8; ++q) {
                uint2 a = s[2 * q], b = s[2 * q + 1];
                uint4 o = {a.x, a.y, b.x, b.y};
                dst[q] = o;
            }
        }
    }
}

// ---- fused FC2 + mean-pool: 8 lanes/node, 3-step shfl_xor reduce ----------
__global__ __launch_bounds__(256) void k_fc2pool(const ushortT* __restrict__ H,
                                                 const float* __restrict__ W2,
                                                 const float* __restrict__ B2,
                                                 const int* __restrict__ batch,
                                                 float* __restrict__ sums,
                                                 float* __restrict__ cnts, int N) {
    __shared__ float ls[192];
    const int t = threadIdx.x;
    if (t < 192) ls[t] = 0.f;
    __syncthreads();
    const int wave = t >> 6, lane = t & 63;
    const int sub = lane & 7;
    const int ng = lane >> 3;

    float w0[16], w1[16];
#pragma unroll
    for (int i = 0; i < 16; ++i) {
        float2 wv = *reinterpret_cast<const float2*>(W2 + (sub * 16 + i) * 2);
        w0[i] = wv.x;
        w1[i] = wv.y;
    }
    const float b0 = B2[0], b1 = B2[1];

    const int nodeBase = blockIdx.x * 256 + wave * 64;
#pragma unroll
    for (int it = 0; it < 8; ++it) {
        int node = nodeBase + it * 8 + ng;
        float d0 = 0.f, d1 = 0.f;
        if (node < N) {
            const uint4* hp = reinterpret_cast<const uint4*>(H + (size_t)node * CH + sub * 16);
            uint4 a = hp[0], b = hp[1];
            uintT uu[8] = {a.x, a.y, a.z, a.w, b.x, b.y, b.z, b.w};
#pragma unroll
            for (int q = 0; q < 8; ++q) {
                float h0 = bf2f(uu[q] & 0xffffu);
                float h1 = bf2f(uu[q] >> 16);
                d0 += h0 * w0[2 * q] + h1 * w0[2 * q + 1];
                d1 += h0 * w1[2 * q] + h1 * w1[2 * q + 1];
            }
        }
#pragma unroll
        for (int m = 4; m >= 1; m >>= 1) {
            d0 += __shfl_xor(d0, m, 64);
            d1 += __shfl_xor(d1, m, 64);
        }
        if (sub == 0 && node < N) {
            int g = batch[node];
            atomicAdd(&ls[g], d0 + b0);
            atomicAdd(&ls[64 + g], d1 + b1);
            atomicAdd(&ls[128 + g], 1.0f);
        }
    }
    __syncthreads();
    if (t < 64) {
        float c = ls[128 + t];
        if (c != 0.f) {
            atomicAdd(&sums[2 * t], ls[t]);
            atomicAdd(&sums[2 * t + 1], ls[64 + t]);
            atomicAdd(&cnts[t], c);
        }
    }
}

__global__ void k_softmax(const float* __restrict__ sums, const float* __restrict__ cnts,
                          float* __restrict__ out, int G) {
    int g = blockIdx.x * blockDim.x + threadIdx.x;
    if (g < G) {
        float c = fmaxf(cnts[g], 1.0f);
        float p0 = sums[2 * g] / c;
        float p1 = sums[2 * g + 1] / c;
        float m = fmaxf(p0, p1);
        float e0 = expf(p0 - m), e1 = expf(p1 - m);
        float inv = 1.f / (e0 + e1);
        out[2 * g] = e0 * inv;
        out[2 * g + 1] = e1 * inv;
    }
}

// ---------------------------------------------------------------------------
extern "C" void kernel_launch(void* const* d_in, const int* in_sizes, int n_in,
                              void* d_out, int out_size, void* d_ws, size_t ws_size,
                              hipStream_t stream) {
    const float* X   = (const float*)d_in[0];
    const int* EI    = (const int*)d_in[1];
    const int* BATCH = (const int*)d_in[2];
    const float* W1  = (const float*)d_in[3];
    const float* B1  = (const float*)d_in[4];
    const float* W2  = (const float*)d_in[5];
    const float* B2  = (const float*)d_in[6];
    const float* W3  = (const float*)d_in[7];
    const float* B3  = (const float*)d_in[8];
    const float* FW1 = (const float*)d_in[9];
    const float* FB1 = (const float*)d_in[10];
    const float* FW2 = (const float*)d_in[11];
    const float* FB2 = (const float*)d_in[12];

    const int N = in_sizes[0] / CH;
    const int E = in_sizes[1] / 2;
    const int G = out_size / 2;
    const int* rowp = EI;
    const int* colp = EI + E;
    const int NB = (N + 127) >> BSH;

    char* w = (char*)d_ws;
    auto alloc = [&](size_t bytes) -> char* {
        char* p = w;
        w += (bytes + 255) & ~(size_t)255;
        return p;
    };
    ushortT* Zb    = (ushortT*)alloc((size_t)N * CH * 2);   // bf16 Z4 (FC1 out)
    ushortT* Hb16  = (ushortT*)alloc((size_t)N * CH * 2);   // bf16 H3
    ucharT*  Z8    = (ucharT*)alloc((size_t)N * CH);        // fp8 Z (agg out)
    ucharT*  Hb8   = (ucharT*)alloc((size_t)N * CH);        // fp8 H1/H2
    ucharT*  Xb8   = (ucharT*)alloc((size_t)N * CH);        // fp8 X
    ushortT* WhiA  = (ushortT*)alloc((size_t)4 * 16384 * 2);
    float* invs    = (float*)alloc((size_t)N * 4);
    int*   indptr  = (int*)alloc((size_t)(N + 1) * 4);
    uintT* epack   = (uintT*)alloc((size_t)E * 4);
    uintT* seg     = (uintT*)alloc((size_t)NB * SEG * 4);
    int*   bfill   = (int*)alloc((size_t)NB * 4);
    int*   bbase   = (int*)alloc((size_t)NB * 4);
    float* sums    = (float*)alloc((size_t)G * 3 * 4);      // sums | cnts
    float* cnts    = sums + 2 * G;

    const int nbAgg  = (N + 15) / 16;
    const int nbGemm = (N + 127) / 128;
    const int nbBin  = (E + EPW - 1) / EPW;
    const int nbPool = (N + 255) / 256;
    const int total4 = N * CH / 4;
    const int nbSP   = NB + 256 + (total4 + 255) / 256;

    k_zero<<<1, 256, 0, stream>>>(bfill, NB, sums, 3 * G);
    k_bin<<<nbBin, 256, 0, stream>>>(rowp, colp, bfill, seg, E, NB);
    k_binvs_bscan<<<NB + 1, 512, 0, stream>>>(bfill, seg, invs, bbase, indptr, NB, N, E);
    k_scatterprep<<<nbSP, 256, 0, stream>>>(bfill, bbase, seg, invs, indptr, epack,
                                            X, Xb8, W1, W2, W3, FW1, WhiA, N, NB, total4);

    // layer 1
    k_agg<<<nbAgg, 256, 0, stream>>>(Xb8, epack, indptr, invs, Z8, N);
    k_gemm<<<nbGemm, 256, 0, stream>>>(Z8, WhiA, B1, Hb8, N, 1, 1);
    // layer 2
    k_agg<<<nbAgg, 256, 0, stream>>>(Hb8, epack, indptr, invs, Z8, N);
    k_gemm<<<nbGemm, 256, 0, stream>>>(Z8, WhiA + 16384, B2, Hb8, N, 1, 1);
    // layer 3 (bf16 out -> FC1 A-operand)
    k_agg<<<nbAgg, 256, 0, stream>>>(Hb8, epack, indptr, invs, Z8, N);
    k_gemm<<<nbGemm, 256, 0, stream>>>(Z8, WhiA + 2 * 16384, B3, Hb16, N, 1, 0);
    // FC1 (bf16 in, bf16 out -> fc2pool)
    k_gemm<<<nbGemm, 256, 0, stream>>>(Hb16, WhiA + 3 * 16384, FB1, Zb, N, 0, 0);
    // FC2 + pool, then softmax
    k_fc2pool<<<nbPool, 256, 0, stream>>>(Zb, FW2, FB2, BATCH, sums, cnts, N);
    k_softmax<<<1, 64, 0, stream>>>(sums, cnts, (float*)d_out, G);
}

// Round 12
// 211.720 us; speedup vs baseline: 1.9542x; 1.0771x over previous
//
#include <hip/hip_runtime.h>

// ---------------------------------------------------------------------------
// colorableGNN: 3x GCN(128->128) + FC(128->128) + FC(128->2) + mean-pool + softmax
// R11: R10 structure with the k_tail staging bug fixed (R10 staged only 32B
// of each 64B half-row -> channels 32..63 & 96..127 were stale LDS garbage
// -> saturated softmax, absmax 0.51). Now 4x uint4 loads = full row staged.
// k_tail fuses GEMM(W3) -> relu -> GEMM(FW1) -> FC2 -> mean-pool; H3/Z4
// never in HBM. fp8 activations+Z, 4B edge records, bf16 weights, fp32 acc.
// NOTE: gather kernels need occupancy; never fuse agg into GEMM (R7: 104us).
// ---------------------------------------------------------------------------

#define CH 128
#define BSH 7              // 128 dst nodes per bucket
#define SEG 4096           // segment capacity (records) per bucket
#define EPW 4096           // edges per phase-1 workgroup
#define SA 40              // LDS stride for W chunks (shorts)
#define SAF 136            // LDS stride full-K A tile (shorts; 272B = 17*16B)
#define SC 132             // bf16 epilogue stride (shorts)
#define SC8 144            // fp8 epilogue stride (bytes)

typedef unsigned short ushortT;
typedef unsigned int uintT;
typedef unsigned char ucharT;
typedef __attribute__((ext_vector_type(8))) short short8;
typedef __attribute__((ext_vector_type(4))) float floatx4;
typedef __attribute__((ext_vector_type(2))) float floatx2;

__device__ __forceinline__ float bf2f(uintT u) {
    return __uint_as_float(u << 16);
}
__device__ __forceinline__ ushortT f2bf(float f) {
    uintT x = __float_as_uint(f);
    return (ushortT)((x + 0x7fffu + ((x >> 16) & 1u)) >> 16);
}
__device__ __forceinline__ void dec4(uintT u, float* o) {
    floatx2 lo = __builtin_amdgcn_cvt_pk_f32_fp8((int)u, false);
    floatx2 hi = __builtin_amdgcn_cvt_pk_f32_fp8((int)u, true);
    o[0] = lo.x; o[1] = lo.y; o[2] = hi.x; o[3] = hi.y;
}

// ---- zero bfill + pooling accumulators ------------------------------------
__global__ void k_zero(int* __restrict__ bfill, int NB, float* __restrict__ acc, int nacc) {
    int t = threadIdx.x;
    for (int i = t; i < NB; i += 256) bfill[i] = 0;
    for (int i = t; i < nacc; i += 256) acc[i] = 0.f;
}

// ---- phase 1: bin edges into dst-buckets; records packed src|(dst<<16) ----
__global__ __launch_bounds__(256) void k_bin(const int* __restrict__ row,
                                             const int* __restrict__ col,
                                             int* __restrict__ bfill,
                                             uintT* __restrict__ seg,
                                             int E, int NB) {
    __shared__ uintT staged[EPW];   // 16 KB
    __shared__ int target[EPW];     // 16 KB
    __shared__ int sval[512];
    __shared__ int horig[512];
    __shared__ int pcnt[512];
    __shared__ int gbase[512];
    const int t = threadIdx.x;
    const int e0 = blockIdx.x * EPW;
    const int cnt = min(EPW, E - e0);

    sval[t] = 0; sval[t + 256] = 0;
    __syncthreads();

    int er[16], ec[16];
#pragma unroll
    for (int i = 0; i < 16; ++i) {
        int le = i * 256 + t;
        if (le < cnt) {
            er[i] = row[e0 + le];
            ec[i] = col[e0 + le];
            atomicAdd(&sval[ec[i] >> BSH], 1);
        }
    }
    __syncthreads();
    horig[t] = sval[t]; horig[t + 256] = sval[t + 256];
    __syncthreads();
    for (int off = 1; off < 512; off <<= 1) {
        int a = (t >= off) ? sval[t - off] : 0;
        int b2 = sval[t + 256 - off];
        __syncthreads();
        sval[t] += a;
        sval[t + 256] += b2;
        __syncthreads();
    }
    for (int b = t; b < 512; b += 256) {
        int h = horig[b];
        pcnt[b] = sval[b] - h;
        gbase[b] = (h > 0 && b < NB) ? atomicAdd(&bfill[b], h) : 0;
    }
    __syncthreads();
#pragma unroll
    for (int i = 0; i < 16; ++i) {
        int le = i * 256 + t;
        if (le < cnt) {
            int b = ec[i] >> BSH;
            int j = atomicAdd(&pcnt[b], 1);
            staged[j] = (uintT)er[i] | ((uintT)ec[i] << 16);
            int lo = sval[b] - horig[b];
            target[j] = b * SEG + gbase[b] + (j - lo);
        }
    }
    __syncthreads();
    for (int s = t; s < cnt; s += 256) seg[target[s]] = staged[s];
}

// ---- fused: per-bucket degree->invs (blocks 0..NB-1) + bucket scan (NB) ---
__global__ __launch_bounds__(512) void k_binvs_bscan(const int* __restrict__ bfill,
                                                     const uintT* __restrict__ seg,
                                                     float* __restrict__ invs,
                                                     int* __restrict__ bbase,
                                                     int* __restrict__ indptr,
                                                     int NB, int N, int E) {
    const int b = blockIdx.x;
    const int t = threadIdx.x;
    if (b < NB) {
        __shared__ int h[128];
        if (t < 128) h[t] = 0;
        __syncthreads();
        int cnt = bfill[b];
        const uintT* sp = seg + (size_t)b * SEG;
        for (int s = t; s < cnt; s += 512) atomicAdd(&h[(sp[s] >> 16) & 127], 1);
        __syncthreads();
        int d = b * 128 + t;
        if (t < 128 && d < N) invs[d] = rsqrtf((float)h[t] + 1.0f);
    } else {
        __shared__ int s[512];
        int v = (t < NB) ? bfill[t] : 0;
        s[t] = v;
        __syncthreads();
        for (int off = 1; off < 512; off <<= 1) {
            int a = (t >= off) ? s[t - off] : 0;
            __syncthreads();
            s[t] += a;
            __syncthreads();
        }
        if (t < NB) bbase[t] = s[t] - v;  // exclusive
        if (t == 0) indptr[N] = E;
    }
}

// ---- heterogeneous: CSR scatter | weight prep | X->fp8 --------------------
__global__ __launch_bounds__(256) void k_scatterprep(const int* __restrict__ bfill,
                                                     const int* __restrict__ bbase,
                                                     const uintT* __restrict__ seg,
                                                     const float* __restrict__ invs,
                                                     int* __restrict__ indptr,
                                                     uintT* __restrict__ epack,
                                                     const float* __restrict__ X,
                                                     ucharT* __restrict__ Xb,
                                                     const float* __restrict__ w0,
                                                     const float* __restrict__ w1,
                                                     const float* __restrict__ w2,
                                                     const float* __restrict__ w3,
                                                     ushortT* __restrict__ Whi,
                                                     int N, int NB, int total4) {
    const int t = threadIdx.x;
    if ((int)blockIdx.x < NB) {
        __shared__ uintT staged[SEG];   // 16 KB
        __shared__ int h[128];
        __shared__ int sc[128];
        __shared__ int pc[128];
        const int b = blockIdx.x;
        const int cnt = bfill[b];
        const int base = bbase[b];
        const uintT* sp = seg + (size_t)b * SEG;

        if (t < 128) h[t] = 0;
        __syncthreads();
        for (int s = t; s < cnt; s += 256) atomicAdd(&h[(sp[s] >> 16) & 127], 1);
        __syncthreads();
        if (t < 128) sc[t] = h[t];
        __syncthreads();
        for (int off = 1; off < 128; off <<= 1) {
            int a = (t >= off && t < 128) ? sc[t - off] : 0;
            __syncthreads();
            if (t < 128) sc[t] += a;
            __syncthreads();
        }
        if (t < 128) {
            int excl = sc[t] - h[t];
            pc[t] = excl;
            int d = b * 128 + t;
            if (d < N) indptr[d] = base + excl;
        }
        __syncthreads();
        for (int s = t; s < cnt; s += 256) {
            uintT rc = sp[s];
            int src = (int)(rc & 0xffffu), dst = (int)(rc >> 16);
            int j = atomicAdd(&pc[dst & 127], 1);
            float nrm = invs[src] * invs[dst];
            staged[j] = (uintT)src | ((uintT)f2bf(nrm) << 16);
        }
        __syncthreads();
        for (int s = t; s < cnt; s += 256) epack[base + s] = staged[s];
    } else if ((int)blockIdx.x < NB + 256) {
        int idx = (blockIdx.x - NB) * 256 + t;  // 0..65535
        int m = idx >> 14;
        int r = idx & 16383;
        int n = r >> 7;
        int k = r & 127;
        const float* W = (m == 0) ? w0 : (m == 1) ? w1 : (m == 2) ? w2 : w3;
        Whi[m * 16384 + n * CH + k] = f2bf(W[k * CH + n]);
    } else {
        int i = (blockIdx.x - NB - 256) * 256 + t;
        if (i < total4) {
            float4 v = reinterpret_cast<const float4*>(X)[i];
            int r0 = __builtin_amdgcn_cvt_pk_fp8_f32(v.x, v.y, 0, false);
            int r1 = __builtin_amdgcn_cvt_pk_fp8_f32(v.z, v.w, r0, true);
            reinterpret_cast<int*>(Xb)[i] = r1;
        }
    }
}

// ---- aggregation: 4 nodes/wave (16 lanes x 8ch), fp8 in, fp8 out ----------
__global__ __launch_bounds__(256) void k_agg(const ucharT* __restrict__ H8,
                                             const uintT* __restrict__ epack,
                                             const int* __restrict__ indptr,
                                             const float* __restrict__ invs,
                                             ucharT* __restrict__ Z8, int N) {
    const int wave = threadIdx.x >> 6, lane = threadIdx.x & 63;
    const int sub = lane >> 4;
    const int l = lane & 15;
    const int node = blockIdx.x * 16 + wave * 4 + sub;
    if (node >= N) return;

    const uint2* H2 = reinterpret_cast<const uint2*>(H8);

    float acc[8];
    {
        float sn = invs[node];
        float sn2 = sn * sn;
        uint2 h = H2[(size_t)node * 16 + l];
        float d[8];
        dec4(h.x, d); dec4(h.y, d + 4);
#pragma unroll
        for (int j = 0; j < 8; ++j) acc[j] = sn2 * d[j];
    }

    int p = indptr[node];
    int p1 = indptr[node + 1];
    for (; p + 8 <= p1; p += 8) {
        uintT e[8];
#pragma unroll
        for (int i = 0; i < 8; ++i) e[i] = epack[p + i];
        uint2 g[8];
#pragma unroll
        for (int i = 0; i < 8; ++i) g[i] = H2[(size_t)(int)(e[i] & 0xffffu) * 16 + l];
#pragma unroll
        for (int i = 0; i < 8; ++i) {
            float wv = bf2f(e[i] >> 16);
            float d[8];
            dec4(g[i].x, d); dec4(g[i].y, d + 4);
#pragma unroll
            for (int j = 0; j < 8; ++j) acc[j] += wv * d[j];
        }
    }
    if (p + 4 <= p1) {
        uintT e[4];
#pragma unroll
        for (int i = 0; i < 4; ++i) e[i] = epack[p + i];
        uint2 g[4];
#pragma unroll
        for (int i = 0; i < 4; ++i) g[i] = H2[(size_t)(int)(e[i] & 0xffffu) * 16 + l];
#pragma unroll
        for (int i = 0; i < 4; ++i) {
            float wv = bf2f(e[i] >> 16);
            float d[8];
            dec4(g[i].x, d); dec4(g[i].y, d + 4);
#pragma unroll
            for (int j = 0; j < 8; ++j) acc[j] += wv * d[j];
        }
        p += 4;
    }
    for (; p < p1; ++p) {
        uintT e = epack[p];
        uint2 g = H2[(size_t)(int)(e & 0xffffu) * 16 + l];
        float wv = bf2f(e >> 16);
        float d[8];
        dec4(g.x, d); dec4(g.y, d + 4);
#pragma unroll
        for (int j = 0; j < 8; ++j) acc[j] += wv * d[j];
    }

    uint2 o;
    {
        int r0 = __builtin_amdgcn_cvt_pk_fp8_f32(acc[0], acc[1], 0, false);
        r0 = __builtin_amdgcn_cvt_pk_fp8_f32(acc[2], acc[3], r0, true);
        int r1 = __builtin_amdgcn_cvt_pk_fp8_f32(acc[4], acc[5], 0, false);
        r1 = __builtin_amdgcn_cvt_pk_fp8_f32(acc[6], acc[7], r1, true);
        o.x = (uintT)r0; o.y = (uintT)r1;
    }
    reinterpret_cast<uint2*>(Z8)[(size_t)node * 16 + l] = o;
}

// ---- MFMA GEMM (GCN layers 1,2): fp8 in, fp8 out, single bf16 W -----------
__global__ __launch_bounds__(256) void k_gemm(const ucharT* __restrict__ In8,
                                              const ushortT* __restrict__ Whi,
                                              const float* __restrict__ Bias,
                                              ucharT* __restrict__ Out8, int N) {
    __shared__ ushortT smem[128 * SC];  // 33792 B union
    ushortT* As = smem;
    ushortT* Ws = smem + 128 * SA;
    ushortT* Cs = smem;                  // epilogue alias

    const int tid = threadIdx.x;
    const int wave = tid >> 6, lane = tid & 63;
    const int quad = lane >> 4, l15 = lane & 15;
    const int mBase = (wave >> 1) * 64, nBase = (wave & 1) * 64;
    const int row0 = blockIdx.x * 128;
    const int r = tid >> 1, half = tid & 1;

    floatx4 acc[4][4];
    const floatx4 zero4 = {0.f, 0.f, 0.f, 0.f};
#pragma unroll
    for (int i = 0; i < 4; i++)
#pragma unroll
        for (int j = 0; j < 4; j++) acc[i][j] = zero4;

    for (int ks = 0; ks < 4; ++ks) {
        {
            int grow = row0 + r;
            uint4 a8 = {0, 0, 0, 0};
            if (grow < N)
                a8 = *reinterpret_cast<const uint4*>(
                    In8 + (size_t)grow * CH + ks * 32 + half * 16);
            uintT wds[4] = {a8.x, a8.y, a8.z, a8.w};
            uintT ob[8];
#pragma unroll
            for (int q = 0; q < 4; ++q) {
                float d[4];
                dec4(wds[q], d);
                ob[2 * q] = (uintT)f2bf(d[0]) | ((uintT)f2bf(d[1]) << 16);
                ob[2 * q + 1] = (uintT)f2bf(d[2]) | ((uintT)f2bf(d[3]) << 16);
            }
            uint4* dd = reinterpret_cast<uint4*>(&As[r * SA + half * 16]);
            dd[0] = uint4{ob[0], ob[1], ob[2], ob[3]};
            dd[1] = uint4{ob[4], ob[5], ob[6], ob[7]};
            const uint4* sh = reinterpret_cast<const uint4*>(Whi + r * CH + ks * 32 + half * 16);
            uint4* dh = reinterpret_cast<uint4*>(&Ws[r * SA + half * 16]);
            dh[0] = sh[0]; dh[1] = sh[1];
        }
        __syncthreads();

        short8 af[4], wf[4];
#pragma unroll
        for (int mt = 0; mt < 4; ++mt)
            af[mt] = *reinterpret_cast<const short8*>(&As[(mBase + mt * 16 + l15) * SA + quad * 8]);
#pragma unroll
        for (int nt = 0; nt < 4; ++nt)
            wf[nt] = *reinterpret_cast<const short8*>(&Ws[(nBase + nt * 16 + l15) * SA + quad * 8]);
#pragma unroll
        for (int mt = 0; mt < 4; ++mt)
#pragma unroll
            for (int nt = 0; nt < 4; ++nt)
                acc[mt][nt] = __builtin_amdgcn_mfma_f32_16x16x32_bf16(af[mt], wf[nt], acc[mt][nt], 0, 0, 0);
        __syncthreads();
    }

    float bb[4];
#pragma unroll
    for (int nt = 0; nt < 4; ++nt) bb[nt] = Bias[nBase + nt * 16 + l15];

    ucharT* Cs8 = reinterpret_cast<ucharT*>(Cs);
#pragma unroll
    for (int mt = 0; mt < 4; ++mt)
#pragma unroll
        for (int nt = 0; nt < 4; ++nt)
#pragma unroll
            for (int r4 = 0; r4 < 4; ++r4) {
                int lrow = mBase + mt * 16 + quad * 4 + r4;
                float v = fmaxf(acc[mt][nt][r4] + bb[nt], 0.f);
                int f8 = __builtin_amdgcn_cvt_pk_fp8_f32(v, 0.f, 0, false);
                Cs8[lrow * SC8 + nBase + nt * 16 + l15] = (ucharT)(f8 & 0xff);
            }
    __syncthreads();
    {
        int grow = row0 + r;
        if (grow < N) {
            const uint4* s4 = reinterpret_cast<const uint4*>(&Cs8[r * SC8 + half * 64]);
            uint4* dst = reinterpret_cast<uint4*>(Out8 + (size_t)grow * CH + half * 64);
#pragma unroll
            for (int q = 0; q < 4; ++q) dst[q] = s4[q];
        }
    }
}

// ---- fused tail: GEMM(W3) -> relu -> GEMM(FW1) -> FC2 -> mean-pool --------
// No gather inside (R7 lesson); H3 tile lives in LDS (Hf), never in HBM.
__global__ __launch_bounds__(256) void k_tail(const ucharT* __restrict__ Z8,
                                              const ushortT* __restrict__ W3hi,
                                              const float* __restrict__ B3,
                                              const ushortT* __restrict__ F1hi,
                                              const float* __restrict__ FB1,
                                              const float* __restrict__ FW2,
                                              const float* __restrict__ FB2,
                                              const int* __restrict__ batch,
                                              float* __restrict__ sums,
                                              float* __restrict__ cnts, int N) {
    __shared__ ushortT Hf[128 * SAF];   // 34816 B: A-tile (Z), then H3 tile
    __shared__ ushortT Ws[128 * SA];    // 10240 B
    __shared__ float rp0[256];
    __shared__ float rp1[256];
    __shared__ float ls[192];

    const int tid = threadIdx.x;
    const int wave = tid >> 6, lane = tid & 63;
    const int quad = lane >> 4, l15 = lane & 15;
    const int mBase = (wave >> 1) * 64, nBase = (wave & 1) * 64;
    const int row0 = blockIdx.x * 128;
    const int r = tid >> 1, half = tid & 1;

    // stage full Z tile: fp8 -> bf16 into Hf (64 B = full half-row per thread)
    {
        int grow = row0 + r;
        uint4 a8 = {0, 0, 0, 0}, b8 = {0, 0, 0, 0}, c8 = {0, 0, 0, 0}, d8v = {0, 0, 0, 0};
        if (grow < N) {
            const uint4* s = reinterpret_cast<const uint4*>(Z8 + (size_t)grow * CH + half * 64);
            a8 = s[0]; b8 = s[1]; c8 = s[2]; d8v = s[3];
        }
        uintT wds[16] = {a8.x, a8.y, a8.z, a8.w, b8.x, b8.y, b8.z, b8.w,
                         c8.x, c8.y, c8.z, c8.w, d8v.x, d8v.y, d8v.z, d8v.w};
#pragma unroll
        for (int q = 0; q < 16; ++q) {
            float d[4];
            dec4(wds[q], d);
            uint2 o;
            o.x = (uintT)f2bf(d[0]) | ((uintT)f2bf(d[1]) << 16);
            o.y = (uintT)f2bf(d[2]) | ((uintT)f2bf(d[3]) << 16);
            *reinterpret_cast<uint2*>(&Hf[r * SAF + half * 64 + q * 4]) = o;
        }
    }

    floatx4 acc[4][4];
    const floatx4 zero4 = {0.f, 0.f, 0.f, 0.f};
#pragma unroll
    for (int i = 0; i < 4; i++)
#pragma unroll
        for (int j = 0; j < 4; j++) acc[i][j] = zero4;

    // GEMM 1: Z @ W3
    for (int ks = 0; ks < 4; ++ks) {
        {
            const uint4* sh = reinterpret_cast<const uint4*>(W3hi + r * CH + ks * 32 + half * 16);
            uint4* dh = reinterpret_cast<uint4*>(&Ws[r * SA + half * 16]);
            dh[0] = sh[0]; dh[1] = sh[1];
        }
        __syncthreads();
        short8 af[4], wf[4];
#pragma unroll
        for (int mt = 0; mt < 4; ++mt)
            af[mt] = *reinterpret_cast<const short8*>(&Hf[(mBase + mt * 16 + l15) * SAF + ks * 32 + quad * 8]);
#pragma unroll
        for (int nt = 0; nt < 4; ++nt)
            wf[nt] = *reinterpret_cast<const short8*>(&Ws[(nBase + nt * 16 + l15) * SA + quad * 8]);
#pragma unroll
        for (int mt = 0; mt < 4; ++mt)
#pragma unroll
            for (int nt = 0; nt < 4; ++nt)
                acc[mt][nt] = __builtin_amdgcn_mfma_f32_16x16x32_bf16(af[mt], wf[nt], acc[mt][nt], 0, 0, 0);
        __syncthreads();
    }

    // epilogue 1: H3 = relu(acc + b3) -> back into Hf (A of FC1)
    {
        float bb[4];
#pragma unroll
        for (int nt = 0; nt < 4; ++nt) bb[nt] = B3[nBase + nt * 16 + l15];
#pragma unroll
        for (int mt = 0; mt < 4; ++mt)
#pragma unroll
            for (int nt = 0; nt < 4; ++nt)
#pragma unroll
                for (int r4 = 0; r4 < 4; ++r4) {
                    int lrow = mBase + mt * 16 + quad * 4 + r4;
                    float v = fmaxf(acc[mt][nt][r4] + bb[nt], 0.f);
                    Hf[lrow * SAF + nBase + nt * 16 + l15] = f2bf(v);
                }
    }
    __syncthreads();

    // GEMM 2: H3 @ FW1
#pragma unroll
    for (int i = 0; i < 4; i++)
#pragma unroll
        for (int j = 0; j < 4; j++) acc[i][j] = zero4;
    for (int ks = 0; ks < 4; ++ks) {
        {
            const uint4* sh = reinterpret_cast<const uint4*>(F1hi + r * CH + ks * 32 + half * 16);
            uint4* dh = reinterpret_cast<uint4*>(&Ws[r * SA + half * 16]);
            dh[0] = sh[0]; dh[1] = sh[1];
        }
        __syncthreads();
        short8 af[4], wf[4];
#pragma unroll
        for (int mt = 0; mt < 4; ++mt)
            af[mt] = *reinterpret_cast<const short8*>(&Hf[(mBase + mt * 16 + l15) * SAF + ks * 32 + quad * 8]);
#pragma unroll
        for (int nt = 0; nt < 4; ++nt)
            wf[nt] = *reinterpret_cast<const short8*>(&Ws[(nBase + nt * 16 + l15) * SA + quad * 8]);
#pragma unroll
        for (int mt = 0; mt < 4; ++mt)
#pragma unroll
            for (int nt = 0; nt < 4; ++nt)
                acc[mt][nt] = __builtin_amdgcn_mfma_f32_16x16x32_bf16(af[mt], wf[nt], acc[mt][nt], 0, 0, 0);
        __syncthreads();
    }

    // FC2: per-row dot with fcW2 over this lane's 4 columns, reduce over l15
    {
        float bb[4];
#pragma unroll
        for (int nt = 0; nt < 4; ++nt) bb[nt] = FB1[nBase + nt * 16 + l15];
        float w20[4], w21[4];
#pragma unroll
        for (int nt = 0; nt < 4; ++nt) {
            float2 wv = *reinterpret_cast<const float2*>(FW2 + 2 * (nBase + nt * 16 + l15));
            w20[nt] = wv.x;
            w21[nt] = wv.y;
        }
#pragma unroll
        for (int mt = 0; mt < 4; ++mt)
#pragma unroll
            for (int r4 = 0; r4 < 4; ++r4) {
                float d0 = 0.f, d1 = 0.f;
#pragma unroll
                for (int nt = 0; nt < 4; ++nt) {
                    float v = fmaxf(acc[mt][nt][r4] + bb[nt], 0.f);
                    d0 += v * w20[nt];
                    d1 += v * w21[nt];
                }
#pragma unroll
                for (int m = 8; m >= 1; m >>= 1) {
                    d0 += __shfl_xor(d0, m, 64);
                    d1 += __shfl_xor(d1, m, 64);
                }
                if (l15 == 0) {
                    int lrow = mBase + mt * 16 + quad * 4 + r4;
                    rp0[lrow * 2 + (wave & 1)] = d0;
                    rp1[lrow * 2 + (wave & 1)] = d1;
                }
            }
    }
    if (tid < 192) ls[tid] = 0.f;
    __syncthreads();

    if (tid < 128) {
        int node = row0 + tid;
        if (node < N) {
            float d0 = rp0[tid * 2] + rp0[tid * 2 + 1] + FB2[0];
            float d1 = rp1[tid * 2] + rp1[tid * 2 + 1] + FB2[1];
            int g = batch[node];
            atomicAdd(&ls[g], d0);
            atomicAdd(&ls[64 + g], d1);
            atomicAdd(&ls[128 + g], 1.0f);
        }
    }
    __syncthreads();
    if (tid < 64) {
        float c = ls[128 + tid];
        if (c != 0.f) {
            atomicAdd(&sums[2 * tid], ls[tid]);
            atomicAdd(&sums[2 * tid + 1], ls[64 + tid]);
            atomicAdd(&cnts[tid], c);
        }
    }
}

__global__ void k_softmax(const float* __restrict__ sums, const float* __restrict__ cnts,
                          float* __restrict__ out, int G) {
    int g = blockIdx.x * blockDim.x + threadIdx.x;
    if (g < G) {
        float c = fmaxf(cnts[g], 1.0f);
        float p0 = sums[2 * g] / c;
        float p1 = sums[2 * g + 1] / c;
        float m = fmaxf(p0, p1);
        float e0 = expf(p0 - m), e1 = expf(p1 - m);
        float inv = 1.f / (e0 + e1);
        out[2 * g] = e0 * inv;
        out[2 * g + 1] = e1 * inv;
    }
}

// ---------------------------------------------------------------------------
extern "C" void kernel_launch(void* const* d_in, const int* in_sizes, int n_in,
                              void* d_out, int out_size, void* d_ws, size_t ws_size,
                              hipStream_t stream) {
    const float* X   = (const float*)d_in[0];
    const int* EI    = (const int*)d_in[1];
    const int* BATCH = (const int*)d_in[2];
    const float* W1  = (const float*)d_in[3];
    const float* B1  = (const float*)d_in[4];
    const float* W2  = (const float*)d_in[5];
    const float* B2  = (const float*)d_in[6];
    const float* W3  = (const float*)d_in[7];
    const float* B3  = (const float*)d_in[8];
    const float* FW1 = (const float*)d_in[9];
    const float* FB1 = (const float*)d_in[10];
    const float* FW2 = (const float*)d_in[11];
    const float* FB2 = (const float*)d_in[12];

    const int N = in_sizes[0] / CH;
    const int E = in_sizes[1] / 2;
    const int G = out_size / 2;
    const int* rowp = EI;
    const int* colp = EI + E;
    const int NB = (N + 127) >> BSH;

    char* w = (char*)d_ws;
    auto alloc = [&](size_t bytes) -> char* {
        char* p = w;
        w += (bytes + 255) & ~(size_t)255;
        return p;
    };
    ucharT*  Z8    = (ucharT*)alloc((size_t)N * CH);        // fp8 Z (agg out)
    ucharT*  Hb8   = (ucharT*)alloc((size_t)N * CH);        // fp8 H1/H2
    ucharT*  Xb8   = (ucharT*)alloc((size_t)N * CH);        // fp8 X
    ushortT* WhiA  = (ushortT*)alloc((size_t)4 * 16384 * 2);
    float* invs    = (float*)alloc((size_t)N * 4);
    int*   indptr  = (int*)alloc((size_t)(N + 1) * 4);
    uintT* epack   = (uintT*)alloc((size_t)E * 4);
    uintT* seg     = (uintT*)alloc((size_t)NB * SEG * 4);
    int*   bfill   = (int*)alloc((size_t)NB * 4);
    int*   bbase   = (int*)alloc((size_t)NB * 4);
    float* sums    = (float*)alloc((size_t)G * 3 * 4);      // sums | cnts
    float* cnts    = sums + 2 * G;

    const int nbAgg  = (N + 15) / 16;
    const int nbGemm = (N + 127) / 128;
    const int nbBin  = (E + EPW - 1) / EPW;
    const int total4 = N * CH / 4;
    const int nbSP   = NB + 256 + (total4 + 255) / 256;

    k_zero<<<1, 256, 0, stream>>>(bfill, NB, sums, 3 * G);
    k_bin<<<nbBin, 256, 0, stream>>>(rowp, colp, bfill, seg, E, NB);
    k_binvs_bscan<<<NB + 1, 512, 0, stream>>>(bfill, seg, invs, bbase, indptr, NB, N, E);
    k_scatterprep<<<nbSP, 256, 0, stream>>>(bfill, bbase, seg, invs, indptr, epack,
                                            X, Xb8, W1, W2, W3, FW1, WhiA, N, NB, total4);

    // layer 1
    k_agg<<<nbAgg, 256, 0, stream>>>(Xb8, epack, indptr, invs, Z8, N);
    k_gemm<<<nbGemm, 256, 0, stream>>>(Z8, WhiA, B1, Hb8, N);
    // layer 2
    k_agg<<<nbAgg, 256, 0, stream>>>(Hb8, epack, indptr, invs, Z8, N);
    k_gemm<<<nbGemm, 256, 0, stream>>>(Z8, WhiA + 16384, B2, Hb8, N);
    // layer 3 agg, then fused tail (GEMM W3 + FC1 + FC2 + pool)
    k_agg<<<nbAgg, 256, 0, stream>>>(Hb8, epack, indptr, invs, Z8, N);
    k_tail<<<nbGemm, 256, 0, stream>>>(Z8, WhiA + 2 * 16384, B3,
                                       WhiA + 3 * 16384, FB1, FW2, FB2,
                                       BATCH, sums, cnts, N);
    k_softmax<<<1, 64, 0, stream>>>(sums, cnts, (float*)d_out, G);
}

// Round 13
// 210.216 us; speedup vs baseline: 1.9682x; 1.0072x over previous
//
#include <hip/hip_runtime.h>

// ---------------------------------------------------------------------------
// colorableGNN: 3x GCN(128->128) + FC(128->128) + FC(128->2) + mean-pool + softmax
// R12 (delta vs R11): fp8 activations split into channel-half arrays
// (64B/row). k_agg blocks pick a half via the %8 XCD round-robin heuristic
// -> per-XCD gather footprint 3.2MB fits the 4MiB XCD L2 (was 6.4MB,
// thrashing). 8 lanes/node x 8ch = 8 edge streams/wave. GEMM/tail stage
// from both halves. Heuristic-safe: wrong mapping only costs the doubled
// epack stream. fp8 acts, 4B edges, bf16 weights, fp32 acc.
// NOTE: gather kernels need occupancy; never fuse agg into GEMM (R7: 104us).
// ---------------------------------------------------------------------------

#define CH 128
#define BSH 7              // 128 dst nodes per bucket
#define SEG 4096           // segment capacity (records) per bucket
#define EPW 4096           // edges per phase-1 workgroup
#define SA 40              // LDS stride for W chunks (shorts)
#define SAF 136            // LDS stride full-K A tile (shorts; 272B = 17*16B)
#define SC 132             // bf16 epilogue stride (shorts)
#define SC8 144            // fp8 epilogue stride (bytes)

typedef unsigned short ushortT;
typedef unsigned int uintT;
typedef unsigned char ucharT;
typedef __attribute__((ext_vector_type(8))) short short8;
typedef __attribute__((ext_vector_type(4))) float floatx4;
typedef __attribute__((ext_vector_type(2))) float floatx2;

__device__ __forceinline__ float bf2f(uintT u) {
    return __uint_as_float(u << 16);
}
__device__ __forceinline__ ushortT f2bf(float f) {
    uintT x = __float_as_uint(f);
    return (ushortT)((x + 0x7fffu + ((x >> 16) & 1u)) >> 16);
}
__device__ __forceinline__ void dec4(uintT u, float* o) {
    floatx2 lo = __builtin_amdgcn_cvt_pk_f32_fp8((int)u, false);
    floatx2 hi = __builtin_amdgcn_cvt_pk_f32_fp8((int)u, true);
    o[0] = lo.x; o[1] = lo.y; o[2] = hi.x; o[3] = hi.y;
}

// ---- zero bfill + pooling accumulators ------------------------------------
__global__ void k_zero(int* __restrict__ bfill, int NB, float* __restrict__ acc, int nacc) {
    int t = threadIdx.x;
    for (int i = t; i < NB; i += 256) bfill[i] = 0;
    for (int i = t; i < nacc; i += 256) acc[i] = 0.f;
}

// ---- phase 1: bin edges into dst-buckets; records packed src|(dst<<16) ----
__global__ __launch_bounds__(256) void k_bin(const int* __restrict__ row,
                                             const int* __restrict__ col,
                                             int* __restrict__ bfill,
                                             uintT* __restrict__ seg,
                                             int E, int NB) {
    __shared__ uintT staged[EPW];   // 16 KB
    __shared__ int target[EPW];     // 16 KB
    __shared__ int sval[512];
    __shared__ int horig[512];
    __shared__ int pcnt[512];
    __shared__ int gbase[512];
    const int t = threadIdx.x;
    const int e0 = blockIdx.x * EPW;
    const int cnt = min(EPW, E - e0);

    sval[t] = 0; sval[t + 256] = 0;
    __syncthreads();

    int er[16], ec[16];
#pragma unroll
    for (int i = 0; i < 16; ++i) {
        int le = i * 256 + t;
        if (le < cnt) {
            er[i] = row[e0 + le];
            ec[i] = col[e0 + le];
            atomicAdd(&sval[ec[i] >> BSH], 1);
        }
    }
    __syncthreads();
    horig[t] = sval[t]; horig[t + 256] = sval[t + 256];
    __syncthreads();
    for (int off = 1; off < 512; off <<= 1) {
        int a = (t >= off) ? sval[t - off] : 0;
        int b2 = sval[t + 256 - off];
        __syncthreads();
        sval[t] += a;
        sval[t + 256] += b2;
        __syncthreads();
    }
    for (int b = t; b < 512; b += 256) {
        int h = horig[b];
        pcnt[b] = sval[b] - h;
        gbase[b] = (h > 0 && b < NB) ? atomicAdd(&bfill[b], h) : 0;
    }
    __syncthreads();
#pragma unroll
    for (int i = 0; i < 16; ++i) {
        int le = i * 256 + t;
        if (le < cnt) {
            int b = ec[i] >> BSH;
            int j = atomicAdd(&pcnt[b], 1);
            staged[j] = (uintT)er[i] | ((uintT)ec[i] << 16);
            int lo = sval[b] - horig[b];
            target[j] = b * SEG + gbase[b] + (j - lo);
        }
    }
    __syncthreads();
    for (int s = t; s < cnt; s += 256) seg[target[s]] = staged[s];
}

// ---- fused: per-bucket degree->invs (blocks 0..NB-1) + bucket scan (NB) ---
__global__ __launch_bounds__(512) void k_binvs_bscan(const int* __restrict__ bfill,
                                                     const uintT* __restrict__ seg,
                                                     float* __restrict__ invs,
                                                     int* __restrict__ bbase,
                                                     int* __restrict__ indptr,
                                                     int NB, int N, int E) {
    const int b = blockIdx.x;
    const int t = threadIdx.x;
    if (b < NB) {
        __shared__ int h[128];
        if (t < 128) h[t] = 0;
        __syncthreads();
        int cnt = bfill[b];
        const uintT* sp = seg + (size_t)b * SEG;
        for (int s = t; s < cnt; s += 512) atomicAdd(&h[(sp[s] >> 16) & 127], 1);
        __syncthreads();
        int d = b * 128 + t;
        if (t < 128 && d < N) invs[d] = rsqrtf((float)h[t] + 1.0f);
    } else {
        __shared__ int s[512];
        int v = (t < NB) ? bfill[t] : 0;
        s[t] = v;
        __syncthreads();
        for (int off = 1; off < 512; off <<= 1) {
            int a = (t >= off) ? s[t - off] : 0;
            __syncthreads();
            s[t] += a;
            __syncthreads();
        }
        if (t < NB) bbase[t] = s[t] - v;  // exclusive
        if (t == 0) indptr[N] = E;
    }
}

// ---- heterogeneous: CSR scatter | weight prep | X->fp8 (split halves) -----
__global__ __launch_bounds__(256) void k_scatterprep(const int* __restrict__ bfill,
                                                     const int* __restrict__ bbase,
                                                     const uintT* __restrict__ seg,
                                                     const float* __restrict__ invs,
                                                     int* __restrict__ indptr,
                                                     uintT* __restrict__ epack,
                                                     const float* __restrict__ X,
                                                     ucharT* __restrict__ Xlo,
                                                     ucharT* __restrict__ Xhi,
                                                     const float* __restrict__ w0,
                                                     const float* __restrict__ w1,
                                                     const float* __restrict__ w2,
                                                     const float* __restrict__ w3,
                                                     ushortT* __restrict__ Whi,
                                                     int N, int NB, int total4) {
    const int t = threadIdx.x;
    if ((int)blockIdx.x < NB) {
        __shared__ uintT staged[SEG];   // 16 KB
        __shared__ int h[128];
        __shared__ int sc[128];
        __shared__ int pc[128];
        const int b = blockIdx.x;
        const int cnt = bfill[b];
        const int base = bbase[b];
        const uintT* sp = seg + (size_t)b * SEG;

        if (t < 128) h[t] = 0;
        __syncthreads();
        for (int s = t; s < cnt; s += 256) atomicAdd(&h[(sp[s] >> 16) & 127], 1);
        __syncthreads();
        if (t < 128) sc[t] = h[t];
        __syncthreads();
        for (int off = 1; off < 128; off <<= 1) {
            int a = (t >= off && t < 128) ? sc[t - off] : 0;
            __syncthreads();
            if (t < 128) sc[t] += a;
            __syncthreads();
        }
        if (t < 128) {
            int excl = sc[t] - h[t];
            pc[t] = excl;
            int d = b * 128 + t;
            if (d < N) indptr[d] = base + excl;
        }
        __syncthreads();
        for (int s = t; s < cnt; s += 256) {
            uintT rc = sp[s];
            int src = (int)(rc & 0xffffu), dst = (int)(rc >> 16);
            int j = atomicAdd(&pc[dst & 127], 1);
            float nrm = invs[src] * invs[dst];
            staged[j] = (uintT)src | ((uintT)f2bf(nrm) << 16);
        }
        __syncthreads();
        for (int s = t; s < cnt; s += 256) epack[base + s] = staged[s];
    } else if ((int)blockIdx.x < NB + 256) {
        int idx = (blockIdx.x - NB) * 256 + t;  // 0..65535
        int m = idx >> 14;
        int r = idx & 16383;
        int n = r >> 7;
        int k = r & 127;
        const float* W = (m == 0) ? w0 : (m == 1) ? w1 : (m == 2) ? w2 : w3;
        Whi[m * 16384 + n * CH + k] = f2bf(W[k * CH + n]);
    } else {
        int i = (blockIdx.x - NB - 256) * 256 + t;  // float4-group index
        if (i < total4) {
            float4 v = reinterpret_cast<const float4*>(X)[i];
            int r0 = __builtin_amdgcn_cvt_pk_fp8_f32(v.x, v.y, 0, false);
            int r1 = __builtin_amdgcn_cvt_pk_fp8_f32(v.z, v.w, r0, true);
            int node = i >> 5;       // 32 dword-groups per 128-ch row
            int g = i & 31;
            int* dst = (g < 16) ? reinterpret_cast<int*>(Xlo + (size_t)node * 64) + g
                                : reinterpret_cast<int*>(Xhi + (size_t)node * 64) + (g - 16);
            *dst = r1;
        }
    }
}

// ---- aggregation: channel-half per block (XCD %8 heuristic) ---------------
// 8 lanes/node x 8ch (uint2); wave = 8 nodes -> 8 independent edge streams.
__global__ __launch_bounds__(256) void k_agg(const ucharT* __restrict__ Hlo,
                                             const ucharT* __restrict__ Hhi,
                                             const uintT* __restrict__ epack,
                                             const int* __restrict__ indptr,
                                             const float* __restrict__ invs,
                                             ucharT* __restrict__ Zlo,
                                             ucharT* __restrict__ Zhi,
                                             int N, int nbHalf) {
    const int half = (blockIdx.x >> 2) & 1;       // XCDs 0-3 -> lo, 4-7 -> hi
    const int nb = (blockIdx.x >> 3) * 4 + (blockIdx.x & 3);
    if (nb >= nbHalf) return;
    const int wave = threadIdx.x >> 6, lane = threadIdx.x & 63;
    const int ng = lane >> 3;        // node slot 0..7
    const int l = lane & 7;          // 8 channels each (uint2)
    const int node = nb * 32 + wave * 8 + ng;
    if (node >= N) return;

    const uint2* H2 = reinterpret_cast<const uint2*>(half ? Hhi : Hlo);

    float acc[8];
    {
        float sn = invs[node];
        float sn2 = sn * sn;
        uint2 h = H2[(size_t)node * 8 + l];
        float d[8];
        dec4(h.x, d); dec4(h.y, d + 4);
#pragma unroll
        for (int j = 0; j < 8; ++j) acc[j] = sn2 * d[j];
    }

    int p = indptr[node];
    int p1 = indptr[node + 1];
    for (; p + 8 <= p1; p += 8) {
        uintT e[8];
#pragma unroll
        for (int i = 0; i < 8; ++i) e[i] = epack[p + i];
        uint2 g[8];
#pragma unroll
        for (int i = 0; i < 8; ++i) g[i] = H2[(size_t)(int)(e[i] & 0xffffu) * 8 + l];
#pragma unroll
        for (int i = 0; i < 8; ++i) {
            float wv = bf2f(e[i] >> 16);
            float d[8];
            dec4(g[i].x, d); dec4(g[i].y, d + 4);
#pragma unroll
            for (int j = 0; j < 8; ++j) acc[j] += wv * d[j];
        }
    }
    if (p + 4 <= p1) {
        uintT e[4];
#pragma unroll
        for (int i = 0; i < 4; ++i) e[i] = epack[p + i];
        uint2 g[4];
#pragma unroll
        for (int i = 0; i < 4; ++i) g[i] = H2[(size_t)(int)(e[i] & 0xffffu) * 8 + l];
#pragma unroll
        for (int i = 0; i < 4; ++i) {
            float wv = bf2f(e[i] >> 16);
            float d[8];
            dec4(g[i].x, d); dec4(g[i].y, d + 4);
#pragma unroll
            for (int j = 0; j < 8; ++j) acc[j] += wv * d[j];
        }
        p += 4;
    }
    for (; p < p1; ++p) {
        uintT e = epack[p];
        uint2 g = H2[(size_t)(int)(e & 0xffffu) * 8 + l];
        float wv = bf2f(e >> 16);
        float d[8];
        dec4(g.x, d); dec4(g.y, d + 4);
#pragma unroll
        for (int j = 0; j < 8; ++j) acc[j] += wv * d[j];
    }

    uint2 o;
    {
        int r0 = __builtin_amdgcn_cvt_pk_fp8_f32(acc[0], acc[1], 0, false);
        r0 = __builtin_amdgcn_cvt_pk_fp8_f32(acc[2], acc[3], r0, true);
        int r1 = __builtin_amdgcn_cvt_pk_fp8_f32(acc[4], acc[5], 0, false);
        r1 = __builtin_amdgcn_cvt_pk_fp8_f32(acc[6], acc[7], r1, true);
        o.x = (uintT)r0; o.y = (uintT)r1;
    }
    reinterpret_cast<uint2*>(half ? Zhi : Zlo)[(size_t)node * 8 + l] = o;
}

// ---- MFMA GEMM (GCN layers 1,2): fp8 halves in/out, single bf16 W ---------
__global__ __launch_bounds__(256) void k_gemm(const ucharT* __restrict__ Inlo,
                                              const ucharT* __restrict__ Inhi,
                                              const ushortT* __restrict__ Whi,
                                              const float* __restrict__ Bias,
                                              ucharT* __restrict__ Outlo,
                                              ucharT* __restrict__ Outhi, int N) {
    __shared__ ushortT smem[128 * SC];  // 33792 B union
    ushortT* As = smem;
    ushortT* Ws = smem + 128 * SA;
    ushortT* Cs = smem;                  // epilogue alias

    const int tid = threadIdx.x;
    const int wave = tid >> 6, lane = tid & 63;
    const int quad = lane >> 4, l15 = lane & 15;
    const int mBase = (wave >> 1) * 64, nBase = (wave & 1) * 64;
    const int row0 = blockIdx.x * 128;
    const int r = tid >> 1, half = tid & 1;

    floatx4 acc[4][4];
    const floatx4 zero4 = {0.f, 0.f, 0.f, 0.f};
#pragma unroll
    for (int i = 0; i < 4; i++)
#pragma unroll
        for (int j = 0; j < 4; j++) acc[i][j] = zero4;

    for (int ks = 0; ks < 4; ++ks) {
        {
            int grow = row0 + r;
            const ucharT* sbase = (ks < 2) ? Inlo : Inhi;
            uint4 a8 = {0, 0, 0, 0};
            if (grow < N)
                a8 = *reinterpret_cast<const uint4*>(
                    sbase + (size_t)grow * 64 + (ks & 1) * 32 + half * 16);
            uintT wds[4] = {a8.x, a8.y, a8.z, a8.w};
            uintT ob[8];
#pragma unroll
            for (int q = 0; q < 4; ++q) {
                float d[4];
                dec4(wds[q], d);
                ob[2 * q] = (uintT)f2bf(d[0]) | ((uintT)f2bf(d[1]) << 16);
                ob[2 * q + 1] = (uintT)f2bf(d[2]) | ((uintT)f2bf(d[3]) << 16);
            }
            uint4* dd = reinterpret_cast<uint4*>(&As[r * SA + half * 16]);
            dd[0] = uint4{ob[0], ob[1], ob[2], ob[3]};
            dd[1] = uint4{ob[4], ob[5], ob[6], ob[7]};
            const uint4* sh = reinterpret_cast<const uint4*>(Whi + r * CH + ks * 32 + half * 16);
            uint4* dh = reinterpret_cast<uint4*>(&Ws[r * SA + half * 16]);
            dh[0] = sh[0]; dh[1] = sh[1];
        }
        __syncthreads();

        short8 af[4], wf[4];
#pragma unroll
        for (int mt = 0; mt < 4; ++mt)
            af[mt] = *reinterpret_cast<const short8*>(&As[(mBase + mt * 16 + l15) * SA + quad * 8]);
#pragma unroll
        for (int nt = 0; nt < 4; ++nt)
            wf[nt] = *reinterpret_cast<const short8*>(&Ws[(nBase + nt * 16 + l15) * SA + quad * 8]);
#pragma unroll
        for (int mt = 0; mt < 4; ++mt)
#pragma unroll
            for (int nt = 0; nt < 4; ++nt)
                acc[mt][nt] = __builtin_amdgcn_mfma_f32_16x16x32_bf16(af[mt], wf[nt], acc[mt][nt], 0, 0, 0);
        __syncthreads();
    }

    float bb[4];
#pragma unroll
    for (int nt = 0; nt < 4; ++nt) bb[nt] = Bias[nBase + nt * 16 + l15];

    ucharT* Cs8 = reinterpret_cast<ucharT*>(Cs);
#pragma unroll
    for (int mt = 0; mt < 4; ++mt)
#pragma unroll
        for (int nt = 0; nt < 4; ++nt)
#pragma unroll
            for (int r4 = 0; r4 < 4; ++r4) {
                int lrow = mBase + mt * 16 + quad * 4 + r4;
                float v = fmaxf(acc[mt][nt][r4] + bb[nt], 0.f);
                int f8 = __builtin_amdgcn_cvt_pk_fp8_f32(v, 0.f, 0, false);
                Cs8[lrow * SC8 + nBase + nt * 16 + l15] = (ucharT)(f8 & 0xff);
            }
    __syncthreads();
    {
        int grow = row0 + r;
        if (grow < N) {
            const uint4* s4 = reinterpret_cast<const uint4*>(&Cs8[r * SC8 + half * 64]);
            ucharT* obase = half ? Outhi : Outlo;
            uint4* dst = reinterpret_cast<uint4*>(obase + (size_t)grow * 64);
#pragma unroll
            for (int q = 0; q < 4; ++q) dst[q] = s4[q];
        }
    }
}

// ---- fused tail: GEMM(W3) -> relu -> GEMM(FW1) -> FC2 -> mean-pool --------
// No gather inside (R7 lesson); H3 tile lives in LDS (Hf), never in HBM.
__global__ __launch_bounds__(256) void k_tail(const ucharT* __restrict__ Zlo,
                                              const ucharT* __restrict__ Zhi,
                                              const ushortT* __restrict__ W3hi,
                                              const float* __restrict__ B3,
                                              const ushortT* __restrict__ F1hi,
                                              const float* __restrict__ FB1,
                                              const float* __restrict__ FW2,
                                              const float* __restrict__ FB2,
                                              const int* __restrict__ batch,
                                              float* __restrict__ sums,
                                              float* __restrict__ cnts, int N) {
    __shared__ ushortT Hf[128 * SAF];   // 34816 B: A-tile (Z), then H3 tile
    __shared__ ushortT Ws[128 * SA];    // 10240 B
    __shared__ float rp0[256];
    __shared__ float rp1[256];
    __shared__ float ls[192];

    const int tid = threadIdx.x;
    const int wave = tid >> 6, lane = tid & 63;
    const int quad = lane >> 4, l15 = lane & 15;
    const int mBase = (wave >> 1) * 64, nBase = (wave & 1) * 64;
    const int row0 = blockIdx.x * 128;
    const int r = tid >> 1, half = tid & 1;

    // stage full Z tile: fp8 halves -> bf16 into Hf (64 B = one half per thread)
    {
        int grow = row0 + r;
        const ucharT* zsrc = half ? Zhi : Zlo;
        uint4 a8 = {0, 0, 0, 0}, b8 = {0, 0, 0, 0}, c8 = {0, 0, 0, 0}, d8v = {0, 0, 0, 0};
        if (grow < N) {
            const uint4* s = reinterpret_cast<const uint4*>(zsrc + (size_t)grow * 64);
            a8 = s[0]; b8 = s[1]; c8 = s[2]; d8v = s[3];
        }
        uintT wds[16] = {a8.x, a8.y, a8.z, a8.w, b8.x, b8.y, b8.z, b8.w,
                         c8.x, c8.y, c8.z, c8.w, d8v.x, d8v.y, d8v.z, d8v.w};
#pragma unroll
        for (int q = 0; q < 16; ++q) {
            float d[4];
            dec4(wds[q], d);
            uint2 o;
            o.x = (uintT)f2bf(d[0]) | ((uintT)f2bf(d[1]) << 16);
            o.y = (uintT)f2bf(d[2]) | ((uintT)f2bf(d[3]) << 16);
            *reinterpret_cast<uint2*>(&Hf[r * SAF + half * 64 + q * 4]) = o;
        }
    }

    floatx4 acc[4][4];
    const floatx4 zero4 = {0.f, 0.f, 0.f, 0.f};
#pragma unroll
    for (int i = 0; i < 4; i++)
#pragma unroll
        for (int j = 0; j < 4; j++) acc[i][j] = zero4;

    // GEMM 1: Z @ W3
    for (int ks = 0; ks < 4; ++ks) {
        {
            const uint4* sh = reinterpret_cast<const uint4*>(W3hi + r * CH + ks * 32 + half * 16);
            uint4* dh = reinterpret_cast<uint4*>(&Ws[r * SA + half * 16]);
            dh[0] = sh[0]; dh[1] = sh[1];
        }
        __syncthreads();
        short8 af[4], wf[4];
#pragma unroll
        for (int mt = 0; mt < 4; ++mt)
            af[mt] = *reinterpret_cast<const short8*>(&Hf[(mBase + mt * 16 + l15) * SAF + ks * 32 + quad * 8]);
#pragma unroll
        for (int nt = 0; nt < 4; ++nt)
            wf[nt] = *reinterpret_cast<const short8*>(&Ws[(nBase + nt * 16 + l15) * SA + quad * 8]);
#pragma unroll
        for (int mt = 0; mt < 4; ++mt)
#pragma unroll
            for (int nt = 0; nt < 4; ++nt)
                acc[mt][nt] = __builtin_amdgcn_mfma_f32_16x16x32_bf16(af[mt], wf[nt], acc[mt][nt], 0, 0, 0);
        __syncthreads();
    }

    // epilogue 1: H3 = relu(acc + b3) -> back into Hf (A of FC1)
    {
        float bb[4];
#pragma unroll
        for (int nt = 0; nt < 4; ++nt) bb[nt] = B3[nBase + nt * 16 + l15];
#pragma unroll
        for (int mt = 0; mt < 4; ++mt)
#pragma unroll
            for (int nt = 0; nt < 4; ++nt)
#pragma unroll
                for (int r4 = 0; r4 < 4; ++r4) {
                    int lrow = mBase + mt * 16 + quad * 4 + r4;
                    float v = fmaxf(acc[mt][nt][r4] + bb[nt], 0.f);
                    Hf[lrow * SAF + nBase + nt * 16 + l15] = f2bf(v);
                }
    }
    __syncthreads();

    // GEMM 2: H3 @ FW1
#pragma unroll
    for (int i = 0; i < 4; i++)
#pragma unroll
        for (int j = 0; j < 4; j++) acc[i][j] = zero4;
    for (int ks = 0; ks < 4; ++ks) {
        {
            const uint4* sh = reinterpret_cast<const uint4*>(F1hi + r * CH + ks * 32 + half * 16);
            uint4* dh = reinterpret_cast<uint4*>(&Ws[r * SA + half * 16]);
            dh[0] = sh[0]; dh[1] = sh[1];
        }
        __syncthreads();
        short8 af[4], wf[4];
#pragma unroll
        for (int mt = 0; mt < 4; ++mt)
            af[mt] = *reinterpret_cast<const short8*>(&Hf[(mBase + mt * 16 + l15) * SAF + ks * 32 + quad * 8]);
#pragma unroll
        for (int nt = 0; nt < 4; ++nt)
            wf[nt] = *reinterpret_cast<const short8*>(&Ws[(nBase + nt * 16 + l15) * SA + quad * 8]);
#pragma unroll
        for (int mt = 0; mt < 4; ++mt)
#pragma unroll
            for (int nt = 0; nt < 4; ++nt)
                acc[mt][nt] = __builtin_amdgcn_mfma_f32_16x16x32_bf16(af[mt], wf[nt], acc[mt][nt], 0, 0, 0);
        __syncthreads();
    }

    // FC2: per-row dot with fcW2 over this lane's 4 columns, reduce over l15
    {
        float bb[4];
#pragma unroll
        for (int nt = 0; nt < 4; ++nt) bb[nt] = FB1[nBase + nt * 16 + l15];
        float w20[4], w21[4];
#pragma unroll
        for (int nt = 0; nt < 4; ++nt) {
            float2 wv = *reinterpret_cast<const float2*>(FW2 + 2 * (nBase + nt * 16 + l15));
            w20[nt] = wv.x;
            w21[nt] = wv.y;
        }
#pragma unroll
        for (int mt = 0; mt < 4; ++mt)
#pragma unroll
            for (int r4 = 0; r4 < 4; ++r4) {
                float d0 = 0.f, d1 = 0.f;
#pragma unroll
                for (int nt = 0; nt < 4; ++nt) {
                    float v = fmaxf(acc[mt][nt][r4] + bb[nt], 0.f);
                    d0 += v * w20[nt];
                    d1 += v * w21[nt];
                }
#pragma unroll
                for (int m = 8; m >= 1; m >>= 1) {
                    d0 += __shfl_xor(d0, m, 64);
                    d1 += __shfl_xor(d1, m, 64);
                }
                if (l15 == 0) {
                    int lrow = mBase + mt * 16 + quad * 4 + r4;
                    rp0[lrow * 2 + (wave & 1)] = d0;
                    rp1[lrow * 2 + (wave & 1)] = d1;
                }
            }
    }
    if (tid < 192) ls[tid] = 0.f;
    __syncthreads();

    if (tid < 128) {
        int node = row0 + tid;
        if (node < N) {
            float d0 = rp0[tid * 2] + rp0[tid * 2 + 1] + FB2[0];
            float d1 = rp1[tid * 2] + rp1[tid * 2 + 1] + FB2[1];
            int g = batch[node];
            atomicAdd(&ls[g], d0);
            atomicAdd(&ls[64 + g], d1);
            atomicAdd(&ls[128 + g], 1.0f);
        }
    }
    __syncthreads();
    if (tid < 64) {
        float c = ls[128 + tid];
        if (c != 0.f) {
            atomicAdd(&sums[2 * tid], ls[tid]);
            atomicAdd(&sums[2 * tid + 1], ls[64 + tid]);
            atomicAdd(&cnts[tid], c);
        }
    }
}

__global__ void k_softmax(const float* __restrict__ sums, const float* __restrict__ cnts,
                          float* __restrict__ out, int G) {
    int g = blockIdx.x * blockDim.x + threadIdx.x;
    if (g < G) {
        float c = fmaxf(cnts[g], 1.0f);
        float p0 = sums[2 * g] / c;
        float p1 = sums[2 * g + 1] / c;
        float m = fmaxf(p0, p1);
        float e0 = expf(p0 - m), e1 = expf(p1 - m);
        float inv = 1.f / (e0 + e1);
        out[2 * g] = e0 * inv;
        out[2 * g + 1] = e1 * inv;
    }
}

// ---------------------------------------------------------------------------
extern "C" void kernel_launch(void* const* d_in, const int* in_sizes, int n_in,
                              void* d_out, int out_size, void* d_ws, size_t ws_size,
                              hipStream_t stream) {
    const float* X   = (const float*)d_in[0];
    const int* EI    = (const int*)d_in[1];
    const int* BATCH = (const int*)d_in[2];
    const float* W1  = (const float*)d_in[3];
    const float* B1  = (const float*)d_in[4];
    const float* W2  = (const float*)d_in[5];
    const float* B2  = (const float*)d_in[6];
    const float* W3  = (const float*)d_in[7];
    const float* B3  = (const float*)d_in[8];
    const float* FW1 = (const float*)d_in[9];
    const float* FB1 = (const float*)d_in[10];
    const float* FW2 = (const float*)d_in[11];
    const float* FB2 = (const float*)d_in[12];

    const int N = in_sizes[0] / CH;
    const int E = in_sizes[1] / 2;
    const int G = out_size / 2;
    const int* rowp = EI;
    const int* colp = EI + E;
    const int NB = (N + 127) >> BSH;

    char* w = (char*)d_ws;
    auto alloc = [&](size_t bytes) -> char* {
        char* p = w;
        w += (bytes + 255) & ~(size_t)255;
        return p;
    };
    ucharT*  Zlo   = (ucharT*)alloc((size_t)N * 64);        // fp8 Z lo half
    ucharT*  Zhi   = (ucharT*)alloc((size_t)N * 64);        // fp8 Z hi half
    ucharT*  Hlo   = (ucharT*)alloc((size_t)N * 64);        // fp8 H lo half
    ucharT*  Hhi   = (ucharT*)alloc((size_t)N * 64);        // fp8 H hi half
    ucharT*  Xlo   = (ucharT*)alloc((size_t)N * 64);        // fp8 X lo half
    ucharT*  Xhi   = (ucharT*)alloc((size_t)N * 64);        // fp8 X hi half
    ushortT* WhiA  = (ushortT*)alloc((size_t)4 * 16384 * 2);
    float* invs    = (float*)alloc((size_t)N * 4);
    int*   indptr  = (int*)alloc((size_t)(N + 1) * 4);
    uintT* epack   = (uintT*)alloc((size_t)E * 4);
    uintT* seg     = (uintT*)alloc((size_t)NB * SEG * 4);
    int*   bfill   = (int*)alloc((size_t)NB * 4);
    int*   bbase   = (int*)alloc((size_t)NB * 4);
    float* sums    = (float*)alloc((size_t)G * 3 * 4);      // sums | cnts
    float* cnts    = sums + 2 * G;

    const int nbHalf = (N + 31) / 32;                       // node blocks per half
    const int nbAgg  = ((nbHalf + 3) / 4) * 8;              // %8 XCD-grouped grid
    const int nbGemm = (N + 127) / 128;
    const int nbBin  = (E + EPW - 1) / EPW;
    const int total4 = N * CH / 4;
    const int nbSP   = NB + 256 + (total4 + 255) / 256;

    k_zero<<<1, 256, 0, stream>>>(bfill, NB, sums, 3 * G);
    k_bin<<<nbBin, 256, 0, stream>>>(rowp, colp, bfill, seg, E, NB);
    k_binvs_bscan<<<NB + 1, 512, 0, stream>>>(bfill, seg, invs, bbase, indptr, NB, N, E);
    k_scatterprep<<<nbSP, 256, 0, stream>>>(bfill, bbase, seg, invs, indptr, epack,
                                            X, Xlo, Xhi, W1, W2, W3, FW1, WhiA,
                                            N, NB, total4);

    // layer 1
    k_agg<<<nbAgg, 256, 0, stream>>>(Xlo, Xhi, epack, indptr, invs, Zlo, Zhi, N, nbHalf);
    k_gemm<<<nbGemm, 256, 0, stream>>>(Zlo, Zhi, WhiA, B1, Hlo, Hhi, N);
    // layer 2
    k_agg<<<nbAgg, 256, 0, stream>>>(Hlo, Hhi, epack, indptr, invs, Zlo, Zhi, N, nbHalf);
    k_gemm<<<nbGemm, 256, 0, stream>>>(Zlo, Zhi, WhiA + 16384, B2, Hlo, Hhi, N);
    // layer 3 agg, then fused tail (GEMM W3 + FC1 + FC2 + pool)
    k_agg<<<nbAgg, 256, 0, stream>>>(Hlo, Hhi, epack, indptr, invs, Zlo, Zhi, N, nbHalf);
    k_tail<<<nbGemm, 256, 0, stream>>>(Zlo, Zhi, WhiA + 2 * 16384, B3,
                                       WhiA + 3 * 16384, FB1, FW2, FB2,
                                       BATCH, sums, cnts, N);
    k_softmax<<<1, 64, 0, stream>>>(sums, cnts, (float*)d_out, G);
}

// Round 14
// 209.900 us; speedup vs baseline: 1.9712x; 1.0015x over previous
//
#include <hip/hip_runtime.h>

// ---------------------------------------------------------------------------
// colorableGNN: 3x GCN(128->128) + FC(128->128) + FC(128->2) + mean-pool + softmax
// R13 (delta vs R12): k_agg latency-chain fixes -- (1) software-pipelined
// edge blocks (prefetch e[next] during gather/compute of current: 2 round
// trips -> ~1 per block); (2) masked vector remainder (trailing <8 edges in
// ONE masked block instead of up to 7 serial scalar iterations: the scalar
// tail was ~7 RTs/node, dominating); (3) k_zero dropped (memsetAsync bfill,
// sums/cnts zeroed in bscan). R12's XCD half-split kept (neutral, harmless).
// fp8 acts, 4B edges, bf16 weights, fp32 acc.
// NOTE: gather kernels need occupancy; never fuse agg into GEMM (R7: 104us).
// ---------------------------------------------------------------------------

#define CH 128
#define BSH 7              // 128 dst nodes per bucket
#define SEG 4096           // segment capacity (records) per bucket
#define EPW 4096           // edges per phase-1 workgroup
#define SA 40              // LDS stride for W chunks (shorts)
#define SAF 136            // LDS stride full-K A tile (shorts; 272B = 17*16B)
#define SC 132             // bf16 epilogue stride (shorts)
#define SC8 144            // fp8 epilogue stride (bytes)

typedef unsigned short ushortT;
typedef unsigned int uintT;
typedef unsigned char ucharT;
typedef __attribute__((ext_vector_type(8))) short short8;
typedef __attribute__((ext_vector_type(4))) float floatx4;
typedef __attribute__((ext_vector_type(2))) float floatx2;

__device__ __forceinline__ float bf2f(uintT u) {
    return __uint_as_float(u << 16);
}
__device__ __forceinline__ ushortT f2bf(float f) {
    uintT x = __float_as_uint(f);
    return (ushortT)((x + 0x7fffu + ((x >> 16) & 1u)) >> 16);
}
__device__ __forceinline__ void dec4(uintT u, float* o) {
    floatx2 lo = __builtin_amdgcn_cvt_pk_f32_fp8((int)u, false);
    floatx2 hi = __builtin_amdgcn_cvt_pk_f32_fp8((int)u, true);
    o[0] = lo.x; o[1] = lo.y; o[2] = hi.x; o[3] = hi.y;
}

// ---- phase 1: bin edges into dst-buckets; records packed src|(dst<<16) ----
__global__ __launch_bounds__(256) void k_bin(const int* __restrict__ row,
                                             const int* __restrict__ col,
                                             int* __restrict__ bfill,
                                             uintT* __restrict__ seg,
                                             int E, int NB) {
    __shared__ uintT staged[EPW];   // 16 KB
    __shared__ int target[EPW];     // 16 KB
    __shared__ int sval[512];
    __shared__ int horig[512];
    __shared__ int pcnt[512];
    __shared__ int gbase[512];
    const int t = threadIdx.x;
    const int e0 = blockIdx.x * EPW;
    const int cnt = min(EPW, E - e0);

    sval[t] = 0; sval[t + 256] = 0;
    __syncthreads();

    int er[16], ec[16];
#pragma unroll
    for (int i = 0; i < 16; ++i) {
        int le = i * 256 + t;
        if (le < cnt) {
            er[i] = row[e0 + le];
            ec[i] = col[e0 + le];
            atomicAdd(&sval[ec[i] >> BSH], 1);
        }
    }
    __syncthreads();
    horig[t] = sval[t]; horig[t + 256] = sval[t + 256];
    __syncthreads();
    for (int off = 1; off < 512; off <<= 1) {
        int a = (t >= off) ? sval[t - off] : 0;
        int b2 = sval[t + 256 - off];
        __syncthreads();
        sval[t] += a;
        sval[t + 256] += b2;
        __syncthreads();
    }
    for (int b = t; b < 512; b += 256) {
        int h = horig[b];
        pcnt[b] = sval[b] - h;
        gbase[b] = (h > 0 && b < NB) ? atomicAdd(&bfill[b], h) : 0;
    }
    __syncthreads();
#pragma unroll
    for (int i = 0; i < 16; ++i) {
        int le = i * 256 + t;
        if (le < cnt) {
            int b = ec[i] >> BSH;
            int j = atomicAdd(&pcnt[b], 1);
            staged[j] = (uintT)er[i] | ((uintT)ec[i] << 16);
            int lo = sval[b] - horig[b];
            target[j] = b * SEG + gbase[b] + (j - lo);
        }
    }
    __syncthreads();
    for (int s = t; s < cnt; s += 256) seg[target[s]] = staged[s];
}

// ---- fused: per-bucket degree->invs (0..NB-1) + bucket scan + zero pools --
__global__ __launch_bounds__(512) void k_binvs_bscan(const int* __restrict__ bfill,
                                                     const uintT* __restrict__ seg,
                                                     float* __restrict__ invs,
                                                     int* __restrict__ bbase,
                                                     int* __restrict__ indptr,
                                                     float* __restrict__ sums,
                                                     float* __restrict__ cnts,
                                                     int NB, int N, int E, int G) {
    const int b = blockIdx.x;
    const int t = threadIdx.x;
    if (b < NB) {
        __shared__ int h[128];
        if (t < 128) h[t] = 0;
        __syncthreads();
        int cnt = bfill[b];
        const uintT* sp = seg + (size_t)b * SEG;
        for (int s = t; s < cnt; s += 512) atomicAdd(&h[(sp[s] >> 16) & 127], 1);
        __syncthreads();
        int d = b * 128 + t;
        if (t < 128 && d < N) invs[d] = rsqrtf((float)h[t] + 1.0f);
    } else {
        __shared__ int s[512];
        for (int i = t; i < 3 * G; i += 512) {
            if (i < 2 * G) sums[i] = 0.f;
            else cnts[i - 2 * G] = 0.f;
        }
        int v = (t < NB) ? bfill[t] : 0;
        s[t] = v;
        __syncthreads();
        for (int off = 1; off < 512; off <<= 1) {
            int a = (t >= off) ? s[t - off] : 0;
            __syncthreads();
            s[t] += a;
            __syncthreads();
        }
        if (t < NB) bbase[t] = s[t] - v;  // exclusive
        if (t == 0) indptr[N] = E;
    }
}

// ---- heterogeneous: CSR scatter | weight prep | X->fp8 (split halves) -----
__global__ __launch_bounds__(256) void k_scatterprep(const int* __restrict__ bfill,
                                                     const int* __restrict__ bbase,
                                                     const uintT* __restrict__ seg,
                                                     const float* __restrict__ invs,
                                                     int* __restrict__ indptr,
                                                     uintT* __restrict__ epack,
                                                     const float* __restrict__ X,
                                                     ucharT* __restrict__ Xlo,
                                                     ucharT* __restrict__ Xhi,
                                                     const float* __restrict__ w0,
                                                     const float* __restrict__ w1,
                                                     const float* __restrict__ w2,
                                                     const float* __restrict__ w3,
                                                     ushortT* __restrict__ Whi,
                                                     int N, int NB, int total4) {
    const int t = threadIdx.x;
    if ((int)blockIdx.x < NB) {
        __shared__ uintT staged[SEG];   // 16 KB
        __shared__ int h[128];
        __shared__ int sc[128];
        __shared__ int pc[128];
        const int b = blockIdx.x;
        const int cnt = bfill[b];
        const int base = bbase[b];
        const uintT* sp = seg + (size_t)b * SEG;

        if (t < 128) h[t] = 0;
        __syncthreads();
        for (int s = t; s < cnt; s += 256) atomicAdd(&h[(sp[s] >> 16) & 127], 1);
        __syncthreads();
        if (t < 128) sc[t] = h[t];
        __syncthreads();
        for (int off = 1; off < 128; off <<= 1) {
            int a = (t >= off && t < 128) ? sc[t - off] : 0;
            __syncthreads();
            if (t < 128) sc[t] += a;
            __syncthreads();
        }
        if (t < 128) {
            int excl = sc[t] - h[t];
            pc[t] = excl;
            int d = b * 128 + t;
            if (d < N) indptr[d] = base + excl;
        }
        __syncthreads();
        for (int s = t; s < cnt; s += 256) {
            uintT rc = sp[s];
            int src = (int)(rc & 0xffffu), dst = (int)(rc >> 16);
            int j = atomicAdd(&pc[dst & 127], 1);
            float nrm = invs[src] * invs[dst];
            staged[j] = (uintT)src | ((uintT)f2bf(nrm) << 16);
        }
        __syncthreads();
        for (int s = t; s < cnt; s += 256) epack[base + s] = staged[s];
    } else if ((int)blockIdx.x < NB + 256) {
        int idx = (blockIdx.x - NB) * 256 + t;  // 0..65535
        int m = idx >> 14;
        int r = idx & 16383;
        int n = r >> 7;
        int k = r & 127;
        const float* W = (m == 0) ? w0 : (m == 1) ? w1 : (m == 2) ? w2 : w3;
        Whi[m * 16384 + n * CH + k] = f2bf(W[k * CH + n]);
    } else {
        int i = (blockIdx.x - NB - 256) * 256 + t;  // float4-group index
        if (i < total4) {
            float4 v = reinterpret_cast<const float4*>(X)[i];
            int r0 = __builtin_amdgcn_cvt_pk_fp8_f32(v.x, v.y, 0, false);
            int r1 = __builtin_amdgcn_cvt_pk_fp8_f32(v.z, v.w, r0, true);
            int node = i >> 5;       // 32 dword-groups per 128-ch row
            int g = i & 31;
            int* dst = (g < 16) ? reinterpret_cast<int*>(Xlo + (size_t)node * 64) + g
                                : reinterpret_cast<int*>(Xhi + (size_t)node * 64) + (g - 16);
            *dst = r1;
        }
    }
}

// ---- aggregation: channel-half per block; pipelined + masked-tail gather --
// 8 lanes/node x 8ch (uint2); wave = 8 nodes -> 8 independent edge streams.
__global__ __launch_bounds__(256) void k_agg(const ucharT* __restrict__ Hlo,
                                             const ucharT* __restrict__ Hhi,
                                             const uintT* __restrict__ epack,
                                             const int* __restrict__ indptr,
                                             const float* __restrict__ invs,
                                             ucharT* __restrict__ Zlo,
                                             ucharT* __restrict__ Zhi,
                                             int N, int nbHalf) {
    const int half = (blockIdx.x >> 2) & 1;       // XCDs 0-3 -> lo, 4-7 -> hi
    const int nb = (blockIdx.x >> 3) * 4 + (blockIdx.x & 3);
    if (nb >= nbHalf) return;
    const int wave = threadIdx.x >> 6, lane = threadIdx.x & 63;
    const int ng = lane >> 3;        // node slot 0..7
    const int l = lane & 7;          // 8 channels each (uint2)
    const int node = nb * 32 + wave * 8 + ng;
    if (node >= N) return;

    const uint2* H2 = reinterpret_cast<const uint2*>(half ? Hhi : Hlo);

    float acc[8];
    {
        float sn = invs[node];
        float sn2 = sn * sn;
        uint2 h = H2[(size_t)node * 8 + l];
        float d[8];
        dec4(h.x, d); dec4(h.y, d + 4);
#pragma unroll
        for (int j = 0; j < 8; ++j) acc[j] = sn2 * d[j];
    }

    int p = indptr[node];
    int p1 = indptr[node + 1];

    if (p + 8 <= p1) {
        uintT e0[8];
#pragma unroll
        for (int i = 0; i < 8; ++i) e0[i] = epack[p + i];
        // pipelined: prefetch next e-block while gathering/computing current
        for (; p + 16 <= p1; p += 8) {
            uintT e1[8];
#pragma unroll
            for (int i = 0; i < 8; ++i) e1[i] = epack[p + 8 + i];
            uint2 g[8];
#pragma unroll
            for (int i = 0; i < 8; ++i) g[i] = H2[(size_t)(int)(e0[i] & 0xffffu) * 8 + l];
#pragma unroll
            for (int i = 0; i < 8; ++i) {
                float wv = bf2f(e0[i] >> 16);
                float d[8];
                dec4(g[i].x, d); dec4(g[i].y, d + 4);
#pragma unroll
                for (int j = 0; j < 8; ++j) acc[j] += wv * d[j];
            }
#pragma unroll
            for (int i = 0; i < 8; ++i) e0[i] = e1[i];
        }
        // drain last full block
        {
            uint2 g[8];
#pragma unroll
            for (int i = 0; i < 8; ++i) g[i] = H2[(size_t)(int)(e0[i] & 0xffffu) * 8 + l];
#pragma unroll
            for (int i = 0; i < 8; ++i) {
                float wv = bf2f(e0[i] >> 16);
                float d[8];
                dec4(g[i].x, d); dec4(g[i].y, d + 4);
#pragma unroll
                for (int j = 0; j < 8; ++j) acc[j] += wv * d[j];
            }
            p += 8;
        }
    }
    // masked vector remainder: trailing <8 edges in ONE block (dup addr, 0 wt)
    int rem = p1 - p;
    if (rem > 0) {
        uintT e[8];
#pragma unroll
        for (int i = 0; i < 8; ++i) e[i] = epack[(i < rem) ? p + i : p];
        uint2 g[8];
#pragma unroll
        for (int i = 0; i < 8; ++i) g[i] = H2[(size_t)(int)(e[i] & 0xffffu) * 8 + l];
#pragma unroll
        for (int i = 0; i < 8; ++i) {
            float wv = (i < rem) ? bf2f(e[i] >> 16) : 0.f;
            float d[8];
            dec4(g[i].x, d); dec4(g[i].y, d + 4);
#pragma unroll
            for (int j = 0; j < 8; ++j) acc[j] += wv * d[j];
        }
    }

    uint2 o;
    {
        int r0 = __builtin_amdgcn_cvt_pk_fp8_f32(acc[0], acc[1], 0, false);
        r0 = __builtin_amdgcn_cvt_pk_fp8_f32(acc[2], acc[3], r0, true);
        int r1 = __builtin_amdgcn_cvt_pk_fp8_f32(acc[4], acc[5], 0, false);
        r1 = __builtin_amdgcn_cvt_pk_fp8_f32(acc[6], acc[7], r1, true);
        o.x = (uintT)r0; o.y = (uintT)r1;
    }
    reinterpret_cast<uint2*>(half ? Zhi : Zlo)[(size_t)node * 8 + l] = o;
}

// ---- MFMA GEMM (GCN layers 1,2): fp8 halves in/out, single bf16 W ---------
__global__ __launch_bounds__(256) void k_gemm(const ucharT* __restrict__ Inlo,
                                              const ucharT* __restrict__ Inhi,
                                              const ushortT* __restrict__ Whi,
                                              const float* __restrict__ Bias,
                                              ucharT* __restrict__ Outlo,
                                              ucharT* __restrict__ Outhi, int N) {
    __shared__ ushortT smem[128 * SC];  // 33792 B union
    ushortT* As = smem;
    ushortT* Ws = smem + 128 * SA;
    ushortT* Cs = smem;                  // epilogue alias

    const int tid = threadIdx.x;
    const int wave = tid >> 6, lane = tid & 63;
    const int quad = lane >> 4, l15 = lane & 15;
    const int mBase = (wave >> 1) * 64, nBase = (wave & 1) * 64;
    const int row0 = blockIdx.x * 128;
    const int r = tid >> 1, half = tid & 1;

    floatx4 acc[4][4];
    const floatx4 zero4 = {0.f, 0.f, 0.f, 0.f};
#pragma unroll
    for (int i = 0; i < 4; i++)
#pragma unroll
        for (int j = 0; j < 4; j++) acc[i][j] = zero4;

    for (int ks = 0; ks < 4; ++ks) {
        {
            int grow = row0 + r;
            const ucharT* sbase = (ks < 2) ? Inlo : Inhi;
            uint4 a8 = {0, 0, 0, 0};
            if (grow < N)
                a8 = *reinterpret_cast<const uint4*>(
                    sbase + (size_t)grow * 64 + (ks & 1) * 32 + half * 16);
            uintT wds[4] = {a8.x, a8.y, a8.z, a8.w};
            uintT ob[8];
#pragma unroll
            for (int q = 0; q < 4; ++q) {
                float d[4];
                dec4(wds[q], d);
                ob[2 * q] = (uintT)f2bf(d[0]) | ((uintT)f2bf(d[1]) << 16);
                ob[2 * q + 1] = (uintT)f2bf(d[2]) | ((uintT)f2bf(d[3]) << 16);
            }
            uint4* dd = reinterpret_cast<uint4*>(&As[r * SA + half * 16]);
            dd[0] = uint4{ob[0], ob[1], ob[2], ob[3]};
            dd[1] = uint4{ob[4], ob[5], ob[6], ob[7]};
            const uint4* sh = reinterpret_cast<const uint4*>(Whi + r * CH + ks * 32 + half * 16);
            uint4* dh = reinterpret_cast<uint4*>(&Ws[r * SA + half * 16]);
            dh[0] = sh[0]; dh[1] = sh[1];
        }
        __syncthreads();

        short8 af[4], wf[4];
#pragma unroll
        for (int mt = 0; mt < 4; ++mt)
            af[mt] = *reinterpret_cast<const short8*>(&As[(mBase + mt * 16 + l15) * SA + quad * 8]);
#pragma unroll
        for (int nt = 0; nt < 4; ++nt)
            wf[nt] = *reinterpret_cast<const short8*>(&Ws[(nBase + nt * 16 + l15) * SA + quad * 8]);
#pragma unroll
        for (int mt = 0; mt < 4; ++mt)
#pragma unroll
            for (int nt = 0; nt < 4; ++nt)
                acc[mt][nt] = __builtin_amdgcn_mfma_f32_16x16x32_bf16(af[mt], wf[nt], acc[mt][nt], 0, 0, 0);
        __syncthreads();
    }

    float bb[4];
#pragma unroll
    for (int nt = 0; nt < 4; ++nt) bb[nt] = Bias[nBase + nt * 16 + l15];

    ucharT* Cs8 = reinterpret_cast<ucharT*>(Cs);
#pragma unroll
    for (int mt = 0; mt < 4; ++mt)
#pragma unroll
        for (int nt = 0; nt < 4; ++nt)
#pragma unroll
            for (int r4 = 0; r4 < 4; ++r4) {
                int lrow = mBase + mt * 16 + quad * 4 + r4;
                float v = fmaxf(acc[mt][nt][r4] + bb[nt], 0.f);
                int f8 = __builtin_amdgcn_cvt_pk_fp8_f32(v, 0.f, 0, false);
                Cs8[lrow * SC8 + nBase + nt * 16 + l15] = (ucharT)(f8 & 0xff);
            }
    __syncthreads();
    {
        int grow = row0 + r;
        if (grow < N) {
            const uint4* s4 = reinterpret_cast<const uint4*>(&Cs8[r * SC8 + half * 64]);
            ucharT* obase = half ? Outhi : Outlo;
            uint4* dst = reinterpret_cast<uint4*>(obase + (size_t)grow * 64);
#pragma unroll
            for (int q = 0; q < 4; ++q) dst[q] = s4[q];
        }
    }
}

// ---- fused tail: GEMM(W3) -> relu -> GEMM(FW1) -> FC2 -> mean-pool --------
// No gather inside (R7 lesson); H3 tile lives in LDS (Hf), never in HBM.
__global__ __launch_bounds__(256) void k_tail(const ucharT* __restrict__ Zlo,
                                              const ucharT* __restrict__ Zhi,
                                              const ushortT* __restrict__ W3hi,
                                              const float* __restrict__ B3,
                                              const ushortT* __restrict__ F1hi,
                                              const float* __restrict__ FB1,
                                              const float* __restrict__ FW2,
                                              const float* __restrict__ FB2,
                                              const int* __restrict__ batch,
                                              float* __restrict__ sums,
                                              float* __restrict__ cnts, int N) {
    __shared__ ushortT Hf[128 * SAF];   // 34816 B: A-tile (Z), then H3 tile
    __shared__ ushortT Ws[128 * SA];    // 10240 B
    __shared__ float rp0[256];
    __shared__ float rp1[256];
    __shared__ float ls[192];

    const int tid = threadIdx.x;
    const int wave = tid >> 6, lane = tid & 63;
    const int quad = lane >> 4, l15 = lane & 15;
    const int mBase = (wave >> 1) * 64, nBase = (wave & 1) * 64;
    const int row0 = blockIdx.x * 128;
    const int r = tid >> 1, half = tid & 1;

    // stage full Z tile: fp8 halves -> bf16 into Hf (64 B = one half per thread)
    {
        int grow = row0 + r;
        const ucharT* zsrc = half ? Zhi : Zlo;
        uint4 a8 = {0, 0, 0, 0}, b8 = {0, 0, 0, 0}, c8 = {0, 0, 0, 0}, d8v = {0, 0, 0, 0};
        if (grow < N) {
            const uint4* s = reinterpret_cast<const uint4*>(zsrc + (size_t)grow * 64);
            a8 = s[0]; b8 = s[1]; c8 = s[2]; d8v = s[3];
        }
        uintT wds[16] = {a8.x, a8.y, a8.z, a8.w, b8.x, b8.y, b8.z, b8.w,
                         c8.x, c8.y, c8.z, c8.w, d8v.x, d8v.y, d8v.z, d8v.w};
#pragma unroll
        for (int q = 0; q < 16; ++q) {
            float d[4];
            dec4(wds[q], d);
            uint2 o;
            o.x = (uintT)f2bf(d[0]) | ((uintT)f2bf(d[1]) << 16);
            o.y = (uintT)f2bf(d[2]) | ((uintT)f2bf(d[3]) << 16);
            *reinterpret_cast<uint2*>(&Hf[r * SAF + half * 64 + q * 4]) = o;
        }
    }

    floatx4 acc[4][4];
    const floatx4 zero4 = {0.f, 0.f, 0.f, 0.f};
#pragma unroll
    for (int i = 0; i < 4; i++)
#pragma unroll
        for (int j = 0; j < 4; j++) acc[i][j] = zero4;

    // GEMM 1: Z @ W3
    for (int ks = 0; ks < 4; ++ks) {
        {
            const uint4* sh = reinterpret_cast<const uint4*>(W3hi + r * CH + ks * 32 + half * 16);
            uint4* dh = reinterpret_cast<uint4*>(&Ws[r * SA + half * 16]);
            dh[0] = sh[0]; dh[1] = sh[1];
        }
        __syncthreads();
        short8 af[4], wf[4];
#pragma unroll
        for (int mt = 0; mt < 4; ++mt)
            af[mt] = *reinterpret_cast<const short8*>(&Hf[(mBase + mt * 16 + l15) * SAF + ks * 32 + quad * 8]);
#pragma unroll
        for (int nt = 0; nt < 4; ++nt)
            wf[nt] = *reinterpret_cast<const short8*>(&Ws[(nBase + nt * 16 + l15) * SA + quad * 8]);
#pragma unroll
        for (int mt = 0; mt < 4; ++mt)
#pragma unroll
            for (int nt = 0; nt < 4; ++nt)
                acc[mt][nt] = __builtin_amdgcn_mfma_f32_16x16x32_bf16(af[mt], wf[nt], acc[mt][nt], 0, 0, 0);
        __syncthreads();
    }

    // epilogue 1: H3 = relu(acc + b3) -> back into Hf (A of FC1)
    {
        float bb[4];
#pragma unroll
        for (int nt = 0; nt < 4; ++nt) bb[nt] = B3[nBase + nt * 16 + l15];
#pragma unroll
        for (int mt = 0; mt < 4; ++mt)
#pragma unroll
            for (int nt = 0; nt < 4; ++nt)
#pragma unroll
                for (int r4 = 0; r4 < 4; ++r4) {
                    int lrow = mBase + mt * 16 + quad * 4 + r4;
                    float v = fmaxf(acc[mt][nt][r4] + bb[nt], 0.f);
                    Hf[lrow * SAF + nBase + nt * 16 + l15] = f2bf(v);
                }
    }
    __syncthreads();

    // GEMM 2: H3 @ FW1
#pragma unroll
    for (int i = 0; i < 4; i++)
#pragma unroll
        for (int j = 0; j < 4; j++) acc[i][j] = zero4;
    for (int ks = 0; ks < 4; ++ks) {
        {
            const uint4* sh = reinterpret_cast<const uint4*>(F1hi + r * CH + ks * 32 + half * 16);
            uint4* dh = reinterpret_cast<uint4*>(&Ws[r * SA + half * 16]);
            dh[0] = sh[0]; dh[1] = sh[1];
        }
        __syncthreads();
        short8 af[4], wf[4];
#pragma unroll
        for (int mt = 0; mt < 4; ++mt)
            af[mt] = *reinterpret_cast<const short8*>(&Hf[(mBase + mt * 16 + l15) * SAF + ks * 32 + quad * 8]);
#pragma unroll
        for (int nt = 0; nt < 4; ++nt)
            wf[nt] = *reinterpret_cast<const short8*>(&Ws[(nBase + nt * 16 + l15) * SA + quad * 8]);
#pragma unroll
        for (int mt = 0; mt < 4; ++mt)
#pragma unroll
            for (int nt = 0; nt < 4; ++nt)
                acc[mt][nt] = __builtin_amdgcn_mfma_f32_16x16x32_bf16(af[mt], wf[nt], acc[mt][nt], 0, 0, 0);
        __syncthreads();
    }

    // FC2: per-row dot with fcW2 over this lane's 4 columns, reduce over l15
    {
        float bb[4];
#pragma unroll
        for (int nt = 0; nt < 4; ++nt) bb[nt] = FB1[nBase + nt * 16 + l15];
        float w20[4], w21[4];
#pragma unroll
        for (int nt = 0; nt < 4; ++nt) {
            float2 wv = *reinterpret_cast<const float2*>(FW2 + 2 * (nBase + nt * 16 + l15));
            w20[nt] = wv.x;
            w21[nt] = wv.y;
        }
#pragma unroll
        for (int mt = 0; mt < 4; ++mt)
#pragma unroll
            for (int r4 = 0; r4 < 4; ++r4) {
                float d0 = 0.f, d1 = 0.f;
#pragma unroll
                for (int nt = 0; nt < 4; ++nt) {
                    float v = fmaxf(acc[mt][nt][r4] + bb[nt], 0.f);
                    d0 += v * w20[nt];
                    d1 += v * w21[nt];
                }
#pragma unroll
                for (int m = 8; m >= 1; m >>= 1) {
                    d0 += __shfl_xor(d0, m, 64);
                    d1 += __shfl_xor(d1, m, 64);
                }
                if (l15 == 0) {
                    int lrow = mBase + mt * 16 + quad * 4 + r4;
                    rp0[lrow * 2 + (wave & 1)] = d0;
                    rp1[lrow * 2 + (wave & 1)] = d1;
                }
            }
    }
    if (tid < 192) ls[tid] = 0.f;
    __syncthreads();

    if (tid < 128) {
        int node = row0 + tid;
        if (node < N) {
            float d0 = rp0[tid * 2] + rp0[tid * 2 + 1] + FB2[0];
            float d1 = rp1[tid * 2] + rp1[tid * 2 + 1] + FB2[1];
            int g = batch[node];
            atomicAdd(&ls[g], d0);
            atomicAdd(&ls[64 + g], d1);
            atomicAdd(&ls[128 + g], 1.0f);
        }
    }
    __syncthreads();
    if (tid < 64) {
        float c = ls[128 + tid];
        if (c != 0.f) {
            atomicAdd(&sums[2 * tid], ls[tid]);
            atomicAdd(&sums[2 * tid + 1], ls[64 + tid]);
            atomicAdd(&cnts[tid], c);
        }
    }
}

__global__ void k_softmax(const float* __restrict__ sums, const float* __restrict__ cnts,
                          float* __restrict__ out, int G) {
    int g = blockIdx.x * blockDim.x + threadIdx.x;
    if (g < G) {
        float c = fmaxf(cnts[g], 1.0f);
        float p0 = sums[2 * g] / c;
        float p1 = sums[2 * g + 1] / c;
        float m = fmaxf(p0, p1);
        float e0 = expf(p0 - m), e1 = expf(p1 - m);
        float inv = 1.f / (e0 + e1);
        out[2 * g] = e0 * inv;
        out[2 * g + 1] = e1 * inv;
    }
}

// ---------------------------------------------------------------------------
extern "C" void kernel_launch(void* const* d_in, const int* in_sizes, int n_in,
                              void* d_out, int out_size, void* d_ws, size_t ws_size,
                              hipStream_t stream) {
    const float* X   = (const float*)d_in[0];
    const int* EI    = (const int*)d_in[1];
    const int* BATCH = (const int*)d_in[2];
    const float* W1  = (const float*)d_in[3];
    const float* B1  = (const float*)d_in[4];
    const float* W2  = (const float*)d_in[5];
    const float* B2  = (const float*)d_in[6];
    const float* W3  = (const float*)d_in[7];
    const float* B3  = (const float*)d_in[8];
    const float* FW1 = (const float*)d_in[9];
    const float* FB1 = (const float*)d_in[10];
    const float* FW2 = (const float*)d_in[11];
    const float* FB2 = (const float*)d_in[12];

    const int N = in_sizes[0] / CH;
    const int E = in_sizes[1] / 2;
    const int G = out_size / 2;
    const int* rowp = EI;
    const int* colp = EI + E;
    const int NB = (N + 127) >> BSH;

    char* w = (char*)d_ws;
    auto alloc = [&](size_t bytes) -> char* {
        char* p = w;
        w += (bytes + 255) & ~(size_t)255;
        return p;
    };
    ucharT*  Zlo   = (ucharT*)alloc((size_t)N * 64);        // fp8 Z lo half
    ucharT*  Zhi   = (ucharT*)alloc((size_t)N * 64);        // fp8 Z hi half
    ucharT*  Hlo   = (ucharT*)alloc((size_t)N * 64);        // fp8 H lo half
    ucharT*  Hhi   = (ucharT*)alloc((size_t)N * 64);        // fp8 H hi half
    ucharT*  Xlo   = (ucharT*)alloc((size_t)N * 64);        // fp8 X lo half
    ucharT*  Xhi   = (ucharT*)alloc((size_t)N * 64);        // fp8 X hi half
    ushortT* WhiA  = (ushortT*)alloc((size_t)4 * 16384 * 2);
    float* invs    = (float*)alloc((size_t)N * 4);
    int*   indptr  = (int*)alloc((size_t)(N + 1) * 4);
    uintT* epack   = (uintT*)alloc((size_t)E * 4);
    uintT* seg     = (uintT*)alloc((size_t)NB * SEG * 4);
    int*   bfill   = (int*)alloc((size_t)NB * 4);
    int*   bbase   = (int*)alloc((size_t)NB * 4);
    float* sums    = (float*)alloc((size_t)G * 3 * 4);      // sums | cnts
    float* cnts    = sums + 2 * G;

    const int nbHalf = (N + 31) / 32;                       // node blocks per half
    const int nbAgg  = ((nbHalf + 3) / 4) * 8;              // %8 XCD-grouped grid
    const int nbGemm = (N + 127) / 128;
    const int nbBin  = (E + EPW - 1) / EPW;
    const int total4 = N * CH / 4;
    const int nbSP   = NB + 256 + (total4 + 255) / 256;

    hipMemsetAsync(bfill, 0, (size_t)NB * 4, stream);
    k_bin<<<nbBin, 256, 0, stream>>>(rowp, colp, bfill, seg, E, NB);
    k_binvs_bscan<<<NB + 1, 512, 0, stream>>>(bfill, seg, invs, bbase, indptr,
                                              sums, cnts, NB, N, E, G);
    k_scatterprep<<<nbSP, 256, 0, stream>>>(bfill, bbase, seg, invs, indptr, epack,
                                            X, Xlo, Xhi, W1, W2, W3, FW1, WhiA,
                                            N, NB, total4);

    // layer 1
    k_agg<<<nbAgg, 256, 0, stream>>>(Xlo, Xhi, epack, indptr, invs, Zlo, Zhi, N, nbHalf);
    k_gemm<<<nbGemm, 256, 0, stream>>>(Zlo, Zhi, WhiA, B1, Hlo, Hhi, N);
    // layer 2
    k_agg<<<nbAgg, 256, 0, stream>>>(Hlo, Hhi, epack, indptr, invs, Zlo, Zhi, N, nbHalf);
    k_gemm<<<nbGemm, 256, 0, stream>>>(Zlo, Zhi, WhiA + 16384, B2, Hlo, Hhi, N);
    // layer 3 agg, then fused tail (GEMM W3 + FC1 + FC2 + pool)
    k_agg<<<nbAgg, 256, 0, stream>>>(Hlo, Hhi, epack, indptr, invs, Zlo, Zhi, N, nbHalf);
    k_tail<<<nbGemm, 256, 0, stream>>>(Zlo, Zhi, WhiA + 2 * 16384, B3,
                                       WhiA + 3 * 16384, FB1, FW2, FB2,
                                       BATCH, sums, cnts, N);
    k_softmax<<<1, 64, 0, stream>>>(sums, cnts, (float*)d_out, G);
}

// Round 15
// 208.984 us; speedup vs baseline: 1.9798x; 1.0044x over previous
//
#include <hip/hip_runtime.h>

// ---------------------------------------------------------------------------
// colorableGNN: 3x GCN(128->128) + FC(128->128) + FC(128->2) + mean-pool + softmax
// R14 (delta vs R13): unified fp8 rows restored (R12 half-split was neutral
// and doubled per-edge work). k_agg: 8 nodes/wave x 8 lanes x 16ch/lane --
// ONE uint4 gather per edge (64 lanes x 16B = 1KB, coalescing sweet spot),
// half the instructions and edge-stream of R13. Pipelined e-prefetch +
// masked remainder kept. fp8 acts+Z, 4B edges, bf16 weights, fp32 acc.
// NOTE: gather kernels need occupancy; never fuse agg into GEMM (R7: 104us).
// ---------------------------------------------------------------------------

#define CH 128
#define BSH 7              // 128 dst nodes per bucket
#define SEG 4096           // segment capacity (records) per bucket
#define EPW 4096           // edges per phase-1 workgroup
#define SA 40              // LDS stride for W chunks (shorts)
#define SAF 136            // LDS stride full-K A tile (shorts; 272B = 17*16B)
#define SC 132             // bf16 epilogue stride (shorts)
#define SC8 144            // fp8 epilogue stride (bytes)

typedef unsigned short ushortT;
typedef unsigned int uintT;
typedef unsigned char ucharT;
typedef __attribute__((ext_vector_type(8))) short short8;
typedef __attribute__((ext_vector_type(4))) float floatx4;
typedef __attribute__((ext_vector_type(2))) float floatx2;

__device__ __forceinline__ float bf2f(uintT u) {
    return __uint_as_float(u << 16);
}
__device__ __forceinline__ ushortT f2bf(float f) {
    uintT x = __float_as_uint(f);
    return (ushortT)((x + 0x7fffu + ((x >> 16) & 1u)) >> 16);
}
__device__ __forceinline__ void dec4(uintT u, float* o) {
    floatx2 lo = __builtin_amdgcn_cvt_pk_f32_fp8((int)u, false);
    floatx2 hi = __builtin_amdgcn_cvt_pk_f32_fp8((int)u, true);
    o[0] = lo.x; o[1] = lo.y; o[2] = hi.x; o[3] = hi.y;
}
__device__ __forceinline__ void dec16(uint4 v, float* o) {
    dec4(v.x, o); dec4(v.y, o + 4); dec4(v.z, o + 8); dec4(v.w, o + 12);
}

// ---- phase 1: bin edges into dst-buckets; records packed src|(dst<<16) ----
__global__ __launch_bounds__(256) void k_bin(const int* __restrict__ row,
                                             const int* __restrict__ col,
                                             int* __restrict__ bfill,
                                             uintT* __restrict__ seg,
                                             int E, int NB) {
    __shared__ uintT staged[EPW];   // 16 KB
    __shared__ int target[EPW];     // 16 KB
    __shared__ int sval[512];
    __shared__ int horig[512];
    __shared__ int pcnt[512];
    __shared__ int gbase[512];
    const int t = threadIdx.x;
    const int e0 = blockIdx.x * EPW;
    const int cnt = min(EPW, E - e0);

    sval[t] = 0; sval[t + 256] = 0;
    __syncthreads();

    int er[16], ec[16];
#pragma unroll
    for (int i = 0; i < 16; ++i) {
        int le = i * 256 + t;
        if (le < cnt) {
            er[i] = row[e0 + le];
            ec[i] = col[e0 + le];
            atomicAdd(&sval[ec[i] >> BSH], 1);
        }
    }
    __syncthreads();
    horig[t] = sval[t]; horig[t + 256] = sval[t + 256];
    __syncthreads();
    for (int off = 1; off < 512; off <<= 1) {
        int a = (t >= off) ? sval[t - off] : 0;
        int b2 = sval[t + 256 - off];
        __syncthreads();
        sval[t] += a;
        sval[t + 256] += b2;
        __syncthreads();
    }
    for (int b = t; b < 512; b += 256) {
        int h = horig[b];
        pcnt[b] = sval[b] - h;
        gbase[b] = (h > 0 && b < NB) ? atomicAdd(&bfill[b], h) : 0;
    }
    __syncthreads();
#pragma unroll
    for (int i = 0; i < 16; ++i) {
        int le = i * 256 + t;
        if (le < cnt) {
            int b = ec[i] >> BSH;
            int j = atomicAdd(&pcnt[b], 1);
            staged[j] = (uintT)er[i] | ((uintT)ec[i] << 16);
            int lo = sval[b] - horig[b];
            target[j] = b * SEG + gbase[b] + (j - lo);
        }
    }
    __syncthreads();
    for (int s = t; s < cnt; s += 256) seg[target[s]] = staged[s];
}

// ---- fused: per-bucket degree->invs (0..NB-1) + bucket scan + zero pools --
__global__ __launch_bounds__(512) void k_binvs_bscan(const int* __restrict__ bfill,
                                                     const uintT* __restrict__ seg,
                                                     float* __restrict__ invs,
                                                     int* __restrict__ bbase,
                                                     int* __restrict__ indptr,
                                                     float* __restrict__ sums,
                                                     float* __restrict__ cnts,
                                                     int NB, int N, int E, int G) {
    const int b = blockIdx.x;
    const int t = threadIdx.x;
    if (b < NB) {
        __shared__ int h[128];
        if (t < 128) h[t] = 0;
        __syncthreads();
        int cnt = bfill[b];
        const uintT* sp = seg + (size_t)b * SEG;
        for (int s = t; s < cnt; s += 512) atomicAdd(&h[(sp[s] >> 16) & 127], 1);
        __syncthreads();
        int d = b * 128 + t;
        if (t < 128 && d < N) invs[d] = rsqrtf((float)h[t] + 1.0f);
    } else {
        __shared__ int s[512];
        for (int i = t; i < 3 * G; i += 512) {
            if (i < 2 * G) sums[i] = 0.f;
            else cnts[i - 2 * G] = 0.f;
        }
        int v = (t < NB) ? bfill[t] : 0;
        s[t] = v;
        __syncthreads();
        for (int off = 1; off < 512; off <<= 1) {
            int a = (t >= off) ? s[t - off] : 0;
            __syncthreads();
            s[t] += a;
            __syncthreads();
        }
        if (t < NB) bbase[t] = s[t] - v;  // exclusive
        if (t == 0) indptr[N] = E;
    }
}

// ---- heterogeneous: CSR scatter | weight prep | X->fp8 --------------------
__global__ __launch_bounds__(256) void k_scatterprep(const int* __restrict__ bfill,
                                                     const int* __restrict__ bbase,
                                                     const uintT* __restrict__ seg,
                                                     const float* __restrict__ invs,
                                                     int* __restrict__ indptr,
                                                     uintT* __restrict__ epack,
                                                     const float* __restrict__ X,
                                                     ucharT* __restrict__ Xb,
                                                     const float* __restrict__ w0,
                                                     const float* __restrict__ w1,
                                                     const float* __restrict__ w2,
                                                     const float* __restrict__ w3,
                                                     ushortT* __restrict__ Whi,
                                                     int N, int NB, int total4) {
    const int t = threadIdx.x;
    if ((int)blockIdx.x < NB) {
        __shared__ uintT staged[SEG];   // 16 KB
        __shared__ int h[128];
        __shared__ int sc[128];
        __shared__ int pc[128];
        const int b = blockIdx.x;
        const int cnt = bfill[b];
        const int base = bbase[b];
        const uintT* sp = seg + (size_t)b * SEG;

        if (t < 128) h[t] = 0;
        __syncthreads();
        for (int s = t; s < cnt; s += 256) atomicAdd(&h[(sp[s] >> 16) & 127], 1);
        __syncthreads();
        if (t < 128) sc[t] = h[t];
        __syncthreads();
        for (int off = 1; off < 128; off <<= 1) {
            int a = (t >= off && t < 128) ? sc[t - off] : 0;
            __syncthreads();
            if (t < 128) sc[t] += a;
            __syncthreads();
        }
        if (t < 128) {
            int excl = sc[t] - h[t];
            pc[t] = excl;
            int d = b * 128 + t;
            if (d < N) indptr[d] = base + excl;
        }
        __syncthreads();
        for (int s = t; s < cnt; s += 256) {
            uintT rc = sp[s];
            int src = (int)(rc & 0xffffu), dst = (int)(rc >> 16);
            int j = atomicAdd(&pc[dst & 127], 1);
            float nrm = invs[src] * invs[dst];
            staged[j] = (uintT)src | ((uintT)f2bf(nrm) << 16);
        }
        __syncthreads();
        for (int s = t; s < cnt; s += 256) epack[base + s] = staged[s];
    } else if ((int)blockIdx.x < NB + 256) {
        int idx = (blockIdx.x - NB) * 256 + t;  // 0..65535
        int m = idx >> 14;
        int r = idx & 16383;
        int n = r >> 7;
        int k = r & 127;
        const float* W = (m == 0) ? w0 : (m == 1) ? w1 : (m == 2) ? w2 : w3;
        Whi[m * 16384 + n * CH + k] = f2bf(W[k * CH + n]);
    } else {
        int i = (blockIdx.x - NB - 256) * 256 + t;
        if (i < total4) {
            float4 v = reinterpret_cast<const float4*>(X)[i];
            int r0 = __builtin_amdgcn_cvt_pk_fp8_f32(v.x, v.y, 0, false);
            int r1 = __builtin_amdgcn_cvt_pk_fp8_f32(v.z, v.w, r0, true);
            reinterpret_cast<int*>(Xb)[i] = r1;
        }
    }
}

// ---- aggregation: 8 nodes/wave x 8 lanes x 16ch (uint4 = full row/gather) -
// pipelined e-prefetch + masked vector remainder (R13).
__global__ __launch_bounds__(256) void k_agg(const ucharT* __restrict__ H8,
                                             const uintT* __restrict__ epack,
                                             const int* __restrict__ indptr,
                                             const float* __restrict__ invs,
                                             ucharT* __restrict__ Z8, int N) {
    const int wave = threadIdx.x >> 6, lane = threadIdx.x & 63;
    const int ng = lane >> 3;        // node slot 0..7
    const int l = lane & 7;          // 16 channels each (uint4)
    const int node = blockIdx.x * 32 + wave * 8 + ng;
    if (node >= N) return;

    const uint4* H4 = reinterpret_cast<const uint4*>(H8);

    float acc[16];
    {
        float sn = invs[node];
        float sn2 = sn * sn;
        float d[16];
        dec16(H4[(size_t)node * 8 + l], d);
#pragma unroll
        for (int j = 0; j < 16; ++j) acc[j] = sn2 * d[j];
    }

    int p = indptr[node];
    int p1 = indptr[node + 1];

    if (p + 8 <= p1) {
        uintT e0[8];
#pragma unroll
        for (int i = 0; i < 8; ++i) e0[i] = epack[p + i];
        for (; p + 16 <= p1; p += 8) {
            uintT e1[8];
#pragma unroll
            for (int i = 0; i < 8; ++i) e1[i] = epack[p + 8 + i];
            uint4 g[8];
#pragma unroll
            for (int i = 0; i < 8; ++i) g[i] = H4[(size_t)(int)(e0[i] & 0xffffu) * 8 + l];
#pragma unroll
            for (int i = 0; i < 8; ++i) {
                float wv = bf2f(e0[i] >> 16);
                float d[16];
                dec16(g[i], d);
#pragma unroll
                for (int j = 0; j < 16; ++j) acc[j] += wv * d[j];
            }
#pragma unroll
            for (int i = 0; i < 8; ++i) e0[i] = e1[i];
        }
        {
            uint4 g[8];
#pragma unroll
            for (int i = 0; i < 8; ++i) g[i] = H4[(size_t)(int)(e0[i] & 0xffffu) * 8 + l];
#pragma unroll
            for (int i = 0; i < 8; ++i) {
                float wv = bf2f(e0[i] >> 16);
                float d[16];
                dec16(g[i], d);
#pragma unroll
                for (int j = 0; j < 16; ++j) acc[j] += wv * d[j];
            }
            p += 8;
        }
    }
    int rem = p1 - p;
    if (rem > 0) {
        uintT e[8];
#pragma unroll
        for (int i = 0; i < 8; ++i) e[i] = epack[(i < rem) ? p + i : p];
        uint4 g[8];
#pragma unroll
        for (int i = 0; i < 8; ++i) g[i] = H4[(size_t)(int)(e[i] & 0xffffu) * 8 + l];
#pragma unroll
        for (int i = 0; i < 8; ++i) {
            float wv = (i < rem) ? bf2f(e[i] >> 16) : 0.f;
            float d[16];
            dec16(g[i], d);
#pragma unroll
            for (int j = 0; j < 16; ++j) acc[j] += wv * d[j];
        }
    }

    uint4 o;
    {
        int r0 = __builtin_amdgcn_cvt_pk_fp8_f32(acc[0], acc[1], 0, false);
        r0 = __builtin_amdgcn_cvt_pk_fp8_f32(acc[2], acc[3], r0, true);
        int r1 = __builtin_amdgcn_cvt_pk_fp8_f32(acc[4], acc[5], 0, false);
        r1 = __builtin_amdgcn_cvt_pk_fp8_f32(acc[6], acc[7], r1, true);
        int r2 = __builtin_amdgcn_cvt_pk_fp8_f32(acc[8], acc[9], 0, false);
        r2 = __builtin_amdgcn_cvt_pk_fp8_f32(acc[10], acc[11], r2, true);
        int r3 = __builtin_amdgcn_cvt_pk_fp8_f32(acc[12], acc[13], 0, false);
        r3 = __builtin_amdgcn_cvt_pk_fp8_f32(acc[14], acc[15], r3, true);
        o.x = (uintT)r0; o.y = (uintT)r1; o.z = (uintT)r2; o.w = (uintT)r3;
    }
    reinterpret_cast<uint4*>(Z8)[(size_t)node * 8 + l] = o;
}

// ---- MFMA GEMM (GCN layers 1,2): fp8 in, fp8 out, single bf16 W -----------
__global__ __launch_bounds__(256) void k_gemm(const ucharT* __restrict__ In8,
                                              const ushortT* __restrict__ Whi,
                                              const float* __restrict__ Bias,
                                              ucharT* __restrict__ Out8, int N) {
    __shared__ ushortT smem[128 * SC];  // 33792 B union
    ushortT* As = smem;
    ushortT* Ws = smem + 128 * SA;
    ushortT* Cs = smem;                  // epilogue alias

    const int tid = threadIdx.x;
    const int wave = tid >> 6, lane = tid & 63;
    const int quad = lane >> 4, l15 = lane & 15;
    const int mBase = (wave >> 1) * 64, nBase = (wave & 1) * 64;
    const int row0 = blockIdx.x * 128;
    const int r = tid >> 1, half = tid & 1;

    floatx4 acc[4][4];
    const floatx4 zero4 = {0.f, 0.f, 0.f, 0.f};
#pragma unroll
    for (int i = 0; i < 4; i++)
#pragma unroll
        for (int j = 0; j < 4; j++) acc[i][j] = zero4;

    for (int ks = 0; ks < 4; ++ks) {
        {
            int grow = row0 + r;
            uint4 a8 = {0, 0, 0, 0};
            if (grow < N)
                a8 = *reinterpret_cast<const uint4*>(
                    In8 + (size_t)grow * CH + ks * 32 + half * 16);
            uintT wds[4] = {a8.x, a8.y, a8.z, a8.w};
            uintT ob[8];
#pragma unroll
            for (int q = 0; q < 4; ++q) {
                float d[4];
                dec4(wds[q], d);
                ob[2 * q] = (uintT)f2bf(d[0]) | ((uintT)f2bf(d[1]) << 16);
                ob[2 * q + 1] = (uintT)f2bf(d[2]) | ((uintT)f2bf(d[3]) << 16);
            }
            uint4* dd = reinterpret_cast<uint4*>(&As[r * SA + half * 16]);
            dd[0] = uint4{ob[0], ob[1], ob[2], ob[3]};
            dd[1] = uint4{ob[4], ob[5], ob[6], ob[7]};
            const uint4* sh = reinterpret_cast<const uint4*>(Whi + r * CH + ks * 32 + half * 16);
            uint4* dh = reinterpret_cast<uint4*>(&Ws[r * SA + half * 16]);
            dh[0] = sh[0]; dh[1] = sh[1];
        }
        __syncthreads();

        short8 af[4], wf[4];
#pragma unroll
        for (int mt = 0; mt < 4; ++mt)
            af[mt] = *reinterpret_cast<const short8*>(&As[(mBase + mt * 16 + l15) * SA + quad * 8]);
#pragma unroll
        for (int nt = 0; nt < 4; ++nt)
            wf[nt] = *reinterpret_cast<const short8*>(&Ws[(nBase + nt * 16 + l15) * SA + quad * 8]);
#pragma unroll
        for (int mt = 0; mt < 4; ++mt)
#pragma unroll
            for (int nt = 0; nt < 4; ++nt)
                acc[mt][nt] = __builtin_amdgcn_mfma_f32_16x16x32_bf16(af[mt], wf[nt], acc[mt][nt], 0, 0, 0);
        __syncthreads();
    }

    float bb[4];
#pragma unroll
    for (int nt = 0; nt < 4; ++nt) bb[nt] = Bias[nBase + nt * 16 + l15];

    ucharT* Cs8 = reinterpret_cast<ucharT*>(Cs);
#pragma unroll
    for (int mt = 0; mt < 4; ++mt)
#pragma unroll
        for (int nt = 0; nt < 4; ++nt)
#pragma unroll
            for (int r4 = 0; r4 < 4; ++r4) {
                int lrow = mBase + mt * 16 + quad * 4 + r4;
                float v = fmaxf(acc[mt][nt][r4] + bb[nt], 0.f);
                int f8 = __builtin_amdgcn_cvt_pk_fp8_f32(v, 0.f, 0, false);
                Cs8[lrow * SC8 + nBase + nt * 16 + l15] = (ucharT)(f8 & 0xff);
            }
    __syncthreads();
    {
        int grow = row0 + r;
        if (grow < N) {
            const uint4* s4 = reinterpret_cast<const uint4*>(&Cs8[r * SC8 + half * 64]);
            uint4* dst = reinterpret_cast<uint4*>(Out8 + (size_t)grow * CH + half * 64);
#pragma unroll
            for (int q = 0; q < 4; ++q) dst[q] = s4[q];
        }
    }
}

// ---- fused tail: GEMM(W3) -> relu -> GEMM(FW1) -> FC2 -> mean-pool --------
__global__ __launch_bounds__(256) void k_tail(const ucharT* __restrict__ Z8,
                                              const ushortT* __restrict__ W3hi,
                                              const float* __restrict__ B3,
                                              const ushortT* __restrict__ F1hi,
                                              const float* __restrict__ FB1,
                                              const float* __restrict__ FW2,
                                              const float* __restrict__ FB2,
                                              const int* __restrict__ batch,
                                              float* __restrict__ sums,
                                              float* __restrict__ cnts, int N) {
    __shared__ ushortT Hf[128 * SAF];   // 34816 B: A-tile (Z), then H3 tile
    __shared__ ushortT Ws[128 * SA];    // 10240 B
    __shared__ float rp0[256];
    __shared__ float rp1[256];
    __shared__ float ls[192];

    const int tid = threadIdx.x;
    const int wave = tid >> 6, lane = tid & 63;
    const int quad = lane >> 4, l15 = lane & 15;
    const int mBase = (wave >> 1) * 64, nBase = (wave & 1) * 64;
    const int row0 = blockIdx.x * 128;
    const int r = tid >> 1, half = tid & 1;

    // stage full Z tile: fp8 -> bf16 into Hf (64 B = full half-row per thread)
    {
        int grow = row0 + r;
        uint4 a8 = {0, 0, 0, 0}, b8 = {0, 0, 0, 0}, c8 = {0, 0, 0, 0}, d8v = {0, 0, 0, 0};
        if (grow < N) {
            const uint4* s = reinterpret_cast<const uint4*>(Z8 + (size_t)grow * CH + half * 64);
            a8 = s[0]; b8 = s[1]; c8 = s[2]; d8v = s[3];
        }
        uintT wds[16] = {a8.x, a8.y, a8.z, a8.w, b8.x, b8.y, b8.z, b8.w,
                         c8.x, c8.y, c8.z, c8.w, d8v.x, d8v.y, d8v.z, d8v.w};
#pragma unroll
        for (int q = 0; q < 16; ++q) {
            float d[4];
            dec4(wds[q], d);
            uint2 o;
            o.x = (uintT)f2bf(d[0]) | ((uintT)f2bf(d[1]) << 16);
            o.y = (uintT)f2bf(d[2]) | ((uintT)f2bf(d[3]) << 16);
            *reinterpret_cast<uint2*>(&Hf[r * SAF + half * 64 + q * 4]) = o;
        }
    }

    floatx4 acc[4][4];
    const floatx4 zero4 = {0.f, 0.f, 0.f, 0.f};
#pragma unroll
    for (int i = 0; i < 4; i++)
#pragma unroll
        for (int j = 0; j < 4; j++) acc[i][j] = zero4;

    // GEMM 1: Z @ W3
    for (int ks = 0; ks < 4; ++ks) {
        {
            const uint4* sh = reinterpret_cast<const uint4*>(W3hi + r * CH + ks * 32 + half * 16);
            uint4* dh = reinterpret_cast<uint4*>(&Ws[r * SA + half * 16]);
            dh[0] = sh[0]; dh[1] = sh[1];
        }
        __syncthreads();
        short8 af[4], wf[4];
#pragma unroll
        for (int mt = 0; mt < 4; ++mt)
            af[mt] = *reinterpret_cast<const short8*>(&Hf[(mBase + mt * 16 + l15) * SAF + ks * 32 + quad * 8]);
#pragma unroll
        for (int nt = 0; nt < 4; ++nt)
            wf[nt] = *reinterpret_cast<const short8*>(&Ws[(nBase + nt * 16 + l15) * SA + quad * 8]);
#pragma unroll
        for (int mt = 0; mt < 4; ++mt)
#pragma unroll
            for (int nt = 0; nt < 4; ++nt)
                acc[mt][nt] = __builtin_amdgcn_mfma_f32_16x16x32_bf16(af[mt], wf[nt], acc[mt][nt], 0, 0, 0);
        __syncthreads();
    }

    // epilogue 1: H3 = relu(acc + b3) -> back into Hf (A of FC1)
    {
        float bb[4];
#pragma unroll
        for (int nt = 0; nt < 4; ++nt) bb[nt] = B3[nBase + nt * 16 + l15];
#pragma unroll
        for (int mt = 0; mt < 4; ++mt)
#pragma unroll
            for (int nt = 0; nt < 4; ++nt)
#pragma unroll
                for (int r4 = 0; r4 < 4; ++r4) {
                    int lrow = mBase + mt * 16 + quad * 4 + r4;
                    float v = fmaxf(acc[mt][nt][r4] + bb[nt], 0.f);
                    Hf[lrow * SAF + nBase + nt * 16 + l15] = f2bf(v);
                }
    }
    __syncthreads();

    // GEMM 2: H3 @ FW1
#pragma unroll
    for (int i = 0; i < 4; i++)
#pragma unroll
        for (int j = 0; j < 4; j++) acc[i][j] = zero4;
    for (int ks = 0; ks < 4; ++ks) {
        {
            const uint4* sh = reinterpret_cast<const uint4*>(F1hi + r * CH + ks * 32 + half * 16);
            uint4* dh = reinterpret_cast<uint4*>(&Ws[r * SA + half * 16]);
            dh[0] = sh[0]; dh[1] = sh[1];
        }
        __syncthreads();
        short8 af[4], wf[4];
#pragma unroll
        for (int mt = 0; mt < 4; ++mt)
            af[mt] = *reinterpret_cast<const short8*>(&Hf[(mBase + mt * 16 + l15) * SAF + ks * 32 + quad * 8]);
#pragma unroll
        for (int nt = 0; nt < 4; ++nt)
            wf[nt] = *reinterpret_cast<const short8*>(&Ws[(nBase + nt * 16 + l15) * SA + quad * 8]);
#pragma unroll
        for (int mt = 0; mt < 4; ++mt)
#pragma unroll
            for (int nt = 0; nt < 4; ++nt)
                acc[mt][nt] = __builtin_amdgcn_mfma_f32_16x16x32_bf16(af[mt], wf[nt], acc[mt][nt], 0, 0, 0);
        __syncthreads();
    }

    // FC2: per-row dot with fcW2 over this lane's 4 columns, reduce over l15
    {
        float bb[4];
#pragma unroll
        for (int nt = 0; nt < 4; ++nt) bb[nt] = FB1[nBase + nt * 16 + l15];
        float w20[4], w21[4];
#pragma unroll
        for (int nt = 0; nt < 4; ++nt) {
            float2 wv = *reinterpret_cast<const float2*>(FW2 + 2 * (nBase + nt * 16 + l15));
            w20[nt] = wv.x;
            w21[nt] = wv.y;
        }
#pragma unroll
        for (int mt = 0; mt < 4; ++mt)
#pragma unroll
            for (int r4 = 0; r4 < 4; ++r4) {
                float d0 = 0.f, d1 = 0.f;
#pragma unroll
                for (int nt = 0; nt < 4; ++nt) {
                    float v = fmaxf(acc[mt][nt][r4] + bb[nt], 0.f);
                    d0 += v * w20[nt];
                    d1 += v * w21[nt];
                }
#pragma unroll
                for (int m = 8; m >= 1; m >>= 1) {
                    d0 += __shfl_xor(d0, m, 64);
                    d1 += __shfl_xor(d1, m, 64);
                }
                if (l15 == 0) {
                    int lrow = mBase + mt * 16 + quad * 4 + r4;
                    rp0[lrow * 2 + (wave & 1)] = d0;
                    rp1[lrow * 2 + (wave & 1)] = d1;
                }
            }
    }
    if (tid < 192) ls[tid] = 0.f;
    __syncthreads();

    if (tid < 128) {
        int node = row0 + tid;
        if (node < N) {
            float d0 = rp0[tid * 2] + rp0[tid * 2 + 1] + FB2[0];
            float d1 = rp1[tid * 2] + rp1[tid * 2 + 1] + FB2[1];
            int g = batch[node];
            atomicAdd(&ls[g], d0);
            atomicAdd(&ls[64 + g], d1);
            atomicAdd(&ls[128 + g], 1.0f);
        }
    }
    __syncthreads();
    if (tid < 64) {
        float c = ls[128 + tid];
        if (c != 0.f) {
            atomicAdd(&sums[2 * tid], ls[tid]);
            atomicAdd(&sums[2 * tid + 1], ls[64 + tid]);
            atomicAdd(&cnts[tid], c);
        }
    }
}

__global__ void k_softmax(const float* __restrict__ sums, const float* __restrict__ cnts,
                          float* __restrict__ out, int G) {
    int g = blockIdx.x * blockDim.x + threadIdx.x;
    if (g < G) {
        float c = fmaxf(cnts[g], 1.0f);
        float p0 = sums[2 * g] / c;
        float p1 = sums[2 * g + 1] / c;
        float m = fmaxf(p0, p1);
        float e0 = expf(p0 - m), e1 = expf(p1 - m);
        float inv = 1.f / (e0 + e1);
        out[2 * g] = e0 * inv;
        out[2 * g + 1] = e1 * inv;
    }
}

// ---------------------------------------------------------------------------
extern "C" void kernel_launch(void* const* d_in, const int* in_sizes, int n_in,
                              void* d_out, int out_size, void* d_ws, size_t ws_size,
                              hipStream_t stream) {
    const float* X   = (const float*)d_in[0];
    const int* EI    = (const int*)d_in[1];
    const int* BATCH = (const int*)d_in[2];
    const float* W1  = (const float*)d_in[3];
    const float* B1  = (const float*)d_in[4];
    const float* W2  = (const float*)d_in[5];
    const float* B2  = (const float*)d_in[6];
    const float* W3  = (const float*)d_in[7];
    const float* B3  = (const float*)d_in[8];
    const float* FW1 = (const float*)d_in[9];
    const float* FB1 = (const float*)d_in[10];
    const float* FW2 = (const float*)d_in[11];
    const float* FB2 = (const float*)d_in[12];

    const int N = in_sizes[0] / CH;
    const int E = in_sizes[1] / 2;
    const int G = out_size / 2;
    const int* rowp = EI;
    const int* colp = EI + E;
    const int NB = (N + 127) >> BSH;

    char* w = (char*)d_ws;
    auto alloc = [&](size_t bytes) -> char* {
        char* p = w;
        w += (bytes + 255) & ~(size_t)255;
        return p;
    };
    ucharT*  Z8    = (ucharT*)alloc((size_t)N * CH);        // fp8 Z (agg out)
    ucharT*  Hb8   = (ucharT*)alloc((size_t)N * CH);        // fp8 H1/H2
    ucharT*  Xb8   = (ucharT*)alloc((size_t)N * CH);        // fp8 X
    ushortT* WhiA  = (ushortT*)alloc((size_t)4 * 16384 * 2);
    float* invs    = (float*)alloc((size_t)N * 4);
    int*   indptr  = (int*)alloc((size_t)(N + 1) * 4);
    uintT* epack   = (uintT*)alloc((size_t)E * 4);
    uintT* seg     = (uintT*)alloc((size_t)NB * SEG * 4);
    int*   bfill   = (int*)alloc((size_t)NB * 4);
    int*   bbase   = (int*)alloc((size_t)NB * 4);
    float* sums    = (float*)alloc((size_t)G * 3 * 4);      // sums | cnts
    float* cnts    = sums + 2 * G;

    const int nbAgg  = (N + 31) / 32;
    const int nbGemm = (N + 127) / 128;
    const int nbBin  = (E + EPW - 1) / EPW;
    const int total4 = N * CH / 4;
    const int nbSP   = NB + 256 + (total4 + 255) / 256;

    hipMemsetAsync(bfill, 0, (size_t)NB * 4, stream);
    k_bin<<<nbBin, 256, 0, stream>>>(rowp, colp, bfill, seg, E, NB);
    k_binvs_bscan<<<NB + 1, 512, 0, stream>>>(bfill, seg, invs, bbase, indptr,
                                              sums, cnts, NB, N, E, G);
    k_scatterprep<<<nbSP, 256, 0, stream>>>(bfill, bbase, seg, invs, indptr, epack,
                                            X, Xb8, W1, W2, W3, FW1, WhiA, N, NB, total4);

    // layer 1
    k_agg<<<nbAgg, 256, 0, stream>>>(Xb8, epack, indptr, invs, Z8, N);
    k_gemm<<<nbGemm, 256, 0, stream>>>(Z8, WhiA, B1, Hb8, N);
    // layer 2
    k_agg<<<nbAgg, 256, 0, stream>>>(Hb8, epack, indptr, invs, Z8, N);
    k_gemm<<<nbGemm, 256, 0, stream>>>(Z8, WhiA + 16384, B2, Hb8, N);
    // layer 3 agg, then fused tail (GEMM W3 + FC1 + FC2 + pool)
    k_agg<<<nbAgg, 256, 0, stream>>>(Hb8, epack, indptr, invs, Z8, N);
    k_tail<<<nbGemm, 256, 0, stream>>>(Z8, WhiA + 2 * 16384, B3,
                                       WhiA + 3 * 16384, FB1, FW2, FB2,
                                       BATCH, sums, cnts, N);
    k_softmax<<<1, 64, 0, stream>>>(sums, cnts, (float*)d_out, G);
}